// Round 13
// baseline (21886.258 us; speedup 1.0000x reference)
//
#include <hip/hip_runtime.h>
#include <math.h>

#define BB 8
#define TT 256
#define HH 768
#define NL 12
#define NH_ 12
#define DH_ 64
#define FF_ 3072
#define LH_ 256
#define KK_ 9
#define NBLK 256

typedef unsigned char u8;
typedef unsigned short u16;
typedef unsigned int u32;
typedef __attribute__((ext_vector_type(8))) short bf16x8;
typedef __attribute__((ext_vector_type(4))) float f32x4;

static __device__ __forceinline__ float sigm_fast(float x) {
    return __builtin_amdgcn_rcpf(1.0f + __expf(-x));
}
static __device__ __forceinline__ float tanh_fast(float x) {
    return 1.0f - 2.0f * __builtin_amdgcn_rcpf(1.0f + __expf(2.0f * x));
}

static __device__ __forceinline__ u16 f2bf(float f) {
    u32 u = __float_as_uint(f);
    u += 0x7fffu + ((u >> 16) & 1u);
    return (u16)(u >> 16);
}
static __device__ __forceinline__ float bf2f(u16 v) {
    return __uint_as_float(((u32)v) << 16);
}

// float -> OCP e4m3fn, RNE (prep path only)
static __device__ __forceinline__ u8 f2e4m3(float x) {
    float a = fabsf(x);
    u8 s = (u8)((__float_as_uint(x) >> 31) << 7);
    if (!(a > 0.001953125f)) {
        int m = (int)rintf(a * 512.0f);
        return s | (u8)m;
    }
    if (a >= 448.0f) return s | 0x7E;
    int e; float fr = frexpf(a, &e);
    int E = e - 1;
    if (E < -6) {
        int m = (int)rintf(a * 512.0f);
        if (m >= 8) return s | 0x08;
        return s | (u8)m;
    }
    int m = (int)rintf((fr * 2.0f - 1.0f) * 8.0f);
    if (m == 8) { E += 1; m = 0; if (E > 8) return s | 0x7E; }
    return s | (u8)((E + 7) << 3) | (u8)m;
}

static __device__ __forceinline__ f32x4 mfma_fp8(long a, long b, f32x4 c) {
    return __builtin_amdgcn_mfma_f32_16x16x32_fp8_fp8(a, b, c, 0, 0, 0);
}

#define GLL16(gp, lp) __builtin_amdgcn_global_load_lds( \
    (const __attribute__((address_space(1))) void*)(gp), \
    (__attribute__((address_space(3))) void*)(lp), 16, 0, 0)

// ---------------- grid barrier (all 256 blocks co-resident) ----------------
static __device__ __forceinline__ void gridbar(unsigned* cnt, unsigned* gen, unsigned& target) {
    __threadfence();            // flush this thread's writes (device scope)
    __syncthreads();            // all threads of block flushed
    ++target;
    if (threadIdx.x == 0) {
        unsigned old = __hip_atomic_fetch_add(cnt, 1u, __ATOMIC_ACQ_REL, __HIP_MEMORY_SCOPE_AGENT);
        if (old == (unsigned)(NBLK - 1)) {
            __hip_atomic_store(cnt, 0u, __ATOMIC_RELAXED, __HIP_MEMORY_SCOPE_AGENT);
            __hip_atomic_fetch_add(gen, 1u, __ATOMIC_RELEASE, __HIP_MEMORY_SCOPE_AGENT);
        } else {
            while (__hip_atomic_load(gen, __ATOMIC_ACQUIRE, __HIP_MEMORY_SCOPE_AGENT) < target)
                __builtin_amdgcn_s_sleep(2);
        }
    }
    __syncthreads();
    __threadfence();            // acquire: invalidate stale cache lines
}

// ---------------- embedding + LN (wave per row) ----------------
__global__ __launch_bounds__(512) void embed_ln_kernel(
    const int* __restrict__ ids, const float* __restrict__ we, const float* __restrict__ pe,
    const float* __restrict__ te, const float* __restrict__ g, const float* __restrict__ b,
    float* __restrict__ out, u16* __restrict__ outb) {
    int row = blockIdx.x * 8 + (threadIdx.x >> 6);
    if (row >= BB * TT) return;
    int lane = threadIdx.x & 63;
    int t = row % TT;
    int id = ids[row];
    float v[12];
    float s = 0.f;
#pragma unroll
    for (int p = 0; p < 3; ++p) {
        int h = p * 256 + lane * 4;
        float4 wv = *(const float4*)&we[(size_t)id * HH + h];
        float4 pv = *(const float4*)&pe[(size_t)t * HH + h];
        float4 tv = *(const float4*)&te[h];
        v[4*p+0] = wv.x + pv.x + tv.x; v[4*p+1] = wv.y + pv.y + tv.y;
        v[4*p+2] = wv.z + pv.z + tv.z; v[4*p+3] = wv.w + pv.w + tv.w;
        s += v[4*p] + v[4*p+1] + v[4*p+2] + v[4*p+3];
    }
#pragma unroll
    for (int o = 32; o > 0; o >>= 1) s += __shfl_xor(s, o);
    float mean = s * (1.0f / HH);
    float vs = 0.f;
#pragma unroll
    for (int i = 0; i < 12; ++i) { float d = v[i] - mean; vs += d * d; }
#pragma unroll
    for (int o = 32; o > 0; o >>= 1) vs += __shfl_xor(vs, o);
    float rstd = rsqrtf(vs * (1.0f / HH) + 1e-12f);
#pragma unroll
    for (int p = 0; p < 3; ++p) {
        int h = p * 256 + lane * 4;
        float4 gv = *(const float4*)&g[h];
        float4 bv = *(const float4*)&b[h];
        float4 o4;
        o4.x = (v[4*p+0] - mean) * rstd * gv.x + bv.x;
        o4.y = (v[4*p+1] - mean) * rstd * gv.y + bv.y;
        o4.z = (v[4*p+2] - mean) * rstd * gv.z + bv.z;
        o4.w = (v[4*p+3] - mean) * rstd * gv.w + bv.w;
        *(float4*)&out[(size_t)row * HH + h] = o4;
        uint2 pk;
        pk.x = (u32)f2bf(o4.x) | ((u32)f2bf(o4.y) << 16);
        pk.y = (u32)f2bf(o4.z) | ((u32)f2bf(o4.w) << 16);
        *(uint2*)&outb[(size_t)row * HH + h] = pk;
    }
}

// ---------------- merged prologue: pack w_hh fp8 frags + convert w_ih ----------------
__global__ __launch_bounds__(256) void prep_kernel(
    const float* __restrict__ whf, const float* __restrict__ whb,
    const float* __restrict__ wif, const float* __restrict__ wib,
    u8* __restrict__ wfrag8, u16* __restrict__ wihT) {
    int bid = blockIdx.x;
    int tid = threadIdx.x;
    if (bid < 256) {
        int idx = bid * 256 + tid;
        int dir = idx >> 15;
        int kt  = (idx >> 12) & 7;
        int mt  = (idx >> 6) & 63;
        int lane = idx & 63;
        const float* W = dir ? whb : whf;
        int row = mt * 16 + (lane & 15);
        int k = kt * 32 + (lane >> 4) * 8;
        const float* src = W + (size_t)row * LH_ + k;
        u8 o[8];
#pragma unroll
        for (int j = 0; j < 8; ++j) o[j] = f2e4m3(src[j]);
        uint2 pk;
        pk.x = (u32)o[0] | ((u32)o[1] << 8) | ((u32)o[2] << 16) | ((u32)o[3] << 24);
        pk.y = (u32)o[4] | ((u32)o[5] << 8) | ((u32)o[6] << 16) | ((u32)o[7] << 24);
        size_t base = (size_t)(((dir * 8 + kt) * 64 + mt) * 64 + lane) * 8;
        *(uint2*)&wfrag8[base] = pk;
    } else {
        int which = (bid < 1024) ? 0 : 1;
        const float* src = which ? wib : wif;
        u16* dst = wihT + (size_t)which * 786432;
        int i = (bid - (which ? 1024 : 256)) * 256 + tid;
        float4 v = *(const float4*)&src[(size_t)i * 4];
        uint2 o;
        o.x = (u32)f2bf(v.x) | ((u32)f2bf(v.y) << 16);
        o.y = (u32)f2bf(v.z) | ((u32)f2bf(v.w) << 16);
        *(uint2*)&dst[(size_t)i * 4] = o;
    }
}

// ================= MEGA KERNEL =================
// 256 blocks x 512 threads; all phases via grid barrier. Each block hosts two
// 256-thread "virtual blocks" (halves) for gemm/conv/attention units.

// ---- stage one tile into LDS (per half) ----
static __device__ __forceinline__ void stage_tile(
    const u16* __restrict__ S, int r0, int K, int k0, u16* lds, int nrows, int w, int lane) {
    int srow = lane >> 3;
    int sgrp = ((lane & 7) ^ srow) * 8;
    int per = nrows >> 5;
#pragma unroll
    for (int i = 0; i < per; ++i) {
        int c = w * per + i;
        GLL16(S + (size_t)(r0 + 8 * c + srow) * K + k0 + sgrp, lds + (size_t)(8 * c) * 64);
    }
}

// ---- gemm phase: C(2048 x N) = A * BT^T + bias; 128x64 tiles ----
static __device__ void gemm_phase(
    const u16* __restrict__ A, const u16* __restrict__ BT,
    const float* __restrict__ b0, const float* __restrict__ b1, const float* __restrict__ b2,
    int seg, float* __restrict__ C, u16* __restrict__ Cbf, int N, int K,
    bool gelu, bool outbf, u8* smem_half, int vb, int tidh) {
    u16* Als0 = (u16*)smem_half;            // [128][64]
    u16* Als1 = Als0 + 128 * 64;
    u16* Bls0 = Als1 + 128 * 64;            // [64][64]
    u16* Bls1 = Bls0 + 64 * 64;
    u16* AlsB[2] = { Als0, Als1 };
    u16* BlsB[2] = { Bls0, Bls1 };
    int lane = tidh & 63, w = tidh >> 6;    // w 0..3
    int wr = w >> 1, wc = w & 1;
    int l15 = lane & 15, q = lane >> 4;
    int ntiles = (N >> 6) * 16;
    int NIT = (ntiles + 511) >> 9;
    int KT = K >> 6;

    for (int it = 0; it < NIT; ++it) {
        int u = it * 512 + vb;
        bool act = u < ntiles;
        int uu = act ? u : (ntiles - 1);
        int m0 = (uu & 15) * 128;
        int n0 = (uu >> 4) * 64;

        f32x4 acc[4][2];
#pragma unroll
        for (int mi = 0; mi < 4; ++mi) {
            acc[mi][0] = (f32x4){0.f, 0.f, 0.f, 0.f};
            acc[mi][1] = (f32x4){0.f, 0.f, 0.f, 0.f};
        }
        stage_tile(A, m0, K, 0, AlsB[0], 128, w, lane);
        stage_tile(BT, n0, K, 0, BlsB[0], 64, w, lane);
        __syncthreads();
        int cur = 0;
        for (int kt = 0; kt < KT; ++kt) {
            if (kt + 1 < KT) {
                stage_tile(A, m0, K, (kt + 1) << 6, AlsB[cur ^ 1], 128, w, lane);
                stage_tile(BT, n0, K, (kt + 1) << 6, BlsB[cur ^ 1], 64, w, lane);
            }
#pragma unroll
            for (int ks = 0; ks < 2; ++ks) {
                int g8 = (((ks * 4 + q) ^ (l15 & 7)) * 8);
                bf16x8 bf0 = *(const bf16x8*)&BlsB[cur][(size_t)(wc * 32 + l15) * 64 + g8];
                bf16x8 bf1 = *(const bf16x8*)&BlsB[cur][(size_t)(wc * 32 + 16 + l15) * 64 + g8];
#pragma unroll
                for (int mi = 0; mi < 4; ++mi) {
                    bf16x8 a = *(const bf16x8*)&AlsB[cur][(size_t)(wr * 64 + mi * 16 + l15) * 64 + g8];
                    acc[mi][0] = __builtin_amdgcn_mfma_f32_16x16x32_bf16(a, bf0, acc[mi][0], 0, 0, 0);
                    acc[mi][1] = __builtin_amdgcn_mfma_f32_16x16x32_bf16(a, bf1, acc[mi][1], 0, 0, 0);
                }
            }
            __syncthreads();
            cur ^= 1;
        }
        if (act) {
            int rbase = m0 + wr * 64 + q * 4;
            int cbase = n0 + wc * 32 + l15;
#pragma unroll
            for (int mi = 0; mi < 4; ++mi) {
#pragma unroll
                for (int nj = 0; nj < 2; ++nj) {
                    int col = cbase + nj * 16;
                    int cc = col;
                    const float* bp;
                    if (cc < seg) bp = b0;
                    else if (cc < 2 * seg) { bp = b1; cc -= seg; }
                    else { bp = b2; cc -= 2 * seg; }
                    float bias = bp[cc];
#pragma unroll
                    for (int j = 0; j < 4; ++j) {
                        int row = rbase + mi * 16 + j;
                        float v = acc[mi][nj][j] + bias;
                        if (gelu) v = 0.5f * v * (1.0f + erff(v * 0.70710678118654752f));
                        if (outbf) Cbf[(size_t)row * N + col] = f2bf(v);
                        else       C[(size_t)row * N + col] = v;
                    }
                }
            }
        }
    }
}

// ---- attention phase (per half, unit = (b,h,qhalf)) ----
static __device__ void attn_phase(
    const float* __restrict__ qkv, const int* __restrict__ mask, u16* __restrict__ ctxb,
    u8* smem_half, int vb, int tidh) {
    bool act = vb < BB * NH_ * 2;
    int u = act ? vb : 0;
    int half = u & 1;
    int bh = u >> 1;
    int b = bh / NH_, h = bh % NH_;
    int q_i = half * 128 + (tidh >> 1);
    int dh = tidh & 1;
    float* bias_s = (float*)smem_half;    // 256 floats
    if (act) {
        for (int i = tidh; i < TT; i += 256)
            bias_s[i] = (1.0f - (float)mask[b * TT + i]) * -10000.0f;
    }
    __syncthreads();
    if (act) {
        const float* qp = qkv + (size_t)(b * TT + q_i) * 2304 + h * DH_ + dh * 32;
        float qv[32];
#pragma unroll
        for (int d = 0; d < 8; ++d) {
            float4 v = *(const float4*)(qp + 4 * d);
            qv[4*d] = v.x; qv[4*d+1] = v.y; qv[4*d+2] = v.z; qv[4*d+3] = v.w;
        }
        const float* kbase = qkv + (size_t)b * TT * 2304 + 768 + h * DH_ + dh * 32;
        const float* vbase = qkv + (size_t)b * TT * 2304 + 1536 + h * DH_ + dh * 32;
        float acc[32] = {};
        float l = 0.f;
        for (int kk = 0; kk < TT; ++kk) {
            const float4* kp = (const float4*)(kbase + (size_t)kk * 2304);
            float4 s4 = {0.f, 0.f, 0.f, 0.f};
#pragma unroll
            for (int d = 0; d < 8; ++d) {
                float4 k4 = kp[d];
                s4.x += qv[4*d] * k4.x;
                s4.y += qv[4*d+1] * k4.y;
                s4.z += qv[4*d+2] * k4.z;
                s4.w += qv[4*d+3] * k4.w;
            }
            float part = (s4.x + s4.y) + (s4.z + s4.w);
            float s = part + __shfl_xor(part, 1);
            s = s * 0.125f + bias_s[kk];
            float p = __expf(s);
            l += p;
            const float4* vp = (const float4*)(vbase + (size_t)kk * 2304);
#pragma unroll
            for (int d = 0; d < 8; ++d) {
                float4 v4 = vp[d];
                acc[4*d]   += p * v4.x;
                acc[4*d+1] += p * v4.y;
                acc[4*d+2] += p * v4.z;
                acc[4*d+3] += p * v4.w;
            }
        }
        float inv = __builtin_amdgcn_rcpf(l);
        size_t base = (size_t)(b * TT + q_i) * HH + h * DH_ + dh * 32;
#pragma unroll
        for (int d = 0; d < 16; ++d) {
            u32 pk = (u32)f2bf(acc[2*d] * inv) | ((u32)f2bf(acc[2*d+1] * inv) << 16);
            *(u32*)&ctxb[base + 2*d] = pk;
        }
    }
}

// ---- LN phase: wave per row, barrier-free ----
static __device__ void ln_phase(
    const float* __restrict__ a, const float* __restrict__ f,
    const float* __restrict__ g, const float* __restrict__ b,
    float* __restrict__ out, u16* __restrict__ outb) {
    int row = blockIdx.x * 8 + (threadIdx.x >> 6);   // 2048 rows exactly
    int lane = threadIdx.x & 63;
    const float* ap = a + (size_t)row * HH;
    const float* fp = f + (size_t)row * HH;
    float v[12];
    float s = 0.f;
#pragma unroll
    for (int p = 0; p < 3; ++p) {
        int h = p * 256 + lane * 4;
        float4 av = *(const float4*)&ap[h];
        float4 fv = *(const float4*)&fp[h];
        v[4*p+0] = av.x + fv.x; v[4*p+1] = av.y + fv.y;
        v[4*p+2] = av.z + fv.z; v[4*p+3] = av.w + fv.w;
        s += v[4*p] + v[4*p+1] + v[4*p+2] + v[4*p+3];
    }
#pragma unroll
    for (int o = 32; o > 0; o >>= 1) s += __shfl_xor(s, o);
    float mean = s * (1.0f / HH);
    float vs = 0.f;
#pragma unroll
    for (int i = 0; i < 12; ++i) { float d = v[i] - mean; vs += d * d; }
#pragma unroll
    for (int o = 32; o > 0; o >>= 1) vs += __shfl_xor(vs, o);
    float rstd = rsqrtf(vs * (1.0f / HH) + 1e-12f);
#pragma unroll
    for (int p = 0; p < 3; ++p) {
        int h = p * 256 + lane * 4;
        float4 gv = *(const float4*)&g[h];
        float4 bv = *(const float4*)&b[h];
        float4 o4;
        o4.x = (v[4*p+0] - mean) * rstd * gv.x + bv.x;
        o4.y = (v[4*p+1] - mean) * rstd * gv.y + bv.y;
        o4.z = (v[4*p+2] - mean) * rstd * gv.z + bv.z;
        o4.w = (v[4*p+3] - mean) * rstd * gv.w + bv.w;
        *(float4*)&out[(size_t)row * HH + h] = o4;
        uint2 pk;
        pk.x = (u32)f2bf(o4.x) | ((u32)f2bf(o4.y) << 16);
        pk.y = (u32)f2bf(o4.z) | ((u32)f2bf(o4.w) << 16);
        *(uint2*)&outb[(size_t)row * HH + h] = pk;
    }
}

// ---- conv phase: per-layer weight transpose fp32->bf16 (per half, 64x64 tiles) ----
static __device__ void conv_phase(
    const float* __restrict__ Wq, const float* __restrict__ Wk,
    const float* __restrict__ Wv, const float* __restrict__ Wo,
    const float* __restrict__ Wf1, const float* __restrict__ Wf2,
    u16* __restrict__ wbuf, u8* smem_half, int vb, int tidh) {
    float (*tile)[65] = (float(*)[65])smem_half;     // 16.6 KB
    for (int it = 0; it < 4; ++it) {
        int u = it * 512 + vb;
        bool act = u < 1728;
        int uu = act ? u : 1727;
        const float* src; u16* dst; int R, C, bx, by;
        if (uu < 576) {
            int m = uu / 144, t = uu % 144;
            src = (m == 0 ? Wq : m == 1 ? Wk : m == 2 ? Wv : Wo);
            dst = wbuf + (size_t)m * 589824;
            R = 768; C = 768; bx = t % 12; by = t / 12;
        } else if (uu < 1152) {
            int t = uu - 576;
            src = Wf1; dst = wbuf + 2359296; R = 768; C = 3072;
            bx = t % 48; by = t / 48;
        } else {
            int t = uu - 1152;
            src = Wf2; dst = wbuf + 4718592; R = 3072; C = 768;
            bx = t % 12; by = t / 12;
        }
        int tx = tidh & 15, ty = tidh >> 4;
#pragma unroll
        for (int p = 0; p < 4; ++p) {
            int row = p * 16 + ty;
            float4 v = *(const float4*)&src[(size_t)(by * 64 + row) * C + bx * 64 + tx * 4];
            tile[row][tx * 4 + 0] = v.x; tile[row][tx * 4 + 1] = v.y;
            tile[row][tx * 4 + 2] = v.z; tile[row][tx * 4 + 3] = v.w;
        }
        __syncthreads();
        if (act) {
            int rr = (tidh & 31) * 2, cc0 = tidh >> 5;
#pragma unroll
            for (int p = 0; p < 8; ++p) {
                int cc = p * 8 + cc0;
                u32 pk = (u32)f2bf(tile[rr][cc]) | ((u32)f2bf(tile[rr + 1][cc]) << 16);
                *(u32*)&dst[(size_t)(bx * 64 + cc) * R + by * 64 + rr] = pk;
            }
        }
        __syncthreads();
    }
}

__global__ __launch_bounds__(512, 2) void mega_kernel(
    const u16* __restrict__ x_bf_in, float* __restrict__ x, u16* __restrict__ x_bf,
    float* __restrict__ qkv, float* __restrict__ tmp, float* __restrict__ ab,
    u16* __restrict__ ab_bf, u16* __restrict__ ctx_bf, u16* __restrict__ big_bf,
    u16* __restrict__ wbuf, u16* __restrict__ wihT, float* __restrict__ xg,
    const int* __restrict__ attn_mask,
    const float* __restrict__ Wq, const float* __restrict__ Wk,
    const float* __restrict__ Wv, const float* __restrict__ Wo,
    const float* __restrict__ Wf1, const float* __restrict__ Wf2,
    const float* __restrict__ bq, const float* __restrict__ bk,
    const float* __restrict__ bv, const float* __restrict__ bo,
    const float* __restrict__ ln1_g, const float* __restrict__ ln1_b,
    const float* __restrict__ bf1, const float* __restrict__ bf2,
    const float* __restrict__ ln2_g, const float* __restrict__ ln2_b,
    const float* __restrict__ b_ih_f, const float* __restrict__ b_ih_b,
    unsigned* __restrict__ bar) {
    __shared__ __align__(16) u8 smem[98304];
    int tid = threadIdx.x;
    int half = tid >> 8;
    int tidh = tid & 255;
    int vb = blockIdx.x * 2 + half;
    u8* smem_half = smem + (size_t)half * 49152;
    unsigned* cnt = bar;
    unsigned* gen = bar + 16;   // separate cacheline-ish
    unsigned target = 0;

    for (int l = 0; l < NL; ++l) {
        conv_phase(Wq + (size_t)l * HH * HH, Wk + (size_t)l * HH * HH,
                   Wv + (size_t)l * HH * HH, Wo + (size_t)l * HH * HH,
                   Wf1 + (size_t)l * HH * FF_, Wf2 + (size_t)l * FF_ * HH,
                   wbuf, smem_half, vb, tidh);
        gridbar(cnt, gen, target);
        gemm_phase(x_bf, wbuf, bq + (size_t)l * HH, bk + (size_t)l * HH, bv + (size_t)l * HH,
                   768, qkv, nullptr, 2304, HH, false, false, smem_half, vb, tidh);
        gridbar(cnt, gen, target);
        attn_phase(qkv, attn_mask, ctx_bf, smem_half, vb, tidh);
        gridbar(cnt, gen, target);
        gemm_phase(ctx_bf, wbuf + 1769472, bo + (size_t)l * HH, bo + (size_t)l * HH,
                   bo + (size_t)l * HH, 768, tmp, nullptr, HH, HH, false, false,
                   smem_half, vb, tidh);
        gridbar(cnt, gen, target);
        ln_phase(x, tmp, ln1_g + (size_t)l * HH, ln1_b + (size_t)l * HH, ab, ab_bf);
        gridbar(cnt, gen, target);
        gemm_phase(ab_bf, wbuf + 2359296, bf1 + (size_t)l * FF_, bf1 + (size_t)l * FF_,
                   bf1 + (size_t)l * FF_, FF_, nullptr, big_bf, FF_, HH, true, true,
                   smem_half, vb, tidh);
        gridbar(cnt, gen, target);
        gemm_phase(big_bf, wbuf + 4718592, bf2 + (size_t)l * HH, bf2 + (size_t)l * HH,
                   bf2 + (size_t)l * HH, 768, tmp, nullptr, HH, FF_, false, false,
                   smem_half, vb, tidh);
        gridbar(cnt, gen, target);
        ln_phase(ab, tmp, ln2_g + (size_t)l * HH, ln2_b + (size_t)l * HH, x, x_bf);
        gridbar(cnt, gen, target);
    }
    // xg gemm: N=2048, seg=1024
    gemm_phase(x_bf, wihT, b_ih_f, b_ih_b, b_ih_b, 1024, xg, nullptr, 2048, HH,
               false, false, smem_half, vb, tidh);
    (void)x_bf_in;
}

// ---------------- LSTM v12 (unchanged) ----------------
__global__ __launch_bounds__(1024, 4) void lstm12_kernel(
    const float* __restrict__ xg, const u8* __restrict__ wfrag8,
    const float* __restrict__ bhh_f, const float* __restrict__ bhh_b,
    float* __restrict__ hf, float* __restrict__ hb) {
    int dir = blockIdx.x;
    const u8* wf8 = wfrag8 + (size_t)dir * 262144;
    const float* bhh = dir ? bhh_b : bhh_f;
    float* hout = dir ? hb : hf;
    int tid = threadIdx.x, lane = tid & 63, wid = tid >> 6;
    __shared__ u8 wlds[4 * 64 * 512];
    __shared__ u8 h_f8[16][280];
    __shared__ u16 g_bf[1024][10];
    for (int i = tid; i < 16 * 280; i += 1024) ((u8*)h_f8)[i] = 0;
#pragma unroll
    for (int c = 0; c < 8; ++c) {
        int off = wid * 8192 + c * 1024;
        GLL16(wf8 + off + lane * 16, &wlds[off]);
    }
    int l15 = lane & 15, qq = lane >> 4;
    int j = tid & 255;
    int bq = (tid >> 8) * 2;
    float bi_ = bhh[j], bf_ = bhh[256 + j], bg_ = bhh[512 + j], bo_ = bhh[768 + j];
    float c_s[2] = {0.f, 0.f};
    __syncthreads();
    for (int step = 0; step < TT; ++step) {
        int t = dir ? (TT - 1 - step) : step;
        long wst[4][4];
#pragma unroll
        for (int kt = 0; kt < 4; ++kt)
#pragma unroll
            for (int m = 0; m < 4; ++m)
                wst[kt][m] = *(const long*)&wf8[(size_t)(((4 + kt) * 64) + wid * 4 + m) * 512 + lane * 8];
        float xgi[2], xgf[2], xgg[2], xgo[2];
#pragma unroll
        for (int bi = 0; bi < 2; ++bi) {
            size_t xa = ((size_t)((bq + bi) * TT + t)) * 2048 + (size_t)dir * 1024;
            xgi[bi] = xg[xa + j];
            xgf[bi] = xg[xa + 256 + j];
            xgg[bi] = xg[xa + 512 + j];
            xgo[bi] = xg[xa + 768 + j];
        }
        f32x4 acc[4];
#pragma unroll
        for (int m = 0; m < 4; ++m) acc[m] = (f32x4){0.f, 0.f, 0.f, 0.f};
#pragma unroll
        for (int kt = 0; kt < 4; ++kt) {
            long hfr = *(const long*)&h_f8[l15][kt * 32 + qq * 8];
#pragma unroll
            for (int m = 0; m < 4; ++m) {
                long a = *(const long*)&wlds[(size_t)(kt * 64 + wid * 4 + m) * 512 + lane * 8];
                acc[m] = mfma_fp8(a, hfr, acc[m]);
            }
        }
#pragma unroll
        for (int kt = 0; kt < 4; ++kt) {
            long hfr = *(const long*)&h_f8[l15][(4 + kt) * 32 + qq * 8];
#pragma unroll
            for (int m = 0; m < 4; ++m)
                acc[m] = mfma_fp8(wst[kt][m], hfr, acc[m]);
        }
        if (l15 < 8) {
#pragma unroll
            for (int m = 0; m < 4; ++m) {
                int R = (wid * 4 + m) * 16 + qq * 4;
#pragma unroll
                for (int jj = 0; jj < 4; ++jj)
                    g_bf[R + jj][l15] = (u16)(__float_as_uint(acc[m][jj]) >> 16);
            }
        }
        __syncthreads();
#pragma unroll
        for (int bi = 0; bi < 2; ++bi) {
            int b = bq + bi;
            float gi = xgi[bi] + bi_ + bf2f(g_bf[j][b]);
            float gf = xgf[bi] + bf_ + bf2f(g_bf[256 + j][b]);
            float gg = xgg[bi] + bg_ + bf2f(g_bf[512 + j][b]);
            float go = xgo[bi] + bo_ + bf2f(g_bf[768 + j][b]);
            float cc = sigm_fast(gf) * c_s[bi] + sigm_fast(gi) * tanh_fast(gg);
            c_s[bi] = cc;
            float hh = sigm_fast(go) * tanh_fast(cc);
            int pk = __builtin_amdgcn_cvt_pk_fp8_f32(hh, hh, 0, false);
            h_f8[b][j] = (u8)(pk & 0xff);
            hout[((size_t)(b * TT + t)) * LH_ + j] = hh;
        }
        __syncthreads();
    }
}

// ---------------- classifier ----------------
__global__ __launch_bounds__(256) void clf_kernel(
    const float* __restrict__ hf, const float* __restrict__ hb,
    const float* __restrict__ W, const float* __restrict__ bias, float* __restrict__ em) {
    int idx = blockIdx.x * blockDim.x + threadIdx.x;
    if (idx >= BB * TT * KK_) return;
    int row = idx / KK_, j = idx % KK_;
    float acc = bias[j];
    const float* hfp = hf + (size_t)row * LH_;
    const float* hbp = hb + (size_t)row * LH_;
    for (int kk = 0; kk < LH_; ++kk) acc += hfp[kk] * W[kk * KK_ + j];
    for (int kk = 0; kk < LH_; ++kk) acc += hbp[kk] * W[(LH_ + kk) * KK_ + j];
    em[idx] = acc;
}

// ---------------- CRF v2 ----------------
__global__ __launch_bounds__(512) void crf2_kernel(
    const float* __restrict__ em, const int* __restrict__ labels, const int* __restrict__ mask,
    const float* __restrict__ cstart, const float* __restrict__ cend,
    const float* __restrict__ ctrans, float* __restrict__ out) {
    __shared__ float trans_s[81];
    __shared__ float res[8];
    int tid = threadIdx.x;
    int b = tid >> 6;
    int l = tid & 63;
    if (tid < 81) trans_s[tid] = ctrans[tid];
    __syncthreads();
    int lc = (l < 9) ? l : 0;
    float tcol[9];
#pragma unroll
    for (int i = 0; i < 9; ++i) tcol[i] = trans_s[i * 9 + lc];
    float alpha = (l < 9) ? cstart[lc] + em[(size_t)b * TT * KK_ + lc] : -1e30f;
    for (int t = 1; t < TT; ++t) {
        float e_t = (l < 9) ? em[((size_t)b * TT + t) * KK_ + lc] : 0.f;
        float m = -1e30f;
        float av[9];
#pragma unroll
        for (int i = 0; i < 9; ++i) {
            av[i] = __shfl(alpha, i) + tcol[i];
            m = fmaxf(m, av[i]);
        }
        float s = 0.f;
#pragma unroll
        for (int i = 0; i < 9; ++i) s += expf(av[i] - m);
        float nv = m + logf(s) + e_t;
        bool upd = (mask[b * TT + t] > 0) && (l < 9);
        alpha = upd ? nv : alpha;
    }
    float z = (l < 9) ? alpha + cend[lc] : -1e30f;
    float zm = z;
#pragma unroll
    for (int o = 32; o > 0; o >>= 1) zm = fmaxf(zm, __shfl_xor(zm, o));
    float zs = (l < 9) ? expf(z - zm) : 0.f;
#pragma unroll
    for (int o = 32; o > 0; o >>= 1) zs += __shfl_xor(zs, o);
    float logZ = zm + logf(zs);
    float sc = 0.f;
    int cnt = 0;
    for (int t = l; t < TT; t += 64) {
        cnt += mask[b * TT + t];
        if (t == 0) {
            int l0 = labels[b * TT];
            sc += cstart[l0] + em[(size_t)b * TT * KK_ + l0];
        } else {
            int lp = labels[b * TT + t - 1];
            int lt = labels[b * TT + t];
            sc += (trans_s[lp * KK_ + lt] + em[((size_t)b * TT + t) * KK_ + lt]) *
                  (float)mask[b * TT + t];
        }
    }
#pragma unroll
    for (int o = 32; o > 0; o >>= 1) { sc += __shfl_xor(sc, o); cnt += __shfl_xor(cnt, o); }
    if (l == 0) {
        int last = labels[b * TT + (cnt - 1)];
        sc += cend[last];
        res[b] = sc - logZ;
    }
    __syncthreads();
    if (tid == 0) {
        float acc = 0.f;
        for (int bb = 0; bb < BB; ++bb) acc += res[bb];
        out[0] = -acc / (float)BB;
    }
}

extern "C" void kernel_launch(void* const* d_in, const int* in_sizes, int n_in,
                              void* d_out, int out_size, void* d_ws, size_t ws_size,
                              hipStream_t stream) {
    const int* input_ids = (const int*)d_in[0];
    const int* attn_mask = (const int*)d_in[1];
    const int* labels    = (const int*)d_in[2];
    const float* word_emb = (const float*)d_in[3];
    const float* pos_emb  = (const float*)d_in[4];
    const float* type_emb = (const float*)d_in[5];
    const float* emb_ln_g = (const float*)d_in[6];
    const float* emb_ln_b = (const float*)d_in[7];
    const float* Wq = (const float*)d_in[8];
    const float* bq = (const float*)d_in[9];
    const float* Wk = (const float*)d_in[10];
    const float* bk = (const float*)d_in[11];
    const float* Wv = (const float*)d_in[12];
    const float* bv = (const float*)d_in[13];
    const float* Wo = (const float*)d_in[14];
    const float* bo = (const float*)d_in[15];
    const float* ln1_g = (const float*)d_in[16];
    const float* ln1_b = (const float*)d_in[17];
    const float* Wf1 = (const float*)d_in[18];
    const float* bf1 = (const float*)d_in[19];
    const float* Wf2 = (const float*)d_in[20];
    const float* bf2 = (const float*)d_in[21];
    const float* ln2_g = (const float*)d_in[22];
    const float* ln2_b = (const float*)d_in[23];
    const float* w_ih_f = (const float*)d_in[24];
    const float* w_hh_f = (const float*)d_in[25];
    const float* b_ih_f = (const float*)d_in[26];
    const float* b_hh_f = (const float*)d_in[27];
    const float* w_ih_b = (const float*)d_in[28];
    const float* w_hh_b = (const float*)d_in[29];
    const float* b_ih_b = (const float*)d_in[30];
    const float* b_hh_b = (const float*)d_in[31];
    const float* W_clf  = (const float*)d_in[32];
    const float* b_clf  = (const float*)d_in[33];
    const float* crf_start = (const float*)d_in[34];
    const float* crf_end   = (const float*)d_in[35];
    const float* crf_trans = (const float*)d_in[36];

    const size_t NTOK = (size_t)BB * TT;          // 2048
    const size_t SZ = NTOK * HH;                  // 1,572,864

    float* ws = (float*)d_ws;
    float* x    = ws;                              // SZ
    float* qkv  = x + SZ;                          // 2048*2304
    float* tmp  = qkv + NTOK * 2304;               // SZ
    float* ab   = tmp + SZ;                        // SZ
    float* xg   = ab + SZ;                         // 2048*2048
    u16* x_bf   = (u16*)(xg + NTOK * 2048);        // SZ u16
    u16* ab_bf  = x_bf + SZ;
    u16* ctx_bf = ab_bf + SZ;
    u16* big_bf = ctx_bf + SZ;                     // 2048*3072
    u16* wbuf   = big_bf + NTOK * (size_t)FF_;     // 7,077,888
    u16* wihT   = wbuf + 7077888;                  // 2048*768
    u8*  wfrag8 = (u8*)(wihT + 1572864);           // 524,288 bytes
    unsigned* bar = (unsigned*)(wfrag8 + 524288);  // 256 bytes barrier state
    float* hf = qkv;
    float* hb = qkv + 524288;
    float* em = qkv + 1048576;

    hipMemsetAsync(bar, 0, 256, stream);

    embed_ln_kernel<<<NTOK / 8, 512, 0, stream>>>(input_ids, word_emb, pos_emb, type_emb,
                                                  emb_ln_g, emb_ln_b, x, x_bf);
    prep_kernel<<<1792, 256, 0, stream>>>(w_hh_f, w_hh_b, w_ih_f, w_ih_b, wfrag8, wihT);

    mega_kernel<<<NBLK, 512, 0, stream>>>(
        x_bf, x, x_bf, qkv, tmp, ab, ab_bf, ctx_bf, big_bf, wbuf, wihT, xg, attn_mask,
        Wq, Wk, Wv, Wo, Wf1, Wf2, bq, bk, bv, bo, ln1_g, ln1_b, bf1, bf2, ln2_g, ln2_b,
        b_ih_f, b_ih_b, bar);

    lstm12_kernel<<<2, 1024, 0, stream>>>(xg, wfrag8, b_hh_f, b_hh_b, hf, hb);
    clf_kernel<<<(BB * TT * KK_ + 255) / 256, 256, 0, stream>>>(hf, hb, W_clf, b_clf, em);
    crf2_kernel<<<1, 512, 0, stream>>>(em, labels, attn_mask, crf_start, crf_end, crf_trans,
                                       (float*)d_out);
}

// Round 14
// 5552.336 us; speedup vs baseline: 3.9418x; 3.9418x over previous
//
#include <hip/hip_runtime.h>
#include <math.h>

#define BB 8
#define TT 256
#define HH 768
#define NL 12
#define NH_ 12
#define DH_ 64
#define FF_ 3072
#define LH_ 256
#define KK_ 9

typedef unsigned char u8;
typedef unsigned short u16;
typedef unsigned int u32;
typedef __attribute__((ext_vector_type(8))) short bf16x8;
typedef __attribute__((ext_vector_type(4))) float f32x4;

static __device__ __forceinline__ float sigm_fast(float x) {
    return __builtin_amdgcn_rcpf(1.0f + __expf(-x));
}
static __device__ __forceinline__ float tanh_fast(float x) {
    return 1.0f - 2.0f * __builtin_amdgcn_rcpf(1.0f + __expf(2.0f * x));
}

static __device__ __forceinline__ u16 f2bf(float f) {
    u32 u = __float_as_uint(f);
    u += 0x7fffu + ((u >> 16) & 1u);
    return (u16)(u >> 16);
}
static __device__ __forceinline__ float bf2f(u16 v) {
    return __uint_as_float(((u32)v) << 16);
}

// float -> OCP e4m3fn, RNE (prep path only)
static __device__ __forceinline__ u8 f2e4m3(float x) {
    float a = fabsf(x);
    u8 s = (u8)((__float_as_uint(x) >> 31) << 7);
    if (!(a > 0.001953125f)) {
        int m = (int)rintf(a * 512.0f);
        return s | (u8)m;
    }
    if (a >= 448.0f) return s | 0x7E;
    int e; float fr = frexpf(a, &e);
    int E = e - 1;
    if (E < -6) {
        int m = (int)rintf(a * 512.0f);
        if (m >= 8) return s | 0x08;
        return s | (u8)m;
    }
    int m = (int)rintf((fr * 2.0f - 1.0f) * 8.0f);
    if (m == 8) { E += 1; m = 0; if (E > 8) return s | 0x7E; }
    return s | (u8)((E + 7) << 3) | (u8)m;
}

static __device__ __forceinline__ f32x4 mfma_fp8(long a, long b, f32x4 c) {
    return __builtin_amdgcn_mfma_f32_16x16x32_fp8_fp8(a, b, c, 0, 0, 0);
}

#define GLL16(gp, lp) __builtin_amdgcn_global_load_lds( \
    (const __attribute__((address_space(1))) void*)(gp), \
    (__attribute__((address_space(3))) void*)(lp), 16, 0, 0)

// ---------------- block reduce ----------------
static __device__ __forceinline__ float block_sum(float v, float* red) {
    int tid = threadIdx.x;
#pragma unroll
    for (int o = 32; o > 0; o >>= 1) v += __shfl_xor(v, o);
    if ((tid & 63) == 0) red[tid >> 6] = v;
    __syncthreads();
    return red[0] + red[1] + red[2] + red[3];
}

// ---------------- embedding + LN ----------------
__global__ __launch_bounds__(256) void embed_ln_kernel(
    const int* __restrict__ ids, const float* __restrict__ we, const float* __restrict__ pe,
    const float* __restrict__ te, const float* __restrict__ g, const float* __restrict__ b,
    float* __restrict__ out, u16* __restrict__ outb) {
    int row = blockIdx.x;
    int t = row % TT;
    int id = ids[row];
    __shared__ float xr[HH];
    __shared__ float reda[8], redb[8];
    int tid = threadIdx.x;
    float s = 0.f;
    for (int h = tid; h < HH; h += 256) {
        float v = we[(size_t)id * HH + h] + pe[(size_t)t * HH + h] + te[h];
        xr[h] = v; s += v;
    }
    float mean = block_sum(s, reda) * (1.0f / HH);
    float vs = 0.f;
    for (int h = tid; h < HH; h += 256) { float d = xr[h] - mean; vs += d * d; }
    float var = block_sum(vs, redb) * (1.0f / HH);
    float rstd = rsqrtf(var + 1e-12f);
    for (int h = tid; h < HH; h += 256) {
        float v = (xr[h] - mean) * rstd * g[h] + b[h];
        out[(size_t)row * HH + h] = v;
        outb[(size_t)row * HH + h] = f2bf(v);
    }
}

// ---------------- LN(a + f) -> fp32 + bf16 ----------------
__global__ __launch_bounds__(256) void ln_residual_kernel(
    const float* __restrict__ a, const float* __restrict__ f,
    const float* __restrict__ g, const float* __restrict__ b,
    float* __restrict__ out, u16* __restrict__ outb) {
    int row = blockIdx.x;
    __shared__ float xr[HH];
    __shared__ float reda[8], redb[8];
    int tid = threadIdx.x;
    float s = 0.f;
    for (int h = tid; h < HH; h += 256) {
        float v = a[(size_t)row * HH + h] + f[(size_t)row * HH + h];
        xr[h] = v; s += v;
    }
    float mean = block_sum(s, reda) * (1.0f / HH);
    float vs = 0.f;
    for (int h = tid; h < HH; h += 256) { float d = xr[h] - mean; vs += d * d; }
    float var = block_sum(vs, redb) * (1.0f / HH);
    float rstd = rsqrtf(var + 1e-12f);
    for (int h = tid; h < HH; h += 256) {
        float v = (xr[h] - mean) * rstd * g[h] + b[h];
        out[(size_t)row * HH + h] = v;
        outb[(size_t)row * HH + h] = f2bf(v);
    }
}

// ---------------- weight transpose+convert, all 12 layers in one grid ----------------
// LAYERS12: grid = 1728 * 12 blocks, layer = bid / 1728. Otherwise per-layer (1728).
template <bool LAYERS12>
__global__ __launch_bounds__(256) void conv_w_kernel(
    const float* __restrict__ Wq, const float* __restrict__ Wk,
    const float* __restrict__ Wv, const float* __restrict__ Wo,
    const float* __restrict__ Wf1, const float* __restrict__ Wf2,
    u16* __restrict__ wbuf) {
    __shared__ float tile[64][65];
    int bid = blockIdx.x;
    int layer = 0;
    if (LAYERS12) { layer = bid / 1728; bid -= layer * 1728; }
    size_t woff = (size_t)layer * 7077888;
    size_t hh2 = (size_t)layer * HH * HH;
    size_t hf2 = (size_t)layer * HH * FF_;
    const float* src; u16* dst; int R, C, bx, by;
    if (bid < 576) {
        int m = bid / 144, t = bid % 144;
        src = (m == 0 ? Wq + hh2 : m == 1 ? Wk + hh2 : m == 2 ? Wv + hh2 : Wo + hh2);
        dst = wbuf + woff + (size_t)m * 589824;
        R = 768; C = 768; bx = t % 12; by = t / 12;
    } else if (bid < 1152) {
        int t = bid - 576;
        src = Wf1 + hf2; dst = wbuf + woff + 2359296; R = 768; C = 3072;
        bx = t % 48; by = t / 48;
    } else {
        int t = bid - 1152;
        src = Wf2 + hf2; dst = wbuf + woff + 4718592; R = 3072; C = 768;
        bx = t % 12; by = t / 12;
    }
    int tx = threadIdx.x & 15, ty = threadIdx.x >> 4;   // 16 x 16
#pragma unroll
    for (int p = 0; p < 4; ++p) {
        int row = p * 16 + ty;
        float4 v = *(const float4*)&src[(size_t)(by * 64 + row) * C + bx * 64 + tx * 4];
        tile[row][tx * 4 + 0] = v.x; tile[row][tx * 4 + 1] = v.y;
        tile[row][tx * 4 + 2] = v.z; tile[row][tx * 4 + 3] = v.w;
    }
    __syncthreads();
    int rr = (threadIdx.x & 31) * 2, cc0 = threadIdx.x >> 5;   // 8 cols/pass
#pragma unroll
    for (int p = 0; p < 8; ++p) {
        int cc = p * 8 + cc0;
        u32 pk = (u32)f2bf(tile[rr][cc]) | ((u32)f2bf(tile[rr + 1][cc]) << 16);
        *(u32*)&dst[(size_t)(bx * 64 + cc) * R + by * 64 + rr] = pk;
    }
}

// ---------------- merged prologue: pack w_hh fp8 frags + convert w_ih ----------------
__global__ __launch_bounds__(256) void prep_kernel(
    const float* __restrict__ whf, const float* __restrict__ whb,
    const float* __restrict__ wif, const float* __restrict__ wib,
    u8* __restrict__ wfrag8, u16* __restrict__ wihT) {
    int bid = blockIdx.x;
    int tid = threadIdx.x;
    if (bid < 256) {
        int idx = bid * 256 + tid;
        int dir = idx >> 15;
        int kt  = (idx >> 12) & 7;
        int mt  = (idx >> 6) & 63;
        int lane = idx & 63;
        const float* W = dir ? whb : whf;
        int row = mt * 16 + (lane & 15);
        int k = kt * 32 + (lane >> 4) * 8;
        const float* src = W + (size_t)row * LH_ + k;
        u8 o[8];
#pragma unroll
        for (int j = 0; j < 8; ++j) o[j] = f2e4m3(src[j]);
        uint2 pk;
        pk.x = (u32)o[0] | ((u32)o[1] << 8) | ((u32)o[2] << 16) | ((u32)o[3] << 24);
        pk.y = (u32)o[4] | ((u32)o[5] << 8) | ((u32)o[6] << 16) | ((u32)o[7] << 24);
        size_t base = (size_t)(((dir * 8 + kt) * 64 + mt) * 64 + lane) * 8;
        *(uint2*)&wfrag8[base] = pk;
    } else {
        int which = (bid < 1024) ? 0 : 1;
        const float* src = which ? wib : wif;
        u16* dst = wihT + (size_t)which * 786432;
        int i = (bid - (which ? 1024 : 256)) * 256 + tid;
        float4 v = *(const float4*)&src[(size_t)i * 4];
        uint2 o;
        o.x = (u32)f2bf(v.x) | ((u32)f2bf(v.y) << 16);
        o.y = (u32)f2bf(v.z) | ((u32)f2bf(v.w) << 16);
        *(uint2*)&dst[(size_t)i * 4] = o;
    }
}

// ---------------- GEMM v2: swizzled LDS + 2-phase double buffer ----------------
template <int BROWS>
__device__ __forceinline__ void stage_rows(
    const u16* __restrict__ S, int r0, int K, int k0, u16 (*lds)[64], int w, int lane) {
    int srow = lane >> 3;
    int sgrp = ((lane & 7) ^ srow) * 8;
#pragma unroll
    for (int i = 0; i < BROWS / 32; ++i) {
        int c = w * (BROWS / 32) + i;
        GLL16(S + (size_t)(r0 + 8 * c + srow) * K + k0 + sgrp, &lds[8 * c][0]);
    }
}

template <int BN, bool GELU, bool OUTBF>
__global__ __launch_bounds__(256) void gemm2_kernel(
    const u16* __restrict__ A, const u16* __restrict__ BT,
    const float* __restrict__ b0, const float* __restrict__ b1, const float* __restrict__ b2,
    int seg, float* __restrict__ C, u16* __restrict__ Cbf, int M, int N, int K) {
    __shared__ u16 Als[2][128][64];
    __shared__ u16 Bls[2][BN][64];
    int tid = threadIdx.x, lane = tid & 63, w = tid >> 6;
    int m0 = blockIdx.y * 128, n0 = blockIdx.x * BN;
    int wr = w >> 1, wc = w & 1;
    int l15 = lane & 15, q = lane >> 4;
    constexpr int NJ = BN / 32;

    f32x4 acc[4][NJ];
#pragma unroll
    for (int mi = 0; mi < 4; ++mi)
#pragma unroll
        for (int nj = 0; nj < NJ; ++nj) acc[mi][nj] = (f32x4){0.f, 0.f, 0.f, 0.f};

    stage_rows<128>(A, m0, K, 0, Als[0], w, lane);
    stage_rows<BN>(BT, n0, K, 0, Bls[0], w, lane);
    __syncthreads();
    int KT = K >> 6, cur = 0;
    for (int kt = 0; kt < KT; ++kt) {
        if (kt + 1 < KT) {
            stage_rows<128>(A, m0, K, (kt + 1) << 6, Als[cur ^ 1], w, lane);
            stage_rows<BN>(BT, n0, K, (kt + 1) << 6, Bls[cur ^ 1], w, lane);
        }
#pragma unroll
        for (int ks = 0; ks < 2; ++ks) {
            int g8 = (((ks * 4 + q) ^ (l15 & 7)) * 8);
            bf16x8 bfr[NJ];
#pragma unroll
            for (int nj = 0; nj < NJ; ++nj)
                bfr[nj] = *(const bf16x8*)&Bls[cur][wc * (BN / 2) + nj * 16 + l15][g8];
#pragma unroll
            for (int mi = 0; mi < 4; ++mi) {
                bf16x8 a = *(const bf16x8*)&Als[cur][wr * 64 + mi * 16 + l15][g8];
#pragma unroll
                for (int nj = 0; nj < NJ; ++nj)
                    acc[mi][nj] = __builtin_amdgcn_mfma_f32_16x16x32_bf16(a, bfr[nj], acc[mi][nj], 0, 0, 0);
            }
        }
        __syncthreads();
        cur ^= 1;
    }

    int rbase = m0 + wr * 64 + q * 4;
    int cbase = n0 + wc * (BN / 2) + l15;
#pragma unroll
    for (int mi = 0; mi < 4; ++mi) {
#pragma unroll
        for (int nj = 0; nj < NJ; ++nj) {
            int col = cbase + nj * 16;
            int cc = col;
            const float* bp;
            if (cc < seg) bp = b0;
            else if (cc < 2 * seg) { bp = b1; cc -= seg; }
            else { bp = b2; cc -= 2 * seg; }
            float bias = bp[cc];
#pragma unroll
            for (int j = 0; j < 4; ++j) {
                int row = rbase + mi * 16 + j;
                float v = acc[mi][nj][j] + bias;
                if (GELU) v = 0.5f * v * (1.0f + erff(v * 0.70710678118654752f));
                if (OUTBF) Cbf[(size_t)row * N + col] = f2bf(v);
                else       C[(size_t)row * N + col] = v;
            }
        }
    }
}

// ---------------- attention v3: (b,h,qquarter) blocks, thread = (qrow, 16-dim quarter) ----------------
__global__ __launch_bounds__(256) void attention_kernel(
    const float* __restrict__ qkv, const int* __restrict__ mask, u16* __restrict__ ctxb) {
    int bid = blockIdx.x;
    int quarter = bid & 3;
    int bh = bid >> 2;
    int b = bh / NH_, h = bh % NH_;
    int tid = threadIdx.x;
    int q_i = quarter * 64 + (tid >> 2);
    int dq = tid & 3;
    const float* qp = qkv + (size_t)(b * TT + q_i) * 2304 + h * DH_ + dq * 16;
    float qv[16];
#pragma unroll
    for (int d = 0; d < 4; ++d) {
        float4 v = *(const float4*)(qp + 4 * d);
        qv[4*d] = v.x; qv[4*d+1] = v.y; qv[4*d+2] = v.z; qv[4*d+3] = v.w;
    }
    const float* kbase = qkv + (size_t)b * TT * 2304 + 768 + h * DH_ + dq * 16;
    const float* vbase = qkv + (size_t)b * TT * 2304 + 1536 + h * DH_ + dq * 16;
    __shared__ float bias_s[TT];
    for (int i = tid; i < TT; i += 256)
        bias_s[i] = (1.0f - (float)mask[b * TT + i]) * -10000.0f;
    __syncthreads();
    float acc[16] = {};
    float l = 0.f;
    for (int kk = 0; kk < TT; ++kk) {
        const float4* kp = (const float4*)(kbase + (size_t)kk * 2304);
        float4 s4 = {0.f, 0.f, 0.f, 0.f};
#pragma unroll
        for (int d = 0; d < 4; ++d) {
            float4 k4 = kp[d];
            s4.x += qv[4*d] * k4.x;
            s4.y += qv[4*d+1] * k4.y;
            s4.z += qv[4*d+2] * k4.z;
            s4.w += qv[4*d+3] * k4.w;
        }
        float part = (s4.x + s4.y) + (s4.z + s4.w);
        part += __shfl_xor(part, 1);
        part += __shfl_xor(part, 2);
        float s = part * 0.125f + bias_s[kk];
        float p = __expf(s);
        l += p;
        const float4* vp = (const float4*)(vbase + (size_t)kk * 2304);
#pragma unroll
        for (int d = 0; d < 4; ++d) {
            float4 v4 = vp[d];
            acc[4*d]   += p * v4.x;
            acc[4*d+1] += p * v4.y;
            acc[4*d+2] += p * v4.z;
            acc[4*d+3] += p * v4.w;
        }
    }
    float inv = __builtin_amdgcn_rcpf(l);
    size_t base = (size_t)(b * TT + q_i) * HH + h * DH_ + dq * 16;
#pragma unroll
    for (int d = 0; d < 8; ++d) {
        u32 pk = (u32)f2bf(acc[2*d] * inv) | ((u32)f2bf(acc[2*d+1] * inv) << 16);
        *(u32*)&ctxb[base + 2*d] = pk;
    }
}

// ---------------- LSTM v12 ----------------
__global__ __launch_bounds__(1024, 4) void lstm12_kernel(
    const float* __restrict__ xg, const u8* __restrict__ wfrag8,
    const float* __restrict__ bhh_f, const float* __restrict__ bhh_b,
    float* __restrict__ hf, float* __restrict__ hb) {
    int dir = blockIdx.x;
    const u8* wf8 = wfrag8 + (size_t)dir * 262144;
    const float* bhh = dir ? bhh_b : bhh_f;
    float* hout = dir ? hb : hf;
    int tid = threadIdx.x, lane = tid & 63, wid = tid >> 6;
    __shared__ u8 wlds[4 * 64 * 512];
    __shared__ u8 h_f8[16][280];
    __shared__ u16 g_bf[1024][10];
    for (int i = tid; i < 16 * 280; i += 1024) ((u8*)h_f8)[i] = 0;
#pragma unroll
    for (int c = 0; c < 8; ++c) {
        int off = wid * 8192 + c * 1024;
        GLL16(wf8 + off + lane * 16, &wlds[off]);
    }
    int l15 = lane & 15, qq = lane >> 4;
    int j = tid & 255;
    int bq = (tid >> 8) * 2;
    float bi_ = bhh[j], bf_ = bhh[256 + j], bg_ = bhh[512 + j], bo_ = bhh[768 + j];
    float c_s[2] = {0.f, 0.f};
    __syncthreads();
    for (int step = 0; step < TT; ++step) {
        int t = dir ? (TT - 1 - step) : step;
        long wst[4][4];
#pragma unroll
        for (int kt = 0; kt < 4; ++kt)
#pragma unroll
            for (int m = 0; m < 4; ++m)
                wst[kt][m] = *(const long*)&wf8[(size_t)(((4 + kt) * 64) + wid * 4 + m) * 512 + lane * 8];
        float xgi[2], xgf[2], xgg[2], xgo[2];
#pragma unroll
        for (int bi = 0; bi < 2; ++bi) {
            size_t xa = ((size_t)((bq + bi) * TT + t)) * 2048 + (size_t)dir * 1024;
            xgi[bi] = xg[xa + j];
            xgf[bi] = xg[xa + 256 + j];
            xgg[bi] = xg[xa + 512 + j];
            xgo[bi] = xg[xa + 768 + j];
        }
        f32x4 acc[4];
#pragma unroll
        for (int m = 0; m < 4; ++m) acc[m] = (f32x4){0.f, 0.f, 0.f, 0.f};
#pragma unroll
        for (int kt = 0; kt < 4; ++kt) {
            long hfr = *(const long*)&h_f8[l15][kt * 32 + qq * 8];
#pragma unroll
            for (int m = 0; m < 4; ++m) {
                long a = *(const long*)&wlds[(size_t)(kt * 64 + wid * 4 + m) * 512 + lane * 8];
                acc[m] = mfma_fp8(a, hfr, acc[m]);
            }
        }
#pragma unroll
        for (int kt = 0; kt < 4; ++kt) {
            long hfr = *(const long*)&h_f8[l15][(4 + kt) * 32 + qq * 8];
#pragma unroll
            for (int m = 0; m < 4; ++m)
                acc[m] = mfma_fp8(wst[kt][m], hfr, acc[m]);
        }
        if (l15 < 8) {
#pragma unroll
            for (int m = 0; m < 4; ++m) {
                int R = (wid * 4 + m) * 16 + qq * 4;
#pragma unroll
                for (int jj = 0; jj < 4; ++jj)
                    g_bf[R + jj][l15] = (u16)(__float_as_uint(acc[m][jj]) >> 16);
            }
        }
        __syncthreads();
#pragma unroll
        for (int bi = 0; bi < 2; ++bi) {
            int b = bq + bi;
            float gi = xgi[bi] + bi_ + bf2f(g_bf[j][b]);
            float gf = xgf[bi] + bf_ + bf2f(g_bf[256 + j][b]);
            float gg = xgg[bi] + bg_ + bf2f(g_bf[512 + j][b]);
            float go = xgo[bi] + bo_ + bf2f(g_bf[768 + j][b]);
            float cc = sigm_fast(gf) * c_s[bi] + sigm_fast(gi) * tanh_fast(gg);
            c_s[bi] = cc;
            float hh = sigm_fast(go) * tanh_fast(cc);
            int pk = __builtin_amdgcn_cvt_pk_fp8_f32(hh, hh, 0, false);
            h_f8[b][j] = (u8)(pk & 0xff);
            hout[((size_t)(b * TT + t)) * LH_ + j] = hh;
        }
        __syncthreads();
    }
}

// ---------------- classifier ----------------
__global__ __launch_bounds__(256) void clf_kernel(
    const float* __restrict__ hf, const float* __restrict__ hb,
    const float* __restrict__ W, const float* __restrict__ bias, float* __restrict__ em) {
    int idx = blockIdx.x * blockDim.x + threadIdx.x;
    if (idx >= BB * TT * KK_) return;
    int row = idx / KK_, j = idx % KK_;
    float acc = bias[j];
    const float* hfp = hf + (size_t)row * LH_;
    const float* hbp = hb + (size_t)row * LH_;
    for (int kk = 0; kk < LH_; ++kk) acc += hfp[kk] * W[kk * KK_ + j];
    for (int kk = 0; kk < LH_; ++kk) acc += hbp[kk] * W[(LH_ + kk) * KK_ + j];
    em[idx] = acc;
}

// ---------------- CRF v2 ----------------
__global__ __launch_bounds__(512) void crf2_kernel(
    const float* __restrict__ em, const int* __restrict__ labels, const int* __restrict__ mask,
    const float* __restrict__ cstart, const float* __restrict__ cend,
    const float* __restrict__ ctrans, float* __restrict__ out) {
    __shared__ float trans_s[81];
    __shared__ float res[8];
    int tid = threadIdx.x;
    int b = tid >> 6;
    int l = tid & 63;
    if (tid < 81) trans_s[tid] = ctrans[tid];
    __syncthreads();
    int lc = (l < 9) ? l : 0;
    float tcol[9];
#pragma unroll
    for (int i = 0; i < 9; ++i) tcol[i] = trans_s[i * 9 + lc];
    float alpha = (l < 9) ? cstart[lc] + em[(size_t)b * TT * KK_ + lc] : -1e30f;
    for (int t = 1; t < TT; ++t) {
        float e_t = (l < 9) ? em[((size_t)b * TT + t) * KK_ + lc] : 0.f;
        float m = -1e30f;
        float av[9];
#pragma unroll
        for (int i = 0; i < 9; ++i) {
            av[i] = __shfl(alpha, i) + tcol[i];
            m = fmaxf(m, av[i]);
        }
        float s = 0.f;
#pragma unroll
        for (int i = 0; i < 9; ++i) s += expf(av[i] - m);
        float nv = m + logf(s) + e_t;
        bool upd = (mask[b * TT + t] > 0) && (l < 9);
        alpha = upd ? nv : alpha;
    }
    float z = (l < 9) ? alpha + cend[lc] : -1e30f;
    float zm = z;
#pragma unroll
    for (int o = 32; o > 0; o >>= 1) zm = fmaxf(zm, __shfl_xor(zm, o));
    float zs = (l < 9) ? expf(z - zm) : 0.f;
#pragma unroll
    for (int o = 32; o > 0; o >>= 1) zs += __shfl_xor(zs, o);
    float logZ = zm + logf(zs);
    float sc = 0.f;
    int cnt = 0;
    for (int t = l; t < TT; t += 64) {
        cnt += mask[b * TT + t];
        if (t == 0) {
            int l0 = labels[b * TT];
            sc += cstart[l0] + em[(size_t)b * TT * KK_ + l0];
        } else {
            int lp = labels[b * TT + t - 1];
            int lt = labels[b * TT + t];
            sc += (trans_s[lp * KK_ + lt] + em[((size_t)b * TT + t) * KK_ + lt]) *
                  (float)mask[b * TT + t];
        }
    }
#pragma unroll
    for (int o = 32; o > 0; o >>= 1) { sc += __shfl_xor(sc, o); cnt += __shfl_xor(cnt, o); }
    if (l == 0) {
        int last = labels[b * TT + (cnt - 1)];
        sc += cend[last];
        res[b] = sc - logZ;
    }
    __syncthreads();
    if (tid == 0) {
        float acc = 0.f;
        for (int bb = 0; bb < BB; ++bb) acc += res[bb];
        out[0] = -acc / (float)BB;
    }
}

extern "C" void kernel_launch(void* const* d_in, const int* in_sizes, int n_in,
                              void* d_out, int out_size, void* d_ws, size_t ws_size,
                              hipStream_t stream) {
    const int* input_ids = (const int*)d_in[0];
    const int* attn_mask = (const int*)d_in[1];
    const int* labels    = (const int*)d_in[2];
    const float* word_emb = (const float*)d_in[3];
    const float* pos_emb  = (const float*)d_in[4];
    const float* type_emb = (const float*)d_in[5];
    const float* emb_ln_g = (const float*)d_in[6];
    const float* emb_ln_b = (const float*)d_in[7];
    const float* Wq = (const float*)d_in[8];
    const float* bq = (const float*)d_in[9];
    const float* Wk = (const float*)d_in[10];
    const float* bk = (const float*)d_in[11];
    const float* Wv = (const float*)d_in[12];
    const float* bv = (const float*)d_in[13];
    const float* Wo = (const float*)d_in[14];
    const float* bo = (const float*)d_in[15];
    const float* ln1_g = (const float*)d_in[16];
    const float* ln1_b = (const float*)d_in[17];
    const float* Wf1 = (const float*)d_in[18];
    const float* bf1 = (const float*)d_in[19];
    const float* Wf2 = (const float*)d_in[20];
    const float* bf2 = (const float*)d_in[21];
    const float* ln2_g = (const float*)d_in[22];
    const float* ln2_b = (const float*)d_in[23];
    const float* w_ih_f = (const float*)d_in[24];
    const float* w_hh_f = (const float*)d_in[25];
    const float* b_ih_f = (const float*)d_in[26];
    const float* b_hh_f = (const float*)d_in[27];
    const float* w_ih_b = (const float*)d_in[28];
    const float* w_hh_b = (const float*)d_in[29];
    const float* b_ih_b = (const float*)d_in[30];
    const float* b_hh_b = (const float*)d_in[31];
    const float* W_clf  = (const float*)d_in[32];
    const float* b_clf  = (const float*)d_in[33];
    const float* crf_start = (const float*)d_in[34];
    const float* crf_end   = (const float*)d_in[35];
    const float* crf_trans = (const float*)d_in[36];

    const size_t NTOK = (size_t)BB * TT;          // 2048
    const size_t SZ = NTOK * HH;                  // 1,572,864

    float* ws = (float*)d_ws;
    float* x    = ws;                              // SZ
    float* qkv  = x + SZ;                          // 2048*2304
    float* tmp  = qkv + NTOK * 2304;               // SZ
    float* ab   = tmp + SZ;                        // SZ
    float* xg   = ab + SZ;                         // 2048*2048
    u16* x_bf   = (u16*)(xg + NTOK * 2048);        // SZ u16
    u16* ab_bf  = x_bf + SZ;
    u16* ctx_bf = ab_bf + SZ;
    u16* big_bf = ctx_bf + SZ;                     // 2048*3072
    u16* wihT   = big_bf + NTOK * (size_t)FF_;     // 2048*768
    u8*  wfrag8 = (u8*)(wihT + 1572864);           // 524,288 bytes
    u16* wbuf   = (u16*)(wfrag8 + 524288);         // per-layer 7,077,888 or x12
    // bytes used before wbuf:
    //   floats: (1.5M+4.7M+1.5M+1.5M+4.2M)*4 = 54.5 MB
    //   u16: (1.5M*3 + 6.3M + 1.5M)*2 = 25.2 MB ; wfrag8 0.5 MB  => ~80.2 MB
    const size_t base_bytes = 80216064ull + 1024;
    bool big = ws_size >= base_bytes + 12ull * 7077888ull * 2ull + (1u << 20);

    float* hf = qkv;
    float* hb = qkv + 524288;
    float* em = qkv + 1048576;

    embed_ln_kernel<<<NTOK, 256, 0, stream>>>(input_ids, word_emb, pos_emb, type_emb,
                                              emb_ln_g, emb_ln_b, x, x_bf);
    prep_kernel<<<1792, 256, 0, stream>>>(w_hh_f, w_hh_b, w_ih_f, w_ih_b, wfrag8, wihT);
    if (big)
        conv_w_kernel<true><<<1728 * 12, 256, 0, stream>>>(Wq, Wk, Wv, Wo, Wf1, Wf2, wbuf);

    dim3 gQKV(2304 / 128, NTOK / 128);  // 18 x 16
    dim3 gH(HH / 64, NTOK / 128);       // 12 x 16
    dim3 gF1(FF_ / 128, NTOK / 128);    // 24 x 16
    dim3 gG(2048 / 128, NTOK / 128);    // 16 x 16

    for (int l = 0; l < NL; ++l) {
        u16* wb = big ? wbuf + (size_t)l * 7077888 : wbuf;
        if (!big)
            conv_w_kernel<false><<<1728, 256, 0, stream>>>(
                Wq + (size_t)l * HH * HH, Wk + (size_t)l * HH * HH,
                Wv + (size_t)l * HH * HH, Wo + (size_t)l * HH * HH,
                Wf1 + (size_t)l * HH * FF_, Wf2 + (size_t)l * FF_ * HH, wb);

        const float* bq_l = bq + (size_t)l * HH;
        const float* bk_l = bk + (size_t)l * HH;
        const float* bv_l = bv + (size_t)l * HH;
        const float* bo_l = bo + (size_t)l * HH;
        const float* g1 = ln1_g + (size_t)l * HH;
        const float* b1 = ln1_b + (size_t)l * HH;
        const float* bf1_l = bf1 + (size_t)l * FF_;
        const float* bf2_l = bf2 + (size_t)l * HH;
        const float* g2 = ln2_g + (size_t)l * HH;
        const float* b2 = ln2_b + (size_t)l * HH;

        gemm2_kernel<128, false, false><<<gQKV, 256, 0, stream>>>(
            x_bf, wb, bq_l, bk_l, bv_l, 768, qkv, nullptr, NTOK, 2304, HH);
        attention_kernel<<<BB * NH_ * 4, 256, 0, stream>>>(qkv, attn_mask, ctx_bf);
        gemm2_kernel<64, false, false><<<gH, 256, 0, stream>>>(
            ctx_bf, wb + 1769472, bo_l, bo_l, bo_l, 768, tmp, nullptr, NTOK, HH, HH);
        ln_residual_kernel<<<NTOK, 256, 0, stream>>>(x, tmp, g1, b1, ab, ab_bf);
        gemm2_kernel<128, true, true><<<gF1, 256, 0, stream>>>(
            ab_bf, wb + 2359296, bf1_l, bf1_l, bf1_l, FF_, nullptr, big_bf, NTOK, FF_, HH);
        gemm2_kernel<64, false, false><<<gH, 256, 0, stream>>>(
            big_bf, wb + 4718592, bf2_l, bf2_l, bf2_l, 768, tmp, nullptr, NTOK, HH, FF_);
        ln_residual_kernel<<<NTOK, 256, 0, stream>>>(ab, tmp, g2, b2, x, x_bf);
    }

    // fused LSTM input projections: xg[tok][dir*1024+g]
    gemm2_kernel<128, false, false><<<gG, 256, 0, stream>>>(
        x_bf, wihT, b_ih_f, b_ih_b, b_ih_b, 1024, xg, nullptr, NTOK, 2048, HH);

    lstm12_kernel<<<2, 1024, 0, stream>>>(xg, wfrag8, b_hh_f, b_hh_b, hf, hb);
    clf_kernel<<<(BB * TT * KK_ + 255) / 256, 256, 0, stream>>>(hf, hb, W_clf, b_clf, em);
    crf2_kernel<<<1, 512, 0, stream>>>(em, labels, attn_mask, crf_start, crf_end, crf_trans,
                                       (float*)d_out);
}

// Round 16
// 5090.284 us; speedup vs baseline: 4.2996x; 1.0908x over previous
//
#include <hip/hip_runtime.h>
#include <math.h>

#define BB 8
#define TT 256
#define HH 768
#define NL 12
#define NH_ 12
#define DH_ 64
#define FF_ 3072
#define LH_ 256
#define KK_ 9

typedef unsigned char u8;
typedef unsigned short u16;
typedef unsigned int u32;
typedef __attribute__((ext_vector_type(4))) float f32x4;

static __device__ __forceinline__ float sigm_fast(float x) {
    return __builtin_amdgcn_rcpf(1.0f + __expf(-x));
}
static __device__ __forceinline__ float tanh_fast(float x) {
    return 1.0f - 2.0f * __builtin_amdgcn_rcpf(1.0f + __expf(2.0f * x));
}
static __device__ __forceinline__ float bf2f(u16 v) {
    return __uint_as_float(((u32)v) << 16);
}
// 2 floats -> 2 fp8 bytes; HI selects which 16-bit half of `old` is replaced
template <bool HI>
static __device__ __forceinline__ u32 pk8(float a, float b, u32 old) {
    return (u32)__builtin_amdgcn_cvt_pk_fp8_f32(a, b, (int)old, HI);
}
static __device__ __forceinline__ u8 f8(float v) {
    return (u8)(pk8<false>(v, v, 0) & 0xff);
}

static __device__ __forceinline__ f32x4 mfma_fp8(long a, long b, f32x4 c) {
    return __builtin_amdgcn_mfma_f32_16x16x32_fp8_fp8(a, b, c, 0, 0, 0);
}

#define GLL16(gp, lp) __builtin_amdgcn_global_load_lds( \
    (const __attribute__((address_space(1))) void*)(gp), \
    (__attribute__((address_space(3))) void*)(lp), 16, 0, 0)

// ---------------- block reduce ----------------
static __device__ __forceinline__ float block_sum(float v, float* red) {
    int tid = threadIdx.x;
#pragma unroll
    for (int o = 32; o > 0; o >>= 1) v += __shfl_xor(v, o);
    if ((tid & 63) == 0) red[tid >> 6] = v;
    __syncthreads();
    return red[0] + red[1] + red[2] + red[3];
}

// ---------------- embedding + LN -> fp32 + fp8 ----------------
__global__ __launch_bounds__(256) void embed_ln_kernel(
    const int* __restrict__ ids, const float* __restrict__ we, const float* __restrict__ pe,
    const float* __restrict__ te, const float* __restrict__ g, const float* __restrict__ b,
    float* __restrict__ out, u8* __restrict__ out8) {
    int row = blockIdx.x;
    int t = row % TT;
    int id = ids[row];
    __shared__ float xr[HH];
    __shared__ float reda[8], redb[8];
    int tid = threadIdx.x;
    float s = 0.f;
    for (int h = tid; h < HH; h += 256) {
        float v = we[(size_t)id * HH + h] + pe[(size_t)t * HH + h] + te[h];
        xr[h] = v; s += v;
    }
    float mean = block_sum(s, reda) * (1.0f / HH);
    float vs = 0.f;
    for (int h = tid; h < HH; h += 256) { float d = xr[h] - mean; vs += d * d; }
    float var = block_sum(vs, redb) * (1.0f / HH);
    float rstd = rsqrtf(var + 1e-12f);
    for (int h = tid; h < HH; h += 256) {
        float v = (xr[h] - mean) * rstd * g[h] + b[h];
        out[(size_t)row * HH + h] = v;
        out8[(size_t)row * HH + h] = f8(v);
    }
}

// ---------------- LN(a + f) -> fp32 + fp8 ----------------
__global__ __launch_bounds__(256) void ln_residual_kernel(
    const float* __restrict__ a, const float* __restrict__ f,
    const float* __restrict__ g, const float* __restrict__ b,
    float* __restrict__ out, u8* __restrict__ out8) {
    int row = blockIdx.x;
    __shared__ float xr[HH];
    __shared__ float reda[8], redb[8];
    int tid = threadIdx.x;
    float s = 0.f;
    for (int h = tid; h < HH; h += 256) {
        float v = a[(size_t)row * HH + h] + f[(size_t)row * HH + h];
        xr[h] = v; s += v;
    }
    float mean = block_sum(s, reda) * (1.0f / HH);
    float vs = 0.f;
    for (int h = tid; h < HH; h += 256) { float d = xr[h] - mean; vs += d * d; }
    float var = block_sum(vs, redb) * (1.0f / HH);
    float rstd = rsqrtf(var + 1e-12f);
    for (int h = tid; h < HH; h += 256) {
        float v = (xr[h] - mean) * rstd * g[h] + b[h];
        out[(size_t)row * HH + h] = v;
        out8[(size_t)row * HH + h] = f8(v);
    }
}

// ---------------- weight transpose+convert fp32 -> fp8 [N][K] ----------------
template <bool LAYERS12>
__global__ __launch_bounds__(256) void conv_w_kernel(
    const float* __restrict__ Wq, const float* __restrict__ Wk,
    const float* __restrict__ Wv, const float* __restrict__ Wo,
    const float* __restrict__ Wf1, const float* __restrict__ Wf2,
    u8* __restrict__ wbuf) {
    __shared__ float tile[64][65];
    int bid = blockIdx.x;
    int layer = 0;
    if (LAYERS12) { layer = bid / 1728; bid -= layer * 1728; }
    size_t woff = (size_t)layer * 7077888;
    size_t hh2 = (size_t)layer * HH * HH;
    size_t hf2 = (size_t)layer * HH * FF_;
    const float* src; u8* dst; int R, C, bx, by;
    if (bid < 576) {
        int m = bid / 144, t = bid % 144;
        src = (m == 0 ? Wq + hh2 : m == 1 ? Wk + hh2 : m == 2 ? Wv + hh2 : Wo + hh2);
        dst = wbuf + woff + (size_t)m * 589824;
        R = 768; C = 768; bx = t % 12; by = t / 12;
    } else if (bid < 1152) {
        int t = bid - 576;
        src = Wf1 + hf2; dst = wbuf + woff + 2359296; R = 768; C = 3072;
        bx = t % 48; by = t / 48;
    } else {
        int t = bid - 1152;
        src = Wf2 + hf2; dst = wbuf + woff + 4718592; R = 3072; C = 768;
        bx = t % 12; by = t / 12;
    }
    int tx = threadIdx.x & 15, ty = threadIdx.x >> 4;   // 16 x 16
#pragma unroll
    for (int p = 0; p < 4; ++p) {
        int row = p * 16 + ty;
        float4 v = *(const float4*)&src[(size_t)(by * 64 + row) * C + bx * 64 + tx * 4];
        tile[row][tx * 4 + 0] = v.x; tile[row][tx * 4 + 1] = v.y;
        tile[row][tx * 4 + 2] = v.z; tile[row][tx * 4 + 3] = v.w;
    }
    __syncthreads();
    int rq = (threadIdx.x & 15) * 4, cc0 = threadIdx.x >> 4;   // 16 cols/pass
#pragma unroll
    for (int p = 0; p < 4; ++p) {
        int cc = p * 16 + cc0;
        u32 w0 = pk8<false>(tile[rq][cc], tile[rq + 1][cc], 0);
        w0 = pk8<true>(tile[rq + 2][cc], tile[rq + 3][cc], w0);
        *(u32*)&dst[(size_t)(bx * 64 + cc) * R + by * 64 + rq] = w0;
    }
}

// ---------------- prologue: pack w_hh fp8 frags + convert w_ih -> fp8 ----------------
__global__ __launch_bounds__(256) void prep_kernel(
    const float* __restrict__ whf, const float* __restrict__ whb,
    const float* __restrict__ wif, const float* __restrict__ wib,
    u8* __restrict__ wfrag8, u8* __restrict__ wihT) {
    int bid = blockIdx.x;
    int tid = threadIdx.x;
    if (bid < 256) {
        int idx = bid * 256 + tid;
        int dir = idx >> 15;
        int kt  = (idx >> 12) & 7;
        int mt  = (idx >> 6) & 63;
        int lane = idx & 63;
        const float* W = dir ? whb : whf;
        int row = mt * 16 + (lane & 15);
        int k = kt * 32 + (lane >> 4) * 8;
        const float* src = W + (size_t)row * LH_ + k;
        u32 w0 = pk8<false>(src[0], src[1], 0);
        w0 = pk8<true>(src[2], src[3], w0);
        u32 w1 = pk8<false>(src[4], src[5], 0);
        w1 = pk8<true>(src[6], src[7], w1);
        uint2 pk; pk.x = w0; pk.y = w1;
        size_t base = (size_t)(((dir * 8 + kt) * 64 + mt) * 64 + lane) * 8;
        *(uint2*)&wfrag8[base] = pk;
    } else {
        int which = (bid < 1024) ? 0 : 1;
        const float* src = which ? wib : wif;
        u8* dst = wihT + (size_t)which * 786432;
        int i = (bid - (which ? 1024 : 256)) * 256 + tid;
        float4 v = *(const float4*)&src[(size_t)i * 4];
        u32 w0 = pk8<false>(v.x, v.y, 0);
        w0 = pk8<true>(v.z, v.w, w0);
        *(u32*)&dst[(size_t)i * 4] = w0;
    }
}

// ---------------- GEMM v3: fp8 operands, 16B-XOR swizzle, dbuf ----------------
// LDS logical [row][k<64] fp8; physical 16B-block: phys = a ^ ((row>>1)&3).
template <int BROWS>
__device__ __forceinline__ void stage8(
    const u8* __restrict__ S, int r0, int K, int k0, u8 (*lds)[64], int w, int lane) {
    int srl = lane >> 2;       // 0..15
    int p = lane & 3;
    constexpr int INSTS = BROWS / 64;   // per wave
#pragma unroll
    for (int i = 0; i < INSTS; ++i) {
        int row0 = (w * INSTS + i) * 16;
        int srow = row0 + srl;
        int a = p ^ ((srow >> 1) & 3);
        GLL16(S + (size_t)(r0 + srow) * K + k0 + a * 16, &lds[row0][0]);
    }
}

static __device__ __forceinline__ long lds8_read(const u8 (*lds)[64], int row, int g) {
    int a = g >> 1;
    int phys = a ^ ((row >> 1) & 3);
    return *(const long*)&lds[row][phys * 16 + (g & 1) * 8];
}

template <int BN, bool GELU, bool OUTF8>
__global__ __launch_bounds__(256) void gemm3_kernel(
    const u8* __restrict__ A, const u8* __restrict__ BT,
    const float* __restrict__ b0, const float* __restrict__ b1, const float* __restrict__ b2,
    int seg, float* __restrict__ C, u8* __restrict__ C8, int M, int N, int K) {
    __shared__ u8 Als[2][128][64];
    __shared__ u8 Bls[2][BN][64];
    int tid = threadIdx.x, lane = tid & 63, w = tid >> 6;
    int m0 = blockIdx.y * 128, n0 = blockIdx.x * BN;
    int wr = w >> 1, wc = w & 1;
    int l15 = lane & 15, q = lane >> 4;
    constexpr int NJ = BN / 32;

    f32x4 acc[4][NJ];
#pragma unroll
    for (int mi = 0; mi < 4; ++mi)
#pragma unroll
        for (int nj = 0; nj < NJ; ++nj) acc[mi][nj] = (f32x4){0.f, 0.f, 0.f, 0.f};

    stage8<128>(A, m0, K, 0, Als[0], w, lane);
    stage8<BN>(BT, n0, K, 0, Bls[0], w, lane);
    __syncthreads();
    int KT = K >> 6, cur = 0;
    for (int kt = 0; kt < KT; ++kt) {
        if (kt + 1 < KT) {
            stage8<128>(A, m0, K, (kt + 1) << 6, Als[cur ^ 1], w, lane);
            stage8<BN>(BT, n0, K, (kt + 1) << 6, Bls[cur ^ 1], w, lane);
        }
#pragma unroll
        for (int ks = 0; ks < 2; ++ks) {
            int g = ks * 4 + q;
            long bfr[NJ];
#pragma unroll
            for (int nj = 0; nj < NJ; ++nj)
                bfr[nj] = lds8_read(Bls[cur], wc * (BN / 2) + nj * 16 + l15, g);
#pragma unroll
            for (int mi = 0; mi < 4; ++mi) {
                long a = lds8_read(Als[cur], wr * 64 + mi * 16 + l15, g);
#pragma unroll
                for (int nj = 0; nj < NJ; ++nj)
                    acc[mi][nj] = mfma_fp8(a, bfr[nj], acc[mi][nj]);
            }
        }
        __syncthreads();
        cur ^= 1;
    }

    int rbase = m0 + wr * 64 + q * 4;
    int cbase = n0 + wc * (BN / 2) + l15;
#pragma unroll
    for (int mi = 0; mi < 4; ++mi) {
#pragma unroll
        for (int nj = 0; nj < NJ; ++nj) {
            int col = cbase + nj * 16;
            int cc = col;
            const float* bp;
            if (cc < seg) bp = b0;
            else if (cc < 2 * seg) { bp = b1; cc -= seg; }
            else { bp = b2; cc -= 2 * seg; }
            float bias = bp[cc];
#pragma unroll
            for (int j = 0; j < 4; ++j) {
                int row = rbase + mi * 16 + j;
                float v = acc[mi][nj][j] + bias;
                if (GELU) v = 0.5f * v * (1.0f + erff(v * 0.70710678118654752f));
                if (OUTF8) C8[(size_t)row * N + col] = f8(v);
                else       C[(size_t)row * N + col] = v;
            }
        }
    }
}

// ---------------- attention v3: (b,h,qquarter) blocks, fp32 in, fp8 ctx out ----------------
__global__ __launch_bounds__(256) void attention_kernel(
    const float* __restrict__ qkv, const int* __restrict__ mask, u8* __restrict__ ctx8) {
    int bid = blockIdx.x;
    int quarter = bid & 3;
    int bh = bid >> 2;
    int b = bh / NH_, h = bh % NH_;
    int tid = threadIdx.x;
    int q_i = quarter * 64 + (tid >> 2);
    int dq = tid & 3;
    const float* qp = qkv + (size_t)(b * TT + q_i) * 2304 + h * DH_ + dq * 16;
    float qv[16];
#pragma unroll
    for (int d = 0; d < 4; ++d) {
        float4 v = *(const float4*)(qp + 4 * d);
        qv[4*d] = v.x; qv[4*d+1] = v.y; qv[4*d+2] = v.z; qv[4*d+3] = v.w;
    }
    const float* kbase = qkv + (size_t)b * TT * 2304 + 768 + h * DH_ + dq * 16;
    const float* vbase = qkv + (size_t)b * TT * 2304 + 1536 + h * DH_ + dq * 16;
    __shared__ float bias_s[TT];
    for (int i = tid; i < TT; i += 256)
        bias_s[i] = (1.0f - (float)mask[b * TT + i]) * -10000.0f;
    __syncthreads();
    float acc[16] = {};
    float l = 0.f;
    for (int kk = 0; kk < TT; ++kk) {
        const float4* kp = (const float4*)(kbase + (size_t)kk * 2304);
        float4 s4 = {0.f, 0.f, 0.f, 0.f};
#pragma unroll
        for (int d = 0; d < 4; ++d) {
            float4 k4 = kp[d];
            s4.x += qv[4*d] * k4.x;
            s4.y += qv[4*d+1] * k4.y;
            s4.z += qv[4*d+2] * k4.z;
            s4.w += qv[4*d+3] * k4.w;
        }
        float part = (s4.x + s4.y) + (s4.z + s4.w);
        part += __shfl_xor(part, 1);
        part += __shfl_xor(part, 2);
        float s = part * 0.125f + bias_s[kk];
        float p = __expf(s);
        l += p;
        const float4* vp = (const float4*)(vbase + (size_t)kk * 2304);
#pragma unroll
        for (int d = 0; d < 4; ++d) {
            float4 v4 = vp[d];
            acc[4*d]   += p * v4.x;
            acc[4*d+1] += p * v4.y;
            acc[4*d+2] += p * v4.z;
            acc[4*d+3] += p * v4.w;
        }
    }
    float inv = __builtin_amdgcn_rcpf(l);
    size_t base = (size_t)(b * TT + q_i) * HH + h * DH_ + dq * 16;
#pragma unroll
    for (int d = 0; d < 4; ++d) {
        u32 w0 = pk8<false>(acc[4*d] * inv, acc[4*d+1] * inv, 0);
        w0 = pk8<true>(acc[4*d+2] * inv, acc[4*d+3] * inv, w0);
        *(u32*)&ctx8[base + 4*d] = w0;
    }
}

// ---------------- LSTM v12 ----------------
__global__ __launch_bounds__(1024, 4) void lstm12_kernel(
    const float* __restrict__ xg, const u8* __restrict__ wfrag8,
    const float* __restrict__ bhh_f, const float* __restrict__ bhh_b,
    float* __restrict__ hf, float* __restrict__ hb) {
    int dir = blockIdx.x;
    const u8* wf8 = wfrag8 + (size_t)dir * 262144;
    const float* bhh = dir ? bhh_b : bhh_f;
    float* hout = dir ? hb : hf;
    int tid = threadIdx.x, lane = tid & 63, wid = tid >> 6;
    __shared__ u8 wlds[4 * 64 * 512];
    __shared__ u8 h_f8[16][280];
    __shared__ u16 g_bf[1024][10];
    for (int i = tid; i < 16 * 280; i += 1024) ((u8*)h_f8)[i] = 0;
#pragma unroll
    for (int c = 0; c < 8; ++c) {
        int off = wid * 8192 + c * 1024;
        GLL16(wf8 + off + lane * 16, &wlds[off]);
    }
    int l15 = lane & 15, qq = lane >> 4;
    int j = tid & 255;
    int bq = (tid >> 8) * 2;
    float bi_ = bhh[j], bf_ = bhh[256 + j], bg_ = bhh[512 + j], bo_ = bhh[768 + j];
    float c_s[2] = {0.f, 0.f};
    __syncthreads();
    for (int step = 0; step < TT; ++step) {
        int t = dir ? (TT - 1 - step) : step;
        long wst[4][4];
#pragma unroll
        for (int kt = 0; kt < 4; ++kt)
#pragma unroll
            for (int m = 0; m < 4; ++m)
                wst[kt][m] = *(const long*)&wf8[(size_t)(((4 + kt) * 64) + wid * 4 + m) * 512 + lane * 8];
        float xgi[2], xgf[2], xgg[2], xgo[2];
#pragma unroll
        for (int bi = 0; bi < 2; ++bi) {
            size_t xa = ((size_t)((bq + bi) * TT + t)) * 2048 + (size_t)dir * 1024;
            xgi[bi] = xg[xa + j];
            xgf[bi] = xg[xa + 256 + j];
            xgg[bi] = xg[xa + 512 + j];
            xgo[bi] = xg[xa + 768 + j];
        }
        f32x4 acc[4];
#pragma unroll
        for (int m = 0; m < 4; ++m) acc[m] = (f32x4){0.f, 0.f, 0.f, 0.f};
#pragma unroll
        for (int kt = 0; kt < 4; ++kt) {
            long hfr = *(const long*)&h_f8[l15][kt * 32 + qq * 8];
#pragma unroll
            for (int m = 0; m < 4; ++m) {
                long a = *(const long*)&wlds[(size_t)(kt * 64 + wid * 4 + m) * 512 + lane * 8];
                acc[m] = mfma_fp8(a, hfr, acc[m]);
            }
        }
#pragma unroll
        for (int kt = 0; kt < 4; ++kt) {
            long hfr = *(const long*)&h_f8[l15][(4 + kt) * 32 + qq * 8];
#pragma unroll
            for (int m = 0; m < 4; ++m)
                acc[m] = mfma_fp8(wst[kt][m], hfr, acc[m]);
        }
        if (l15 < 8) {
#pragma unroll
            for (int m = 0; m < 4; ++m) {
                int R = (wid * 4 + m) * 16 + qq * 4;
#pragma unroll
                for (int jj = 0; jj < 4; ++jj)
                    g_bf[R + jj][l15] = (u16)(__float_as_uint(acc[m][jj]) >> 16);
            }
        }
        __syncthreads();
#pragma unroll
        for (int bi = 0; bi < 2; ++bi) {
            int b = bq + bi;
            float gi = xgi[bi] + bi_ + bf2f(g_bf[j][b]);
            float gf = xgf[bi] + bf_ + bf2f(g_bf[256 + j][b]);
            float gg = xgg[bi] + bg_ + bf2f(g_bf[512 + j][b]);
            float go = xgo[bi] + bo_ + bf2f(g_bf[768 + j][b]);
            float cc = sigm_fast(gf) * c_s[bi] + sigm_fast(gi) * tanh_fast(gg);
            c_s[bi] = cc;
            float hh = sigm_fast(go) * tanh_fast(cc);
            h_f8[b][j] = f8(hh);
            hout[((size_t)(b * TT + t)) * LH_ + j] = hh;
        }
        __syncthreads();
    }
}

// ---------------- classifier ----------------
__global__ __launch_bounds__(256) void clf_kernel(
    const float* __restrict__ hf, const float* __restrict__ hb,
    const float* __restrict__ W, const float* __restrict__ bias, float* __restrict__ em) {
    int idx = blockIdx.x * blockDim.x + threadIdx.x;
    if (idx >= BB * TT * KK_) return;
    int row = idx / KK_, j = idx % KK_;
    float acc = bias[j];
    const float* hfp = hf + (size_t)row * LH_;
    const float* hbp = hb + (size_t)row * LH_;
    for (int kk = 0; kk < LH_; ++kk) acc += hfp[kk] * W[kk * KK_ + j];
    for (int kk = 0; kk < LH_; ++kk) acc += hbp[kk] * W[(LH_ + kk) * KK_ + j];
    em[idx] = acc;
}

// ---------------- CRF v2 ----------------
__global__ __launch_bounds__(512) void crf2_kernel(
    const float* __restrict__ em, const int* __restrict__ labels, const int* __restrict__ mask,
    const float* __restrict__ cstart, const float* __restrict__ cend,
    const float* __restrict__ ctrans, float* __restrict__ out) {
    __shared__ float trans_s[81];
    __shared__ float res[8];
    int tid = threadIdx.x;
    int b = tid >> 6;
    int l = tid & 63;
    if (tid < 81) trans_s[tid] = ctrans[tid];
    __syncthreads();
    int lc = (l < 9) ? l : 0;
    float tcol[9];
#pragma unroll
    for (int i = 0; i < 9; ++i) tcol[i] = trans_s[i * 9 + lc];
    float alpha = (l < 9) ? cstart[lc] + em[(size_t)b * TT * KK_ + lc] : -1e30f;
    for (int t = 1; t < TT; ++t) {
        float e_t = (l < 9) ? em[((size_t)b * TT + t) * KK_ + lc] : 0.f;
        float m = -1e30f;
        float av[9];
#pragma unroll
        for (int i = 0; i < 9; ++i) {
            av[i] = __shfl(alpha, i) + tcol[i];
            m = fmaxf(m, av[i]);
        }
        float s = 0.f;
#pragma unroll
        for (int i = 0; i < 9; ++i) s += expf(av[i] - m);
        float nv = m + logf(s) + e_t;
        bool upd = (mask[b * TT + t] > 0) && (l < 9);
        alpha = upd ? nv : alpha;
    }
    float z = (l < 9) ? alpha + cend[lc] : -1e30f;
    float zm = z;
#pragma unroll
    for (int o = 32; o > 0; o >>= 1) zm = fmaxf(zm, __shfl_xor(zm, o));
    float zs = (l < 9) ? expf(z - zm) : 0.f;
#pragma unroll
    for (int o = 32; o > 0; o >>= 1) zs += __shfl_xor(zs, o);
    float logZ = zm + logf(zs);
    float sc = 0.f;
    int cnt = 0;
    for (int t = l; t < TT; t += 64) {
        cnt += mask[b * TT + t];
        if (t == 0) {
            int l0 = labels[b * TT];
            sc += cstart[l0] + em[(size_t)b * TT * KK_ + l0];
        } else {
            int lp = labels[b * TT + t - 1];
            int lt = labels[b * TT + t];
            sc += (trans_s[lp * KK_ + lt] + em[((size_t)b * TT + t) * KK_ + lt]) *
                  (float)mask[b * TT + t];
        }
    }
#pragma unroll
    for (int o = 32; o > 0; o >>= 1) { sc += __shfl_xor(sc, o); cnt += __shfl_xor(cnt, o); }
    if (l == 0) {
        int last = labels[b * TT + (cnt - 1)];
        sc += cend[last];
        res[b] = sc - logZ;
    }
    __syncthreads();
    if (tid == 0) {
        float acc = 0.f;
        for (int bb = 0; bb < BB; ++bb) acc += res[bb];
        out[0] = -acc / (float)BB;
    }
}

extern "C" void kernel_launch(void* const* d_in, const int* in_sizes, int n_in,
                              void* d_out, int out_size, void* d_ws, size_t ws_size,
                              hipStream_t stream) {
    const int* input_ids = (const int*)d_in[0];
    const int* attn_mask = (const int*)d_in[1];
    const int* labels    = (const int*)d_in[2];
    const float* word_emb = (const float*)d_in[3];
    const float* pos_emb  = (const float*)d_in[4];
    const float* type_emb = (const float*)d_in[5];
    const float* emb_ln_g = (const float*)d_in[6];
    const float* emb_ln_b = (const float*)d_in[7];
    const float* Wq = (const float*)d_in[8];
    const float* bq = (const float*)d_in[9];
    const float* Wk = (const float*)d_in[10];
    const float* bk = (const float*)d_in[11];
    const float* Wv = (const float*)d_in[12];
    const float* bv = (const float*)d_in[13];
    const float* Wo = (const float*)d_in[14];
    const float* bo = (const float*)d_in[15];
    const float* ln1_g = (const float*)d_in[16];
    const float* ln1_b = (const float*)d_in[17];
    const float* Wf1 = (const float*)d_in[18];
    const float* bf1 = (const float*)d_in[19];
    const float* Wf2 = (const float*)d_in[20];
    const float* bf2 = (const float*)d_in[21];
    const float* ln2_g = (const float*)d_in[22];
    const float* ln2_b = (const float*)d_in[23];
    const float* w_ih_f = (const float*)d_in[24];
    const float* w_hh_f = (const float*)d_in[25];
    const float* b_ih_f = (const float*)d_in[26];
    const float* b_hh_f = (const float*)d_in[27];
    const float* w_ih_b = (const float*)d_in[28];
    const float* w_hh_b = (const float*)d_in[29];
    const float* b_ih_b = (const float*)d_in[30];
    const float* b_hh_b = (const float*)d_in[31];
    const float* W_clf  = (const float*)d_in[32];
    const float* b_clf  = (const float*)d_in[33];
    const float* crf_start = (const float*)d_in[34];
    const float* crf_end   = (const float*)d_in[35];
    const float* crf_trans = (const float*)d_in[36];

    const size_t NTOK = (size_t)BB * TT;          // 2048
    const size_t SZ = NTOK * HH;                  // 1,572,864

    float* ws = (float*)d_ws;
    float* x    = ws;                              // SZ
    float* qkv  = x + SZ;                          // 2048*2304
    float* tmp  = qkv + NTOK * 2304;               // SZ
    float* ab   = tmp + SZ;                        // SZ
    float* xg   = ab + SZ;                         // 2048*2048
    u8* x_f8    = (u8*)(xg + NTOK * 2048);         // SZ bytes
    u8* ab_f8   = x_f8 + SZ;
    u8* ctx_f8  = ab_f8 + SZ;
    u8* big_f8  = ctx_f8 + SZ;                     // 2048*3072
    u8* wihT    = big_f8 + NTOK * (size_t)FF_;     // 2048*768 bytes
    u8* wfrag8  = wihT + 1572864;                  // 524,288 bytes
    u8* wbuf    = wfrag8 + 524288;                 // per-layer 7,077,888 B (or x12)
    const size_t base_off = (size_t)((u8*)wbuf - (u8*)d_ws);
    bool big = ws_size >= base_off + 12ull * 7077888ull + (1u << 20);

    float* hf = qkv;
    float* hb = qkv + 524288;
    float* em = qkv + 1048576;

    embed_ln_kernel<<<NTOK, 256, 0, stream>>>(input_ids, word_emb, pos_emb, type_emb,
                                              emb_ln_g, emb_ln_b, x, x_f8);
    prep_kernel<<<1792, 256, 0, stream>>>(w_hh_f, w_hh_b, w_ih_f, w_ih_b, wfrag8, wihT);
    if (big)
        conv_w_kernel<true><<<1728 * 12, 256, 0, stream>>>(Wq, Wk, Wv, Wo, Wf1, Wf2, wbuf);

    dim3 gQKV(2304 / 128, NTOK / 128);  // 18 x 16
    dim3 gH(HH / 64, NTOK / 128);       // 12 x 16
    dim3 gF1(FF_ / 128, NTOK / 128);    // 24 x 16
    dim3 gG(2048 / 128, NTOK / 128);    // 16 x 16

    for (int l = 0; l < NL; ++l) {
        u8* wb = big ? wbuf + (size_t)l * 7077888 : wbuf;
        if (!big)
            conv_w_kernel<false><<<1728, 256, 0, stream>>>(
                Wq + (size_t)l * HH * HH, Wk + (size_t)l * HH * HH,
                Wv + (size_t)l * HH * HH, Wo + (size_t)l * HH * HH,
                Wf1 + (size_t)l * HH * FF_, Wf2 + (size_t)l * FF_ * HH, wb);

        const float* bq_l = bq + (size_t)l * HH;
        const float* bk_l = bk + (size_t)l * HH;
        const float* bv_l = bv + (size_t)l * HH;
        const float* bo_l = bo + (size_t)l * HH;
        const float* g1 = ln1_g + (size_t)l * HH;
        const float* b1 = ln1_b + (size_t)l * HH;
        const float* bf1_l = bf1 + (size_t)l * FF_;
        const float* bf2_l = bf2 + (size_t)l * HH;
        const float* g2 = ln2_g + (size_t)l * HH;
        const float* b2 = ln2_b + (size_t)l * HH;

        gemm3_kernel<128, false, false><<<gQKV, 256, 0, stream>>>(
            x_f8, wb, bq_l, bk_l, bv_l, 768, qkv, nullptr, NTOK, 2304, HH);
        attention_kernel<<<BB * NH_ * 4, 256, 0, stream>>>(qkv, attn_mask, ctx_f8);
        gemm3_kernel<64, false, false><<<gH, 256, 0, stream>>>(
            ctx_f8, wb + 1769472, bo_l, bo_l, bo_l, 768, tmp, nullptr, NTOK, HH, HH);
        ln_residual_kernel<<<NTOK, 256, 0, stream>>>(x, tmp, g1, b1, ab, ab_f8);
        gemm3_kernel<128, true, true><<<gF1, 256, 0, stream>>>(
            ab_f8, wb + 2359296, bf1_l, bf1_l, bf1_l, FF_, nullptr, big_f8, NTOK, FF_, HH);
        gemm3_kernel<64, false, false><<<gH, 256, 0, stream>>>(
            big_f8, wb + 4718592, bf2_l, bf2_l, bf2_l, 768, tmp, nullptr, NTOK, HH, FF_);
        ln_residual_kernel<<<NTOK, 256, 0, stream>>>(ab, tmp, g2, b2, x, x_f8);
    }

    // fused LSTM input projections: xg[tok][dir*1024+g]
    gemm3_kernel<128, false, false><<<gG, 256, 0, stream>>>(
        x_f8, wihT, b_ih_f, b_ih_b, b_ih_b, 1024, xg, nullptr, NTOK, 2048, HH);

    lstm12_kernel<<<2, 1024, 0, stream>>>(xg, wfrag8, b_hh_f, b_hh_b, hf, hb);
    clf_kernel<<<(BB * TT * KK_ + 255) / 256, 256, 0, stream>>>(hf, hb, W_clf, b_clf, em);
    crf2_kernel<<<1, 512, 0, stream>>>(em, labels, attn_mask, crf_start, crf_end, crf_trans,
                                       (float*)d_out);
}

// Round 17
// 4943.035 us; speedup vs baseline: 4.4277x; 1.0298x over previous
//
#include <hip/hip_runtime.h>
#include <math.h>

#define BB 8
#define TT 256
#define HH 768
#define NL 12
#define NH_ 12
#define DH_ 64
#define FF_ 3072
#define LH_ 256
#define KK_ 9

typedef unsigned char u8;
typedef unsigned short u16;
typedef unsigned int u32;
typedef __attribute__((ext_vector_type(4))) float f32x4;

static __device__ __forceinline__ float sigm_fast(float x) {
    return __builtin_amdgcn_rcpf(1.0f + __expf(-x));
}
static __device__ __forceinline__ float tanh_fast(float x) {
    return 1.0f - 2.0f * __builtin_amdgcn_rcpf(1.0f + __expf(2.0f * x));
}
static __device__ __forceinline__ float bf2f(u16 v) {
    return __uint_as_float(((u32)v) << 16);
}
// 2 floats -> 2 fp8 bytes; HI selects which 16-bit half of `old` is replaced
template <bool HI>
static __device__ __forceinline__ u32 pk8(float a, float b, u32 old) {
    return (u32)__builtin_amdgcn_cvt_pk_fp8_f32(a, b, (int)old, HI);
}
static __device__ __forceinline__ u8 f8(float v) {
    return (u8)(pk8<false>(v, v, 0) & 0xff);
}

static __device__ __forceinline__ f32x4 mfma_fp8(long a, long b, f32x4 c) {
    return __builtin_amdgcn_mfma_f32_16x16x32_fp8_fp8(a, b, c, 0, 0, 0);
}

#define GLL16(gp, lp) __builtin_amdgcn_global_load_lds( \
    (const __attribute__((address_space(1))) void*)(gp), \
    (__attribute__((address_space(3))) void*)(lp), 16, 0, 0)

// ---------------- block reduce ----------------
static __device__ __forceinline__ float block_sum(float v, float* red) {
    int tid = threadIdx.x;
#pragma unroll
    for (int o = 32; o > 0; o >>= 1) v += __shfl_xor(v, o);
    if ((tid & 63) == 0) red[tid >> 6] = v;
    __syncthreads();
    return red[0] + red[1] + red[2] + red[3];
}

// ---------------- embedding + LN -> fp32 + fp8 ----------------
__global__ __launch_bounds__(256) void embed_ln_kernel(
    const int* __restrict__ ids, const float* __restrict__ we, const float* __restrict__ pe,
    const float* __restrict__ te, const float* __restrict__ g, const float* __restrict__ b,
    float* __restrict__ out, u8* __restrict__ out8) {
    int row = blockIdx.x;
    int t = row % TT;
    int id = ids[row];
    __shared__ float xr[HH];
    __shared__ float reda[8], redb[8];
    int tid = threadIdx.x;
    float s = 0.f;
    for (int h = tid; h < HH; h += 256) {
        float v = we[(size_t)id * HH + h] + pe[(size_t)t * HH + h] + te[h];
        xr[h] = v; s += v;
    }
    float mean = block_sum(s, reda) * (1.0f / HH);
    float vs = 0.f;
    for (int h = tid; h < HH; h += 256) { float d = xr[h] - mean; vs += d * d; }
    float var = block_sum(vs, redb) * (1.0f / HH);
    float rstd = rsqrtf(var + 1e-12f);
    for (int h = tid; h < HH; h += 256) {
        float v = (xr[h] - mean) * rstd * g[h] + b[h];
        out[(size_t)row * HH + h] = v;
        out8[(size_t)row * HH + h] = f8(v);
    }
}

// ---------------- LN(a + f) -> fp32 + fp8 ----------------
__global__ __launch_bounds__(256) void ln_residual_kernel(
    const float* __restrict__ a, const float* __restrict__ f,
    const float* __restrict__ g, const float* __restrict__ b,
    float* __restrict__ out, u8* __restrict__ out8) {
    int row = blockIdx.x;
    __shared__ float xr[HH];
    __shared__ float reda[8], redb[8];
    int tid = threadIdx.x;
    float s = 0.f;
    for (int h = tid; h < HH; h += 256) {
        float v = a[(size_t)row * HH + h] + f[(size_t)row * HH + h];
        xr[h] = v; s += v;
    }
    float mean = block_sum(s, reda) * (1.0f / HH);
    float vs = 0.f;
    for (int h = tid; h < HH; h += 256) { float d = xr[h] - mean; vs += d * d; }
    float var = block_sum(vs, redb) * (1.0f / HH);
    float rstd = rsqrtf(var + 1e-12f);
    for (int h = tid; h < HH; h += 256) {
        float v = (xr[h] - mean) * rstd * g[h] + b[h];
        out[(size_t)row * HH + h] = v;
        out8[(size_t)row * HH + h] = f8(v);
    }
}

// ---------------- weight transpose+convert fp32 -> fp8 [N][K] ----------------
template <bool LAYERS12>
__global__ __launch_bounds__(256) void conv_w_kernel(
    const float* __restrict__ Wq, const float* __restrict__ Wk,
    const float* __restrict__ Wv, const float* __restrict__ Wo,
    const float* __restrict__ Wf1, const float* __restrict__ Wf2,
    u8* __restrict__ wbuf) {
    __shared__ float tile[64][65];
    int bid = blockIdx.x;
    int layer = 0;
    if (LAYERS12) { layer = bid / 1728; bid -= layer * 1728; }
    size_t woff = (size_t)layer * 7077888;
    size_t hh2 = (size_t)layer * HH * HH;
    size_t hf2 = (size_t)layer * HH * FF_;
    const float* src; u8* dst; int R, C, bx, by;
    if (bid < 576) {
        int m = bid / 144, t = bid % 144;
        src = (m == 0 ? Wq + hh2 : m == 1 ? Wk + hh2 : m == 2 ? Wv + hh2 : Wo + hh2);
        dst = wbuf + woff + (size_t)m * 589824;
        R = 768; C = 768; bx = t % 12; by = t / 12;
    } else if (bid < 1152) {
        int t = bid - 576;
        src = Wf1 + hf2; dst = wbuf + woff + 2359296; R = 768; C = 3072;
        bx = t % 48; by = t / 48;
    } else {
        int t = bid - 1152;
        src = Wf2 + hf2; dst = wbuf + woff + 4718592; R = 3072; C = 768;
        bx = t % 12; by = t / 12;
    }
    int tx = threadIdx.x & 15, ty = threadIdx.x >> 4;   // 16 x 16
#pragma unroll
    for (int p = 0; p < 4; ++p) {
        int row = p * 16 + ty;
        float4 v = *(const float4*)&src[(size_t)(by * 64 + row) * C + bx * 64 + tx * 4];
        tile[row][tx * 4 + 0] = v.x; tile[row][tx * 4 + 1] = v.y;
        tile[row][tx * 4 + 2] = v.z; tile[row][tx * 4 + 3] = v.w;
    }
    __syncthreads();
    int rq = (threadIdx.x & 15) * 4, cc0 = threadIdx.x >> 4;   // 16 cols/pass
#pragma unroll
    for (int p = 0; p < 4; ++p) {
        int cc = p * 16 + cc0;
        u32 w0 = pk8<false>(tile[rq][cc], tile[rq + 1][cc], 0);
        w0 = pk8<true>(tile[rq + 2][cc], tile[rq + 3][cc], w0);
        *(u32*)&dst[(size_t)(bx * 64 + cc) * R + by * 64 + rq] = w0;
    }
}

// ---------------- prologue: pack w_hh fp8 frags + convert w_ih -> fp8 ----------------
__global__ __launch_bounds__(256) void prep_kernel(
    const float* __restrict__ whf, const float* __restrict__ whb,
    const float* __restrict__ wif, const float* __restrict__ wib,
    u8* __restrict__ wfrag8, u8* __restrict__ wihT) {
    int bid = blockIdx.x;
    int tid = threadIdx.x;
    if (bid < 256) {
        int idx = bid * 256 + tid;
        int dir = idx >> 15;
        int kt  = (idx >> 12) & 7;
        int mt  = (idx >> 6) & 63;
        int lane = idx & 63;
        const float* W = dir ? whb : whf;
        int row = mt * 16 + (lane & 15);
        int k = kt * 32 + (lane >> 4) * 8;
        const float* src = W + (size_t)row * LH_ + k;
        u32 w0 = pk8<false>(src[0], src[1], 0);
        w0 = pk8<true>(src[2], src[3], w0);
        u32 w1 = pk8<false>(src[4], src[5], 0);
        w1 = pk8<true>(src[6], src[7], w1);
        uint2 pk; pk.x = w0; pk.y = w1;
        size_t base = (size_t)(((dir * 8 + kt) * 64 + mt) * 64 + lane) * 8;
        *(uint2*)&wfrag8[base] = pk;
    } else {
        int which = (bid < 1024) ? 0 : 1;
        const float* src = which ? wib : wif;
        u8* dst = wihT + (size_t)which * 786432;
        int i = (bid - (which ? 1024 : 256)) * 256 + tid;
        float4 v = *(const float4*)&src[(size_t)i * 4];
        u32 w0 = pk8<false>(v.x, v.y, 0);
        w0 = pk8<true>(v.z, v.w, w0);
        *(u32*)&dst[(size_t)i * 4] = w0;
    }
}

// ---------------- GEMM v3: fp8 operands, 16B-XOR swizzle, dbuf ----------------
template <int BROWS>
__device__ __forceinline__ void stage8(
    const u8* __restrict__ S, int r0, int K, int k0, u8 (*lds)[64], int w, int lane) {
    int srl = lane >> 2;       // 0..15
    int p = lane & 3;
    constexpr int INSTS = BROWS / 64;   // per wave
#pragma unroll
    for (int i = 0; i < INSTS; ++i) {
        int row0 = (w * INSTS + i) * 16;
        int srow = row0 + srl;
        int a = p ^ ((srow >> 1) & 3);
        GLL16(S + (size_t)(r0 + srow) * K + k0 + a * 16, &lds[row0][0]);
    }
}

static __device__ __forceinline__ long lds8_read(const u8 (*lds)[64], int row, int g) {
    int a = g >> 1;
    int phys = a ^ ((row >> 1) & 3);
    return *(const long*)&lds[row][phys * 16 + (g & 1) * 8];
}

template <int BN, bool GELU, bool OUTF8>
__global__ __launch_bounds__(256) void gemm3_kernel(
    const u8* __restrict__ A, const u8* __restrict__ BT,
    const float* __restrict__ b0, const float* __restrict__ b1, const float* __restrict__ b2,
    int seg, float* __restrict__ C, u8* __restrict__ C8, int M, int N, int K) {
    __shared__ u8 Als[2][128][64];
    __shared__ u8 Bls[2][BN][64];
    int tid = threadIdx.x, lane = tid & 63, w = tid >> 6;
    int m0 = blockIdx.y * 128, n0 = blockIdx.x * BN;
    int wr = w >> 1, wc = w & 1;
    int l15 = lane & 15, q = lane >> 4;
    constexpr int NJ = BN / 32;

    f32x4 acc[4][NJ];
#pragma unroll
    for (int mi = 0; mi < 4; ++mi)
#pragma unroll
        for (int nj = 0; nj < NJ; ++nj) acc[mi][nj] = (f32x4){0.f, 0.f, 0.f, 0.f};

    stage8<128>(A, m0, K, 0, Als[0], w, lane);
    stage8<BN>(BT, n0, K, 0, Bls[0], w, lane);
    __syncthreads();
    int KT = K >> 6, cur = 0;
    for (int kt = 0; kt < KT; ++kt) {
        if (kt + 1 < KT) {
            stage8<128>(A, m0, K, (kt + 1) << 6, Als[cur ^ 1], w, lane);
            stage8<BN>(BT, n0, K, (kt + 1) << 6, Bls[cur ^ 1], w, lane);
        }
#pragma unroll
        for (int ks = 0; ks < 2; ++ks) {
            int g = ks * 4 + q;
            long bfr[NJ];
#pragma unroll
            for (int nj = 0; nj < NJ; ++nj)
                bfr[nj] = lds8_read(Bls[cur], wc * (BN / 2) + nj * 16 + l15, g);
#pragma unroll
            for (int mi = 0; mi < 4; ++mi) {
                long a = lds8_read(Als[cur], wr * 64 + mi * 16 + l15, g);
#pragma unroll
                for (int nj = 0; nj < NJ; ++nj)
                    acc[mi][nj] = mfma_fp8(a, bfr[nj], acc[mi][nj]);
            }
        }
        __syncthreads();
        cur ^= 1;
    }

    int rbase = m0 + wr * 64 + q * 4;
    int cbase = n0 + wc * (BN / 2) + l15;
#pragma unroll
    for (int mi = 0; mi < 4; ++mi) {
#pragma unroll
        for (int nj = 0; nj < NJ; ++nj) {
            int col = cbase + nj * 16;
            int cc = col;
            const float* bp;
            if (cc < seg) bp = b0;
            else if (cc < 2 * seg) { bp = b1; cc -= seg; }
            else { bp = b2; cc -= 2 * seg; }
            float bias = bp[cc];
#pragma unroll
            for (int j = 0; j < 4; ++j) {
                int row = rbase + mi * 16 + j;
                float v = acc[mi][nj][j] + bias;
                if (GELU) v = 0.5f * v * (1.0f + erff(v * 0.70710678118654752f));
                if (OUTF8) C8[(size_t)row * N + col] = f8(v);
                else       C[(size_t)row * N + col] = v;
            }
        }
    }
}

// ---------------- attention v4: 2-way kk unroll, dual accumulators ----------------
__global__ __launch_bounds__(256) void attention_kernel(
    const float* __restrict__ qkv, const int* __restrict__ mask, u8* __restrict__ ctx8) {
    int bid = blockIdx.x;
    int quarter = bid & 3;
    int bh = bid >> 2;
    int b = bh / NH_, h = bh % NH_;
    int tid = threadIdx.x;
    int q_i = quarter * 64 + (tid >> 2);
    int dq = tid & 3;
    const float* qp = qkv + (size_t)(b * TT + q_i) * 2304 + h * DH_ + dq * 16;
    float qv[16];
#pragma unroll
    for (int d = 0; d < 4; ++d) {
        float4 v = *(const float4*)(qp + 4 * d);
        qv[4*d] = v.x; qv[4*d+1] = v.y; qv[4*d+2] = v.z; qv[4*d+3] = v.w;
    }
    const float* kbase = qkv + (size_t)b * TT * 2304 + 768 + h * DH_ + dq * 16;
    const float* vbase = qkv + (size_t)b * TT * 2304 + 1536 + h * DH_ + dq * 16;
    __shared__ float bias_s[TT];
    for (int i = tid; i < TT; i += 256)
        bias_s[i] = (1.0f - (float)mask[b * TT + i]) * -10000.0f;
    __syncthreads();
    float acc0[16] = {}, acc1[16] = {};
    float l0 = 0.f, l1 = 0.f;
    for (int kk = 0; kk < TT; kk += 2) {
        const float4* kpA = (const float4*)(kbase + (size_t)kk * 2304);
        const float4* kpB = (const float4*)(kbase + (size_t)(kk + 1) * 2304);
        float4 sA = {0.f, 0.f, 0.f, 0.f}, sB = {0.f, 0.f, 0.f, 0.f};
#pragma unroll
        for (int d = 0; d < 4; ++d) {
            float4 kA = kpA[d], kB = kpB[d];
            sA.x += qv[4*d] * kA.x;   sB.x += qv[4*d] * kB.x;
            sA.y += qv[4*d+1] * kA.y; sB.y += qv[4*d+1] * kB.y;
            sA.z += qv[4*d+2] * kA.z; sB.z += qv[4*d+2] * kB.z;
            sA.w += qv[4*d+3] * kA.w; sB.w += qv[4*d+3] * kB.w;
        }
        float pA = (sA.x + sA.y) + (sA.z + sA.w);
        float pB = (sB.x + sB.y) + (sB.z + sB.w);
        pA += __shfl_xor(pA, 1); pA += __shfl_xor(pA, 2);
        pB += __shfl_xor(pB, 1); pB += __shfl_xor(pB, 2);
        float eA = __expf(pA * 0.125f + bias_s[kk]);
        float eB = __expf(pB * 0.125f + bias_s[kk + 1]);
        l0 += eA; l1 += eB;
        const float4* vpA = (const float4*)(vbase + (size_t)kk * 2304);
        const float4* vpB = (const float4*)(vbase + (size_t)(kk + 1) * 2304);
#pragma unroll
        for (int d = 0; d < 4; ++d) {
            float4 vA = vpA[d], vB = vpB[d];
            acc0[4*d]   += eA * vA.x; acc1[4*d]   += eB * vB.x;
            acc0[4*d+1] += eA * vA.y; acc1[4*d+1] += eB * vB.y;
            acc0[4*d+2] += eA * vA.z; acc1[4*d+2] += eB * vB.z;
            acc0[4*d+3] += eA * vA.w; acc1[4*d+3] += eB * vB.w;
        }
    }
    float inv = __builtin_amdgcn_rcpf(l0 + l1);
    size_t base = (size_t)(b * TT + q_i) * HH + h * DH_ + dq * 16;
#pragma unroll
    for (int d = 0; d < 4; ++d) {
        u32 w0 = pk8<false>((acc0[4*d] + acc1[4*d]) * inv,
                            (acc0[4*d+1] + acc1[4*d+1]) * inv, 0);
        w0 = pk8<true>((acc0[4*d+2] + acc1[4*d+2]) * inv,
                       (acc0[4*d+3] + acc1[4*d+3]) * inv, w0);
        *(u32*)&ctx8[base + 4*d] = w0;
    }
}

// ---------------- LSTM v13: streamed W hoisted + pinned (32 VGPR) ----------------
__global__ __launch_bounds__(1024, 4) void lstm13_kernel(
    const float* __restrict__ xg, const u8* __restrict__ wfrag8,
    const float* __restrict__ bhh_f, const float* __restrict__ bhh_b,
    float* __restrict__ hf, float* __restrict__ hb) {
    int dir = blockIdx.x;
    const u8* wf8 = wfrag8 + (size_t)dir * 262144;
    const float* bhh = dir ? bhh_b : bhh_f;
    float* hout = dir ? hb : hf;
    int tid = threadIdx.x, lane = tid & 63, wid = tid >> 6;
    __shared__ u8 wlds[4 * 64 * 512];
    __shared__ u8 h_f8[16][280];
    __shared__ u16 g_bf[1024][10];
    for (int i = tid; i < 16 * 280; i += 1024) ((u8*)h_f8)[i] = 0;
#pragma unroll
    for (int c = 0; c < 8; ++c) {
        int off = wid * 8192 + c * 1024;
        GLL16(wf8 + off + lane * 16, &wlds[off]);
    }
    // hoist step-invariant streamed W (kt4-7) into pinned registers: 16 x 8B = 32 VGPR
    long wst[4][4];
#pragma unroll
    for (int kt = 0; kt < 4; ++kt)
#pragma unroll
        for (int m = 0; m < 4; ++m) {
            wst[kt][m] = *(const long*)&wf8[(size_t)(((4 + kt) * 64) + wid * 4 + m) * 512 + lane * 8];
            asm volatile("" : "+v"(wst[kt][m]));
        }
    int l15 = lane & 15, qq = lane >> 4;
    int j = tid & 255;
    int bq = (tid >> 8) * 2;
    float bi_ = bhh[j], bf_ = bhh[256 + j], bg_ = bhh[512 + j], bo_ = bhh[768 + j];
    float c_s[2] = {0.f, 0.f};
    __syncthreads();
    for (int step = 0; step < TT; ++step) {
        int t = dir ? (TT - 1 - step) : step;
        float xgi[2], xgf[2], xgg[2], xgo[2];
#pragma unroll
        for (int bi = 0; bi < 2; ++bi) {
            size_t xa = ((size_t)((bq + bi) * TT + t)) * 2048 + (size_t)dir * 1024;
            xgi[bi] = xg[xa + j];
            xgf[bi] = xg[xa + 256 + j];
            xgg[bi] = xg[xa + 512 + j];
            xgo[bi] = xg[xa + 768 + j];
        }
        f32x4 acc[4];
#pragma unroll
        for (int m = 0; m < 4; ++m) acc[m] = (f32x4){0.f, 0.f, 0.f, 0.f};
#pragma unroll
        for (int kt = 0; kt < 4; ++kt) {
            long hfr = *(const long*)&h_f8[l15][kt * 32 + qq * 8];
#pragma unroll
            for (int m = 0; m < 4; ++m) {
                long a = *(const long*)&wlds[(size_t)(kt * 64 + wid * 4 + m) * 512 + lane * 8];
                acc[m] = mfma_fp8(a, hfr, acc[m]);
            }
        }
#pragma unroll
        for (int kt = 0; kt < 4; ++kt) {
            long hfr = *(const long*)&h_f8[l15][(4 + kt) * 32 + qq * 8];
#pragma unroll
            for (int m = 0; m < 4; ++m)
                acc[m] = mfma_fp8(wst[kt][m], hfr, acc[m]);
        }
        if (l15 < 8) {
#pragma unroll
            for (int m = 0; m < 4; ++m) {
                int R = (wid * 4 + m) * 16 + qq * 4;
#pragma unroll
                for (int jj = 0; jj < 4; ++jj)
                    g_bf[R + jj][l15] = (u16)(__float_as_uint(acc[m][jj]) >> 16);
            }
        }
        __syncthreads();
#pragma unroll
        for (int bi = 0; bi < 2; ++bi) {
            int b = bq + bi;
            float gi = xgi[bi] + bi_ + bf2f(g_bf[j][b]);
            float gf = xgf[bi] + bf_ + bf2f(g_bf[256 + j][b]);
            float gg = xgg[bi] + bg_ + bf2f(g_bf[512 + j][b]);
            float go = xgo[bi] + bo_ + bf2f(g_bf[768 + j][b]);
            float cc = sigm_fast(gf) * c_s[bi] + sigm_fast(gi) * tanh_fast(gg);
            c_s[bi] = cc;
            float hh = sigm_fast(go) * tanh_fast(cc);
            h_f8[b][j] = f8(hh);
            hout[((size_t)(b * TT + t)) * LH_ + j] = hh;
        }
        __syncthreads();
    }
}

// ---------------- classifier ----------------
__global__ __launch_bounds__(256) void clf_kernel(
    const float* __restrict__ hf, const float* __restrict__ hb,
    const float* __restrict__ W, const float* __restrict__ bias, float* __restrict__ em) {
    int idx = blockIdx.x * blockDim.x + threadIdx.x;
    if (idx >= BB * TT * KK_) return;
    int row = idx / KK_, j = idx % KK_;
    float acc = bias[j];
    const float* hfp = hf + (size_t)row * LH_;
    const float* hbp = hb + (size_t)row * LH_;
    for (int kk = 0; kk < LH_; ++kk) acc += hfp[kk] * W[kk * KK_ + j];
    for (int kk = 0; kk < LH_; ++kk) acc += hbp[kk] * W[(LH_ + kk) * KK_ + j];
    em[idx] = acc;
}

// ---------------- CRF v2 ----------------
__global__ __launch_bounds__(512) void crf2_kernel(
    const float* __restrict__ em, const int* __restrict__ labels, const int* __restrict__ mask,
    const float* __restrict__ cstart, const float* __restrict__ cend,
    const float* __restrict__ ctrans, float* __restrict__ out) {
    __shared__ float trans_s[81];
    __shared__ float res[8];
    int tid = threadIdx.x;
    int b = tid >> 6;
    int l = tid & 63;
    if (tid < 81) trans_s[tid] = ctrans[tid];
    __syncthreads();
    int lc = (l < 9) ? l : 0;
    float tcol[9];
#pragma unroll
    for (int i = 0; i < 9; ++i) tcol[i] = trans_s[i * 9 + lc];
    float alpha = (l < 9) ? cstart[lc] + em[(size_t)b * TT * KK_ + lc] : -1e30f;
    for (int t = 1; t < TT; ++t) {
        float e_t = (l < 9) ? em[((size_t)b * TT + t) * KK_ + lc] : 0.f;
        float m = -1e30f;
        float av[9];
#pragma unroll
        for (int i = 0; i < 9; ++i) {
            av[i] = __shfl(alpha, i) + tcol[i];
            m = fmaxf(m, av[i]);
        }
        float s = 0.f;
#pragma unroll
        for (int i = 0; i < 9; ++i) s += expf(av[i] - m);
        float nv = m + logf(s) + e_t;
        bool upd = (mask[b * TT + t] > 0) && (l < 9);
        alpha = upd ? nv : alpha;
    }
    float z = (l < 9) ? alpha + cend[lc] : -1e30f;
    float zm = z;
#pragma unroll
    for (int o = 32; o > 0; o >>= 1) zm = fmaxf(zm, __shfl_xor(zm, o));
    float zs = (l < 9) ? expf(z - zm) : 0.f;
#pragma unroll
    for (int o = 32; o > 0; o >>= 1) zs += __shfl_xor(zs, o);
    float logZ = zm + logf(zs);
    float sc = 0.f;
    int cnt = 0;
    for (int t = l; t < TT; t += 64) {
        cnt += mask[b * TT + t];
        if (t == 0) {
            int l0 = labels[b * TT];
            sc += cstart[l0] + em[(size_t)b * TT * KK_ + l0];
        } else {
            int lp = labels[b * TT + t - 1];
            int lt = labels[b * TT + t];
            sc += (trans_s[lp * KK_ + lt] + em[((size_t)b * TT + t) * KK_ + lt]) *
                  (float)mask[b * TT + t];
        }
    }
#pragma unroll
    for (int o = 32; o > 0; o >>= 1) { sc += __shfl_xor(sc, o); cnt += __shfl_xor(cnt, o); }
    if (l == 0) {
        int last = labels[b * TT + (cnt - 1)];
        sc += cend[last];
        res[b] = sc - logZ;
    }
    __syncthreads();
    if (tid == 0) {
        float acc = 0.f;
        for (int bb = 0; bb < BB; ++bb) acc += res[bb];
        out[0] = -acc / (float)BB;
    }
}

extern "C" void kernel_launch(void* const* d_in, const int* in_sizes, int n_in,
                              void* d_out, int out_size, void* d_ws, size_t ws_size,
                              hipStream_t stream) {
    const int* input_ids = (const int*)d_in[0];
    const int* attn_mask = (const int*)d_in[1];
    const int* labels    = (const int*)d_in[2];
    const float* word_emb = (const float*)d_in[3];
    const float* pos_emb  = (const float*)d_in[4];
    const float* type_emb = (const float*)d_in[5];
    const float* emb_ln_g = (const float*)d_in[6];
    const float* emb_ln_b = (const float*)d_in[7];
    const float* Wq = (const float*)d_in[8];
    const float* bq = (const float*)d_in[9];
    const float* Wk = (const float*)d_in[10];
    const float* bk = (const float*)d_in[11];
    const float* Wv = (const float*)d_in[12];
    const float* bv = (const float*)d_in[13];
    const float* Wo = (const float*)d_in[14];
    const float* bo = (const float*)d_in[15];
    const float* ln1_g = (const float*)d_in[16];
    const float* ln1_b = (const float*)d_in[17];
    const float* Wf1 = (const float*)d_in[18];
    const float* bf1 = (const float*)d_in[19];
    const float* Wf2 = (const float*)d_in[20];
    const float* bf2 = (const float*)d_in[21];
    const float* ln2_g = (const float*)d_in[22];
    const float* ln2_b = (const float*)d_in[23];
    const float* w_ih_f = (const float*)d_in[24];
    const float* w_hh_f = (const float*)d_in[25];
    const float* b_ih_f = (const float*)d_in[26];
    const float* b_hh_f = (const float*)d_in[27];
    const float* w_ih_b = (const float*)d_in[28];
    const float* w_hh_b = (const float*)d_in[29];
    const float* b_ih_b = (const float*)d_in[30];
    const float* b_hh_b = (const float*)d_in[31];
    const float* W_clf  = (const float*)d_in[32];
    const float* b_clf  = (const float*)d_in[33];
    const float* crf_start = (const float*)d_in[34];
    const float* crf_end   = (const float*)d_in[35];
    const float* crf_trans = (const float*)d_in[36];

    const size_t NTOK = (size_t)BB * TT;          // 2048
    const size_t SZ = NTOK * HH;                  // 1,572,864

    float* ws = (float*)d_ws;
    float* x    = ws;                              // SZ
    float* qkv  = x + SZ;                          // 2048*2304
    float* tmp  = qkv + NTOK * 2304;               // SZ
    float* ab   = tmp + SZ;                        // SZ
    float* xg   = ab + SZ;                         // 2048*2048
    u8* x_f8    = (u8*)(xg + NTOK * 2048);         // SZ bytes
    u8* ab_f8   = x_f8 + SZ;
    u8* ctx_f8  = ab_f8 + SZ;
    u8* big_f8  = ctx_f8 + SZ;                     // 2048*3072
    u8* wihT    = big_f8 + NTOK * (size_t)FF_;     // 2048*768 bytes
    u8* wfrag8  = wihT + 1572864;                  // 524,288 bytes
    u8* wbuf    = wfrag8 + 524288;                 // per-layer 7,077,888 B (or x12)
    const size_t base_off = (size_t)((u8*)wbuf - (u8*)d_ws);
    bool big = ws_size >= base_off + 12ull * 7077888ull + (1u << 20);

    float* hf = qkv;
    float* hb = qkv + 524288;
    float* em = qkv + 1048576;

    embed_ln_kernel<<<NTOK, 256, 0, stream>>>(input_ids, word_emb, pos_emb, type_emb,
                                              emb_ln_g, emb_ln_b, x, x_f8);
    prep_kernel<<<1792, 256, 0, stream>>>(w_hh_f, w_hh_b, w_ih_f, w_ih_b, wfrag8, wihT);
    if (big)
        conv_w_kernel<true><<<1728 * 12, 256, 0, stream>>>(Wq, Wk, Wv, Wo, Wf1, Wf2, wbuf);

    dim3 gQKV(2304 / 128, NTOK / 128);  // 18 x 16
    dim3 gH(HH / 64, NTOK / 128);       // 12 x 16
    dim3 gF1(FF_ / 128, NTOK / 128);    // 24 x 16
    dim3 gG(2048 / 128, NTOK / 128);    // 16 x 16

    for (int l = 0; l < NL; ++l) {
        u8* wb = big ? wbuf + (size_t)l * 7077888 : wbuf;
        if (!big)
            conv_w_kernel<false><<<1728, 256, 0, stream>>>(
                Wq + (size_t)l * HH * HH, Wk + (size_t)l * HH * HH,
                Wv + (size_t)l * HH * HH, Wo + (size_t)l * HH * HH,
                Wf1 + (size_t)l * HH * FF_, Wf2 + (size_t)l * FF_ * HH, wb);

        const float* bq_l = bq + (size_t)l * HH;
        const float* bk_l = bk + (size_t)l * HH;
        const float* bv_l = bv + (size_t)l * HH;
        const float* bo_l = bo + (size_t)l * HH;
        const float* g1 = ln1_g + (size_t)l * HH;
        const float* b1 = ln1_b + (size_t)l * HH;
        const float* bf1_l = bf1 + (size_t)l * FF_;
        const float* bf2_l = bf2 + (size_t)l * HH;
        const float* g2 = ln2_g + (size_t)l * HH;
        const float* b2 = ln2_b + (size_t)l * HH;

        gemm3_kernel<128, false, false><<<gQKV, 256, 0, stream>>>(
            x_f8, wb, bq_l, bk_l, bv_l, 768, qkv, nullptr, NTOK, 2304, HH);
        attention_kernel<<<BB * NH_ * 4, 256, 0, stream>>>(qkv, attn_mask, ctx_f8);
        gemm3_kernel<64, false, false><<<gH, 256, 0, stream>>>(
            ctx_f8, wb + 1769472, bo_l, bo_l, bo_l, 768, tmp, nullptr, NTOK, HH, HH);
        ln_residual_kernel<<<NTOK, 256, 0, stream>>>(x, tmp, g1, b1, ab, ab_f8);
        gemm3_kernel<128, true, true><<<gF1, 256, 0, stream>>>(
            ab_f8, wb + 2359296, bf1_l, bf1_l, bf1_l, FF_, nullptr, big_f8, NTOK, FF_, HH);
        gemm3_kernel<64, false, false><<<gH, 256, 0, stream>>>(
            big_f8, wb + 4718592, bf2_l, bf2_l, bf2_l, 768, tmp, nullptr, NTOK, HH, FF_);
        ln_residual_kernel<<<NTOK, 256, 0, stream>>>(ab, tmp, g2, b2, x, x_f8);
    }

    // fused LSTM input projections: xg[tok][dir*1024+g]
    gemm3_kernel<128, false, false><<<gG, 256, 0, stream>>>(
        x_f8, wihT, b_ih_f, b_ih_b, b_ih_b, 1024, xg, nullptr, NTOK, 2048, HH);

    lstm13_kernel<<<2, 1024, 0, stream>>>(xg, wfrag8, b_hh_f, b_hh_b, hf, hb);
    clf_kernel<<<(BB * TT * KK_ + 255) / 256, 256, 0, stream>>>(hf, hb, W_clf, b_clf, em);
    crf2_kernel<<<1, 512, 0, stream>>>(em, labels, attn_mask, crf_start, crf_end, crf_trans,
                                       (float*)d_out);
}

// Round 18
// 4864.393 us; speedup vs baseline: 4.4993x; 1.0162x over previous
//
#include <hip/hip_runtime.h>
#include <math.h>

#define BB 8
#define TT 256
#define HH 768
#define NL 12
#define NH_ 12
#define DH_ 64
#define FF_ 3072
#define LH_ 256
#define KK_ 9

typedef unsigned char u8;
typedef unsigned short u16;
typedef unsigned int u32;
typedef __attribute__((ext_vector_type(4))) float f32x4;

static __device__ __forceinline__ float sigm_fast(float x) {
    return __builtin_amdgcn_rcpf(1.0f + __expf(-x));
}
static __device__ __forceinline__ float tanh_fast(float x) {
    return 1.0f - 2.0f * __builtin_amdgcn_rcpf(1.0f + __expf(2.0f * x));
}
static __device__ __forceinline__ float bf2f(u16 v) {
    return __uint_as_float(((u32)v) << 16);
}
template <bool HI>
static __device__ __forceinline__ u32 pk8(float a, float b, u32 old) {
    return (u32)__builtin_amdgcn_cvt_pk_fp8_f32(a, b, (int)old, HI);
}
static __device__ __forceinline__ u8 f8(float v) {
    return (u8)(pk8<false>(v, v, 0) & 0xff);
}

static __device__ __forceinline__ f32x4 mfma_fp8(long a, long b, f32x4 c) {
    return __builtin_amdgcn_mfma_f32_16x16x32_fp8_fp8(a, b, c, 0, 0, 0);
}

#define GLL16(gp, lp) __builtin_amdgcn_global_load_lds( \
    (const __attribute__((address_space(1))) void*)(gp), \
    (__attribute__((address_space(3))) void*)(lp), 16, 0, 0)

// ---------------- block reduce ----------------
static __device__ __forceinline__ float block_sum(float v, float* red) {
    int tid = threadIdx.x;
#pragma unroll
    for (int o = 32; o > 0; o >>= 1) v += __shfl_xor(v, o);
    if ((tid & 63) == 0) red[tid >> 6] = v;
    __syncthreads();
    return red[0] + red[1] + red[2] + red[3];
}

// ---------------- embedding + LN -> fp32 + fp8 ----------------
__global__ __launch_bounds__(256) void embed_ln_kernel(
    const int* __restrict__ ids, const float* __restrict__ we, const float* __restrict__ pe,
    const float* __restrict__ te, const float* __restrict__ g, const float* __restrict__ b,
    float* __restrict__ out, u8* __restrict__ out8) {
    int row = blockIdx.x;
    int t = row % TT;
    int id = ids[row];
    __shared__ float xr[HH];
    __shared__ float reda[8], redb[8];
    int tid = threadIdx.x;
    float s = 0.f;
    for (int h = tid; h < HH; h += 256) {
        float v = we[(size_t)id * HH + h] + pe[(size_t)t * HH + h] + te[h];
        xr[h] = v; s += v;
    }
    float mean = block_sum(s, reda) * (1.0f / HH);
    float vs = 0.f;
    for (int h = tid; h < HH; h += 256) { float d = xr[h] - mean; vs += d * d; }
    float var = block_sum(vs, redb) * (1.0f / HH);
    float rstd = rsqrtf(var + 1e-12f);
    for (int h = tid; h < HH; h += 256) {
        float v = (xr[h] - mean) * rstd * g[h] + b[h];
        out[(size_t)row * HH + h] = v;
        out8[(size_t)row * HH + h] = f8(v);
    }
}

// ---------------- LN(a + f) -> fp32 + fp8 ----------------
__global__ __launch_bounds__(256) void ln_residual_kernel(
    const float* __restrict__ a, const float* __restrict__ f,
    const float* __restrict__ g, const float* __restrict__ b,
    float* __restrict__ out, u8* __restrict__ out8) {
    int row = blockIdx.x;
    __shared__ float xr[HH];
    __shared__ float reda[8], redb[8];
    int tid = threadIdx.x;
    float s = 0.f;
    for (int h = tid; h < HH; h += 256) {
        float v = a[(size_t)row * HH + h] + f[(size_t)row * HH + h];
        xr[h] = v; s += v;
    }
    float mean = block_sum(s, reda) * (1.0f / HH);
    float vs = 0.f;
    for (int h = tid; h < HH; h += 256) { float d = xr[h] - mean; vs += d * d; }
    float var = block_sum(vs, redb) * (1.0f / HH);
    float rstd = rsqrtf(var + 1e-12f);
    for (int h = tid; h < HH; h += 256) {
        float v = (xr[h] - mean) * rstd * g[h] + b[h];
        out[(size_t)row * HH + h] = v;
        out8[(size_t)row * HH + h] = f8(v);
    }
}

// ---------------- weight transpose+convert fp32 -> fp8 [N][K] ----------------
template <bool LAYERS12>
__global__ __launch_bounds__(256) void conv_w_kernel(
    const float* __restrict__ Wq, const float* __restrict__ Wk,
    const float* __restrict__ Wv, const float* __restrict__ Wo,
    const float* __restrict__ Wf1, const float* __restrict__ Wf2,
    u8* __restrict__ wbuf) {
    __shared__ float tile[64][65];
    int bid = blockIdx.x;
    int layer = 0;
    if (LAYERS12) { layer = bid / 1728; bid -= layer * 1728; }
    size_t woff = (size_t)layer * 7077888;
    size_t hh2 = (size_t)layer * HH * HH;
    size_t hf2 = (size_t)layer * HH * FF_;
    const float* src; u8* dst; int R, C, bx, by;
    if (bid < 576) {
        int m = bid / 144, t = bid % 144;
        src = (m == 0 ? Wq + hh2 : m == 1 ? Wk + hh2 : m == 2 ? Wv + hh2 : Wo + hh2);
        dst = wbuf + woff + (size_t)m * 589824;
        R = 768; C = 768; bx = t % 12; by = t / 12;
    } else if (bid < 1152) {
        int t = bid - 576;
        src = Wf1 + hf2; dst = wbuf + woff + 2359296; R = 768; C = 3072;
        bx = t % 48; by = t / 48;
    } else {
        int t = bid - 1152;
        src = Wf2 + hf2; dst = wbuf + woff + 4718592; R = 3072; C = 768;
        bx = t % 12; by = t / 12;
    }
    int tx = threadIdx.x & 15, ty = threadIdx.x >> 4;   // 16 x 16
#pragma unroll
    for (int p = 0; p < 4; ++p) {
        int row = p * 16 + ty;
        float4 v = *(const float4*)&src[(size_t)(by * 64 + row) * C + bx * 64 + tx * 4];
        tile[row][tx * 4 + 0] = v.x; tile[row][tx * 4 + 1] = v.y;
        tile[row][tx * 4 + 2] = v.z; tile[row][tx * 4 + 3] = v.w;
    }
    __syncthreads();
    int rq = (threadIdx.x & 15) * 4, cc0 = threadIdx.x >> 4;   // 16 cols/pass
#pragma unroll
    for (int p = 0; p < 4; ++p) {
        int cc = p * 16 + cc0;
        u32 w0 = pk8<false>(tile[rq][cc], tile[rq + 1][cc], 0);
        w0 = pk8<true>(tile[rq + 2][cc], tile[rq + 3][cc], w0);
        *(u32*)&dst[(size_t)(bx * 64 + cc) * R + by * 64 + rq] = w0;
    }
}

// ---------------- prologue: pack w_hh fp8 frags + convert w_ih -> fp8 ----------------
__global__ __launch_bounds__(256) void prep_kernel(
    const float* __restrict__ whf, const float* __restrict__ whb,
    const float* __restrict__ wif, const float* __restrict__ wib,
    u8* __restrict__ wfrag8, u8* __restrict__ wihT) {
    int bid = blockIdx.x;
    int tid = threadIdx.x;
    if (bid < 256) {
        int idx = bid * 256 + tid;
        int dir = idx >> 15;
        int kt  = (idx >> 12) & 7;
        int mt  = (idx >> 6) & 63;
        int lane = idx & 63;
        const float* W = dir ? whb : whf;
        int row = mt * 16 + (lane & 15);
        int k = kt * 32 + (lane >> 4) * 8;
        const float* src = W + (size_t)row * LH_ + k;
        u32 w0 = pk8<false>(src[0], src[1], 0);
        w0 = pk8<true>(src[2], src[3], w0);
        u32 w1 = pk8<false>(src[4], src[5], 0);
        w1 = pk8<true>(src[6], src[7], w1);
        uint2 pk; pk.x = w0; pk.y = w1;
        size_t base = (size_t)(((dir * 8 + kt) * 64 + mt) * 64 + lane) * 8;
        *(uint2*)&wfrag8[base] = pk;
    } else {
        int which = (bid < 1024) ? 0 : 1;
        const float* src = which ? wib : wif;
        u8* dst = wihT + (size_t)which * 786432;
        int i = (bid - (which ? 1024 : 256)) * 256 + tid;
        float4 v = *(const float4*)&src[(size_t)i * 4];
        u32 w0 = pk8<false>(v.x, v.y, 0);
        w0 = pk8<true>(v.z, v.w, w0);
        *(u32*)&dst[(size_t)i * 4] = w0;
    }
}

// ---------------- GEMM v4: fp8, templated BM/BN, 16B-XOR swizzle, dbuf ----------------
template <int BROWS>
__device__ __forceinline__ void stage8(
    const u8* __restrict__ S, int r0, int K, int k0, u8 (*lds)[64], int w, int lane) {
    int srl = lane >> 2;       // 0..15
    int p = lane & 3;
    constexpr int INSTS = BROWS / 64;   // per wave
#pragma unroll
    for (int i = 0; i < INSTS; ++i) {
        int row0 = (w * INSTS + i) * 16;
        int srow = row0 + srl;
        int a = p ^ ((srow >> 1) & 3);
        GLL16(S + (size_t)(r0 + srow) * K + k0 + a * 16, &lds[row0][0]);
    }
}

static __device__ __forceinline__ long lds8_read(const u8 (*lds)[64], int row, int g) {
    int a = g >> 1;
    int phys = a ^ ((row >> 1) & 3);
    return *(const long*)&lds[row][phys * 16 + (g & 1) * 8];
}

template <int BM, int BN, bool GELU, bool OUTF8>
__global__ __launch_bounds__(256) void gemm3_kernel(
    const u8* __restrict__ A, const u8* __restrict__ BT,
    const float* __restrict__ b0, const float* __restrict__ b1, const float* __restrict__ b2,
    int seg, float* __restrict__ C, u8* __restrict__ C8, int M, int N, int K) {
    __shared__ u8 Als[2][BM][64];
    __shared__ u8 Bls[2][BN][64];
    int tid = threadIdx.x, lane = tid & 63, w = tid >> 6;
    int m0 = blockIdx.y * BM, n0 = blockIdx.x * BN;
    int wr = w >> 1, wc = w & 1;
    int l15 = lane & 15, q = lane >> 4;
    constexpr int MI = BM / 32;     // 16-row frags per wave
    constexpr int NJ = BN / 32;

    f32x4 acc[MI][NJ];
#pragma unroll
    for (int mi = 0; mi < MI; ++mi)
#pragma unroll
        for (int nj = 0; nj < NJ; ++nj) acc[mi][nj] = (f32x4){0.f, 0.f, 0.f, 0.f};

    stage8<BM>(A, m0, K, 0, Als[0], w, lane);
    stage8<BN>(BT, n0, K, 0, Bls[0], w, lane);
    __syncthreads();
    int KT = K >> 6, cur = 0;
    for (int kt = 0; kt < KT; ++kt) {
        if (kt + 1 < KT) {
            stage8<BM>(A, m0, K, (kt + 1) << 6, Als[cur ^ 1], w, lane);
            stage8<BN>(BT, n0, K, (kt + 1) << 6, Bls[cur ^ 1], w, lane);
        }
#pragma unroll
        for (int ks = 0; ks < 2; ++ks) {
            int g = ks * 4 + q;
            long bfr[NJ];
#pragma unroll
            for (int nj = 0; nj < NJ; ++nj)
                bfr[nj] = lds8_read(Bls[cur], wc * (BN / 2) + nj * 16 + l15, g);
#pragma unroll
            for (int mi = 0; mi < MI; ++mi) {
                long a = lds8_read(Als[cur], wr * (BM / 2) + mi * 16 + l15, g);
#pragma unroll
                for (int nj = 0; nj < NJ; ++nj)
                    acc[mi][nj] = mfma_fp8(a, bfr[nj], acc[mi][nj]);
            }
        }
        __syncthreads();
        cur ^= 1;
    }

    int rbase = m0 + wr * (BM / 2) + q * 4;
    int cbase = n0 + wc * (BN / 2) + l15;
#pragma unroll
    for (int mi = 0; mi < MI; ++mi) {
#pragma unroll
        for (int nj = 0; nj < NJ; ++nj) {
            int col = cbase + nj * 16;
            int cc = col;
            const float* bp;
            if (cc < seg) bp = b0;
            else if (cc < 2 * seg) { bp = b1; cc -= seg; }
            else { bp = b2; cc -= 2 * seg; }
            float bias = bp[cc];
#pragma unroll
            for (int j = 0; j < 4; ++j) {
                int row = rbase + mi * 16 + j;
                float v = acc[mi][nj][j] + bias;
                if (GELU) v = 0.5f * v * (1.0f + erff(v * 0.70710678118654752f));
                if (OUTF8) C8[(size_t)row * N + col] = f8(v);
                else       C[(size_t)row * N + col] = v;
            }
        }
    }
}

// ---------------- attention v4: 2-way kk unroll, dual accumulators ----------------
__global__ __launch_bounds__(256) void attention_kernel(
    const float* __restrict__ qkv, const int* __restrict__ mask, u8* __restrict__ ctx8) {
    int bid = blockIdx.x;
    int quarter = bid & 3;
    int bh = bid >> 2;
    int b = bh / NH_, h = bh % NH_;
    int tid = threadIdx.x;
    int q_i = quarter * 64 + (tid >> 2);
    int dq = tid & 3;
    const float* qp = qkv + (size_t)(b * TT + q_i) * 2304 + h * DH_ + dq * 16;
    float qv[16];
#pragma unroll
    for (int d = 0; d < 4; ++d) {
        float4 v = *(const float4*)(qp + 4 * d);
        qv[4*d] = v.x; qv[4*d+1] = v.y; qv[4*d+2] = v.z; qv[4*d+3] = v.w;
    }
    const float* kbase = qkv + (size_t)b * TT * 2304 + 768 + h * DH_ + dq * 16;
    const float* vbase = qkv + (size_t)b * TT * 2304 + 1536 + h * DH_ + dq * 16;
    __shared__ float bias_s[TT];
    for (int i = tid; i < TT; i += 256)
        bias_s[i] = (1.0f - (float)mask[b * TT + i]) * -10000.0f;
    __syncthreads();
    float acc0[16] = {}, acc1[16] = {};
    float l0 = 0.f, l1 = 0.f;
    for (int kk = 0; kk < TT; kk += 2) {
        const float4* kpA = (const float4*)(kbase + (size_t)kk * 2304);
        const float4* kpB = (const float4*)(kbase + (size_t)(kk + 1) * 2304);
        float4 sA = {0.f, 0.f, 0.f, 0.f}, sB = {0.f, 0.f, 0.f, 0.f};
#pragma unroll
        for (int d = 0; d < 4; ++d) {
            float4 kA = kpA[d], kB = kpB[d];
            sA.x += qv[4*d] * kA.x;   sB.x += qv[4*d] * kB.x;
            sA.y += qv[4*d+1] * kA.y; sB.y += qv[4*d+1] * kB.y;
            sA.z += qv[4*d+2] * kA.z; sB.z += qv[4*d+2] * kB.z;
            sA.w += qv[4*d+3] * kA.w; sB.w += qv[4*d+3] * kB.w;
        }
        float pA = (sA.x + sA.y) + (sA.z + sA.w);
        float pB = (sB.x + sB.y) + (sB.z + sB.w);
        pA += __shfl_xor(pA, 1); pA += __shfl_xor(pA, 2);
        pB += __shfl_xor(pB, 1); pB += __shfl_xor(pB, 2);
        float eA = __expf(pA * 0.125f + bias_s[kk]);
        float eB = __expf(pB * 0.125f + bias_s[kk + 1]);
        l0 += eA; l1 += eB;
        const float4* vpA = (const float4*)(vbase + (size_t)kk * 2304);
        const float4* vpB = (const float4*)(vbase + (size_t)(kk + 1) * 2304);
#pragma unroll
        for (int d = 0; d < 4; ++d) {
            float4 vA = vpA[d], vB = vpB[d];
            acc0[4*d]   += eA * vA.x; acc1[4*d]   += eB * vB.x;
            acc0[4*d+1] += eA * vA.y; acc1[4*d+1] += eB * vB.y;
            acc0[4*d+2] += eA * vA.z; acc1[4*d+2] += eB * vB.z;
            acc0[4*d+3] += eA * vA.w; acc1[4*d+3] += eB * vB.w;
        }
    }
    float inv = __builtin_amdgcn_rcpf(l0 + l1);
    size_t base = (size_t)(b * TT + q_i) * HH + h * DH_ + dq * 16;
#pragma unroll
    for (int d = 0; d < 4; ++d) {
        u32 w0 = pk8<false>((acc0[4*d] + acc1[4*d]) * inv,
                            (acc0[4*d+1] + acc1[4*d+1]) * inv, 0);
        w0 = pk8<true>((acc0[4*d+2] + acc1[4*d+2]) * inv,
                       (acc0[4*d+3] + acc1[4*d+3]) * inv, w0);
        *(u32*)&ctx8[base + 4*d] = w0;
    }
}

// ---------------- LSTM v13: streamed W hoisted + pinned ----------------
__global__ __launch_bounds__(1024, 4) void lstm13_kernel(
    const float* __restrict__ xg, const u8* __restrict__ wfrag8,
    const float* __restrict__ bhh_f, const float* __restrict__ bhh_b,
    float* __restrict__ hf, float* __restrict__ hb) {
    int dir = blockIdx.x;
    const u8* wf8 = wfrag8 + (size_t)dir * 262144;
    const float* bhh = dir ? bhh_b : bhh_f;
    float* hout = dir ? hb : hf;
    int tid = threadIdx.x, lane = tid & 63, wid = tid >> 6;
    __shared__ u8 wlds[4 * 64 * 512];
    __shared__ u8 h_f8[16][280];
    __shared__ u16 g_bf[1024][10];
    for (int i = tid; i < 16 * 280; i += 1024) ((u8*)h_f8)[i] = 0;
#pragma unroll
    for (int c = 0; c < 8; ++c) {
        int off = wid * 8192 + c * 1024;
        GLL16(wf8 + off + lane * 16, &wlds[off]);
    }
    long wst[4][4];
#pragma unroll
    for (int kt = 0; kt < 4; ++kt)
#pragma unroll
        for (int m = 0; m < 4; ++m) {
            wst[kt][m] = *(const long*)&wf8[(size_t)(((4 + kt) * 64) + wid * 4 + m) * 512 + lane * 8];
            asm volatile("" : "+v"(wst[kt][m]));
        }
    int l15 = lane & 15, qq = lane >> 4;
    int j = tid & 255;
    int bq = (tid >> 8) * 2;
    float bi_ = bhh[j], bf_ = bhh[256 + j], bg_ = bhh[512 + j], bo_ = bhh[768 + j];
    float c_s[2] = {0.f, 0.f};
    __syncthreads();
    for (int step = 0; step < TT; ++step) {
        int t = dir ? (TT - 1 - step) : step;
        float xgi[2], xgf[2], xgg[2], xgo[2];
#pragma unroll
        for (int bi = 0; bi < 2; ++bi) {
            size_t xa = ((size_t)((bq + bi) * TT + t)) * 2048 + (size_t)dir * 1024;
            xgi[bi] = xg[xa + j];
            xgf[bi] = xg[xa + 256 + j];
            xgg[bi] = xg[xa + 512 + j];
            xgo[bi] = xg[xa + 768 + j];
        }
        f32x4 acc[4];
#pragma unroll
        for (int m = 0; m < 4; ++m) acc[m] = (f32x4){0.f, 0.f, 0.f, 0.f};
#pragma unroll
        for (int kt = 0; kt < 4; ++kt) {
            long hfr = *(const long*)&h_f8[l15][kt * 32 + qq * 8];
#pragma unroll
            for (int m = 0; m < 4; ++m) {
                long a = *(const long*)&wlds[(size_t)(kt * 64 + wid * 4 + m) * 512 + lane * 8];
                acc[m] = mfma_fp8(a, hfr, acc[m]);
            }
        }
#pragma unroll
        for (int kt = 0; kt < 4; ++kt) {
            long hfr = *(const long*)&h_f8[l15][(4 + kt) * 32 + qq * 8];
#pragma unroll
            for (int m = 0; m < 4; ++m)
                acc[m] = mfma_fp8(wst[kt][m], hfr, acc[m]);
        }
        if (l15 < 8) {
#pragma unroll
            for (int m = 0; m < 4; ++m) {
                int R = (wid * 4 + m) * 16 + qq * 4;
#pragma unroll
                for (int jj = 0; jj < 4; ++jj)
                    g_bf[R + jj][l15] = (u16)(__float_as_uint(acc[m][jj]) >> 16);
            }
        }
        __syncthreads();
#pragma unroll
        for (int bi = 0; bi < 2; ++bi) {
            int b = bq + bi;
            float gi = xgi[bi] + bi_ + bf2f(g_bf[j][b]);
            float gf = xgf[bi] + bf_ + bf2f(g_bf[256 + j][b]);
            float gg = xgg[bi] + bg_ + bf2f(g_bf[512 + j][b]);
            float go = xgo[bi] + bo_ + bf2f(g_bf[768 + j][b]);
            float cc = sigm_fast(gf) * c_s[bi] + sigm_fast(gi) * tanh_fast(gg);
            c_s[bi] = cc;
            float hh = sigm_fast(go) * tanh_fast(cc);
            h_f8[b][j] = f8(hh);
            hout[((size_t)(b * TT + t)) * LH_ + j] = hh;
        }
        __syncthreads();
    }
}

// ---------------- classifier ----------------
__global__ __launch_bounds__(256) void clf_kernel(
    const float* __restrict__ hf, const float* __restrict__ hb,
    const float* __restrict__ W, const float* __restrict__ bias, float* __restrict__ em) {
    int idx = blockIdx.x * blockDim.x + threadIdx.x;
    if (idx >= BB * TT * KK_) return;
    int row = idx / KK_, j = idx % KK_;
    float acc = bias[j];
    const float* hfp = hf + (size_t)row * LH_;
    const float* hbp = hb + (size_t)row * LH_;
    for (int kk = 0; kk < LH_; ++kk) acc += hfp[kk] * W[kk * KK_ + j];
    for (int kk = 0; kk < LH_; ++kk) acc += hbp[kk] * W[(LH_ + kk) * KK_ + j];
    em[idx] = acc;
}

// ---------------- CRF v2 ----------------
__global__ __launch_bounds__(512) void crf2_kernel(
    const float* __restrict__ em, const int* __restrict__ labels, const int* __restrict__ mask,
    const float* __restrict__ cstart, const float* __restrict__ cend,
    const float* __restrict__ ctrans, float* __restrict__ out) {
    __shared__ float trans_s[81];
    __shared__ float res[8];
    int tid = threadIdx.x;
    int b = tid >> 6;
    int l = tid & 63;
    if (tid < 81) trans_s[tid] = ctrans[tid];
    __syncthreads();
    int lc = (l < 9) ? l : 0;
    float tcol[9];
#pragma unroll
    for (int i = 0; i < 9; ++i) tcol[i] = trans_s[i * 9 + lc];
    float alpha = (l < 9) ? cstart[lc] + em[(size_t)b * TT * KK_ + lc] : -1e30f;
    for (int t = 1; t < TT; ++t) {
        float e_t = (l < 9) ? em[((size_t)b * TT + t) * KK_ + lc] : 0.f;
        float m = -1e30f;
        float av[9];
#pragma unroll
        for (int i = 0; i < 9; ++i) {
            av[i] = __shfl(alpha, i) + tcol[i];
            m = fmaxf(m, av[i]);
        }
        float s = 0.f;
#pragma unroll
        for (int i = 0; i < 9; ++i) s += expf(av[i] - m);
        float nv = m + logf(s) + e_t;
        bool upd = (mask[b * TT + t] > 0) && (l < 9);
        alpha = upd ? nv : alpha;
    }
    float z = (l < 9) ? alpha + cend[lc] : -1e30f;
    float zm = z;
#pragma unroll
    for (int o = 32; o > 0; o >>= 1) zm = fmaxf(zm, __shfl_xor(zm, o));
    float zs = (l < 9) ? expf(z - zm) : 0.f;
#pragma unroll
    for (int o = 32; o > 0; o >>= 1) zs += __shfl_xor(zs, o);
    float logZ = zm + logf(zs);
    float sc = 0.f;
    int cnt = 0;
    for (int t = l; t < TT; t += 64) {
        cnt += mask[b * TT + t];
        if (t == 0) {
            int l0 = labels[b * TT];
            sc += cstart[l0] + em[(size_t)b * TT * KK_ + l0];
        } else {
            int lp = labels[b * TT + t - 1];
            int lt = labels[b * TT + t];
            sc += (trans_s[lp * KK_ + lt] + em[((size_t)b * TT + t) * KK_ + lt]) *
                  (float)mask[b * TT + t];
        }
    }
#pragma unroll
    for (int o = 32; o > 0; o >>= 1) { sc += __shfl_xor(sc, o); cnt += __shfl_xor(cnt, o); }
    if (l == 0) {
        int last = labels[b * TT + (cnt - 1)];
        sc += cend[last];
        res[b] = sc - logZ;
    }
    __syncthreads();
    if (tid == 0) {
        float acc = 0.f;
        for (int bb = 0; bb < BB; ++bb) acc += res[bb];
        out[0] = -acc / (float)BB;
    }
}

extern "C" void kernel_launch(void* const* d_in, const int* in_sizes, int n_in,
                              void* d_out, int out_size, void* d_ws, size_t ws_size,
                              hipStream_t stream) {
    const int* input_ids = (const int*)d_in[0];
    const int* attn_mask = (const int*)d_in[1];
    const int* labels    = (const int*)d_in[2];
    const float* word_emb = (const float*)d_in[3];
    const float* pos_emb  = (const float*)d_in[4];
    const float* type_emb = (const float*)d_in[5];
    const float* emb_ln_g = (const float*)d_in[6];
    const float* emb_ln_b = (const float*)d_in[7];
    const float* Wq = (const float*)d_in[8];
    const float* bq = (const float*)d_in[9];
    const float* Wk = (const float*)d_in[10];
    const float* bk = (const float*)d_in[11];
    const float* Wv = (const float*)d_in[12];
    const float* bv = (const float*)d_in[13];
    const float* Wo = (const float*)d_in[14];
    const float* bo = (const float*)d_in[15];
    const float* ln1_g = (const float*)d_in[16];
    const float* ln1_b = (const float*)d_in[17];
    const float* Wf1 = (const float*)d_in[18];
    const float* bf1 = (const float*)d_in[19];
    const float* Wf2 = (const float*)d_in[20];
    const float* bf2 = (const float*)d_in[21];
    const float* ln2_g = (const float*)d_in[22];
    const float* ln2_b = (const float*)d_in[23];
    const float* w_ih_f = (const float*)d_in[24];
    const float* w_hh_f = (const float*)d_in[25];
    const float* b_ih_f = (const float*)d_in[26];
    const float* b_hh_f = (const float*)d_in[27];
    const float* w_ih_b = (const float*)d_in[28];
    const float* w_hh_b = (const float*)d_in[29];
    const float* b_ih_b = (const float*)d_in[30];
    const float* b_hh_b = (const float*)d_in[31];
    const float* W_clf  = (const float*)d_in[32];
    const float* b_clf  = (const float*)d_in[33];
    const float* crf_start = (const float*)d_in[34];
    const float* crf_end   = (const float*)d_in[35];
    const float* crf_trans = (const float*)d_in[36];

    const size_t NTOK = (size_t)BB * TT;          // 2048
    const size_t SZ = NTOK * HH;                  // 1,572,864

    float* ws = (float*)d_ws;
    float* x    = ws;                              // SZ
    float* qkv  = x + SZ;                          // 2048*2304
    float* tmp  = qkv + NTOK * 2304;               // SZ
    float* ab   = tmp + SZ;                        // SZ
    float* xg   = ab + SZ;                         // 2048*2048
    u8* x_f8    = (u8*)(xg + NTOK * 2048);         // SZ bytes
    u8* ab_f8   = x_f8 + SZ;
    u8* ctx_f8  = ab_f8 + SZ;
    u8* big_f8  = ctx_f8 + SZ;                     // 2048*3072
    u8* wihT    = big_f8 + NTOK * (size_t)FF_;     // 2048*768 bytes
    u8* wfrag8  = wihT + 1572864;                  // 524,288 bytes
    u8* wbuf    = wfrag8 + 524288;                 // per-layer 7,077,888 B (or x12)
    const size_t base_off = (size_t)((u8*)wbuf - (u8*)d_ws);
    bool big = ws_size >= base_off + 12ull * 7077888ull + (1u << 20);

    float* hf = qkv;
    float* hb = qkv + 524288;
    float* em = qkv + 1048576;

    embed_ln_kernel<<<NTOK, 256, 0, stream>>>(input_ids, word_emb, pos_emb, type_emb,
                                              emb_ln_g, emb_ln_b, x, x_f8);
    prep_kernel<<<1792, 256, 0, stream>>>(w_hh_f, w_hh_b, w_ih_f, w_ih_b, wfrag8, wihT);
    if (big)
        conv_w_kernel<true><<<1728 * 12, 256, 0, stream>>>(Wq, Wk, Wv, Wo, Wf1, Wf2, wbuf);

    dim3 gQKV(2304 / 128, NTOK / 128);  // 18 x 16
    dim3 gH(HH / 64, NTOK / 64);        // 12 x 32  (64x64 tiles)
    dim3 gF1(FF_ / 128, NTOK / 128);    // 24 x 16
    dim3 gG(2048 / 128, NTOK / 128);    // 16 x 16

    for (int l = 0; l < NL; ++l) {
        u8* wb = big ? wbuf + (size_t)l * 7077888 : wbuf;
        if (!big)
            conv_w_kernel<false><<<1728, 256, 0, stream>>>(
                Wq + (size_t)l * HH * HH, Wk + (size_t)l * HH * HH,
                Wv + (size_t)l * HH * HH, Wo + (size_t)l * HH * HH,
                Wf1 + (size_t)l * HH * FF_, Wf2 + (size_t)l * FF_ * HH, wb);

        const float* bq_l = bq + (size_t)l * HH;
        const float* bk_l = bk + (size_t)l * HH;
        const float* bv_l = bv + (size_t)l * HH;
        const float* bo_l = bo + (size_t)l * HH;
        const float* g1 = ln1_g + (size_t)l * HH;
        const float* b1 = ln1_b + (size_t)l * HH;
        const float* bf1_l = bf1 + (size_t)l * FF_;
        const float* bf2_l = bf2 + (size_t)l * HH;
        const float* g2 = ln2_g + (size_t)l * HH;
        const float* b2 = ln2_b + (size_t)l * HH;

        gemm3_kernel<128, 128, false, false><<<gQKV, 256, 0, stream>>>(
            x_f8, wb, bq_l, bk_l, bv_l, 768, qkv, nullptr, NTOK, 2304, HH);
        attention_kernel<<<BB * NH_ * 4, 256, 0, stream>>>(qkv, attn_mask, ctx_f8);
        gemm3_kernel<64, 64, false, false><<<gH, 256, 0, stream>>>(
            ctx_f8, wb + 1769472, bo_l, bo_l, bo_l, 768, tmp, nullptr, NTOK, HH, HH);
        ln_residual_kernel<<<NTOK, 256, 0, stream>>>(x, tmp, g1, b1, ab, ab_f8);
        gemm3_kernel<128, 128, true, true><<<gF1, 256, 0, stream>>>(
            ab_f8, wb + 2359296, bf1_l, bf1_l, bf1_l, FF_, nullptr, big_f8, NTOK, FF_, HH);
        gemm3_kernel<64, 64, false, false><<<gH, 256, 0, stream>>>(
            big_f8, wb + 4718592, bf2_l, bf2_l, bf2_l, 768, tmp, nullptr, NTOK, HH, FF_);
        ln_residual_kernel<<<NTOK, 256, 0, stream>>>(ab, tmp, g2, b2, x, x_f8);
    }

    // fused LSTM input projections: xg[tok][dir*1024+g]
    gemm3_kernel<128, 128, false, false><<<gG, 256, 0, stream>>>(
        x_f8, wihT, b_ih_f, b_ih_b, b_ih_b, 1024, xg, nullptr, NTOK, 2048, HH);

    lstm13_kernel<<<2, 1024, 0, stream>>>(xg, wfrag8, b_hh_f, b_hh_b, hf, hb);
    clf_kernel<<<(BB * TT * KK_ + 255) / 256, 256, 0, stream>>>(hf, hb, W_clf, b_clf, em);
    crf2_kernel<<<1, 512, 0, stream>>>(em, labels, attn_mask, crf_start, crf_end, crf_trans,
                                       (float*)d_out);
}

// Round 19
// 4790.239 us; speedup vs baseline: 4.5689x; 1.0155x over previous
//
#include <hip/hip_runtime.h>
#include <math.h>

#define BB 8
#define TT 256
#define HH 768
#define NL 12
#define NH_ 12
#define DH_ 64
#define FF_ 3072
#define LH_ 256
#define KK_ 9

typedef unsigned char u8;
typedef unsigned short u16;
typedef unsigned int u32;
typedef __attribute__((ext_vector_type(4))) float f32x4;

static __device__ __forceinline__ float sigm_fast(float x) {
    return __builtin_amdgcn_rcpf(1.0f + __expf(-x));
}
static __device__ __forceinline__ float tanh_fast(float x) {
    return 1.0f - 2.0f * __builtin_amdgcn_rcpf(1.0f + __expf(2.0f * x));
}
static __device__ __forceinline__ float bf2f(u16 v) {
    return __uint_as_float(((u32)v) << 16);
}
template <bool HI>
static __device__ __forceinline__ u32 pk8(float a, float b, u32 old) {
    return (u32)__builtin_amdgcn_cvt_pk_fp8_f32(a, b, (int)old, HI);
}
static __device__ __forceinline__ u8 f8(float v) {
    return (u8)(pk8<false>(v, v, 0) & 0xff);
}

static __device__ __forceinline__ f32x4 mfma_fp8(long a, long b, f32x4 c) {
    return __builtin_amdgcn_mfma_f32_16x16x32_fp8_fp8(a, b, c, 0, 0, 0);
}

#define GLL16(gp, lp) __builtin_amdgcn_global_load_lds( \
    (const __attribute__((address_space(1))) void*)(gp), \
    (__attribute__((address_space(3))) void*)(lp), 16, 0, 0)

// ---------------- block reduce ----------------
static __device__ __forceinline__ float block_sum(float v, float* red) {
    int tid = threadIdx.x;
#pragma unroll
    for (int o = 32; o > 0; o >>= 1) v += __shfl_xor(v, o);
    if ((tid & 63) == 0) red[tid >> 6] = v;
    __syncthreads();
    return red[0] + red[1] + red[2] + red[3];
}

// ---------------- embedding + LN -> fp32 + fp8 ----------------
__global__ __launch_bounds__(256) void embed_ln_kernel(
    const int* __restrict__ ids, const float* __restrict__ we, const float* __restrict__ pe,
    const float* __restrict__ te, const float* __restrict__ g, const float* __restrict__ b,
    float* __restrict__ out, u8* __restrict__ out8) {
    int row = blockIdx.x;
    int t = row % TT;
    int id = ids[row];
    __shared__ float xr[HH];
    __shared__ float reda[8], redb[8];
    int tid = threadIdx.x;
    float s = 0.f;
    for (int h = tid; h < HH; h += 256) {
        float v = we[(size_t)id * HH + h] + pe[(size_t)t * HH + h] + te[h];
        xr[h] = v; s += v;
    }
    float mean = block_sum(s, reda) * (1.0f / HH);
    float vs = 0.f;
    for (int h = tid; h < HH; h += 256) { float d = xr[h] - mean; vs += d * d; }
    float var = block_sum(vs, redb) * (1.0f / HH);
    float rstd = rsqrtf(var + 1e-12f);
    for (int h = tid; h < HH; h += 256) {
        float v = (xr[h] - mean) * rstd * g[h] + b[h];
        out[(size_t)row * HH + h] = v;
        out8[(size_t)row * HH + h] = f8(v);
    }
}

// ---------------- LN(a + f) -> fp32 + fp8 ----------------
__global__ __launch_bounds__(256) void ln_residual_kernel(
    const float* __restrict__ a, const float* __restrict__ f,
    const float* __restrict__ g, const float* __restrict__ b,
    float* __restrict__ out, u8* __restrict__ out8) {
    int row = blockIdx.x;
    __shared__ float xr[HH];
    __shared__ float reda[8], redb[8];
    int tid = threadIdx.x;
    float s = 0.f;
    for (int h = tid; h < HH; h += 256) {
        float v = a[(size_t)row * HH + h] + f[(size_t)row * HH + h];
        xr[h] = v; s += v;
    }
    float mean = block_sum(s, reda) * (1.0f / HH);
    float vs = 0.f;
    for (int h = tid; h < HH; h += 256) { float d = xr[h] - mean; vs += d * d; }
    float var = block_sum(vs, redb) * (1.0f / HH);
    float rstd = rsqrtf(var + 1e-12f);
    for (int h = tid; h < HH; h += 256) {
        float v = (xr[h] - mean) * rstd * g[h] + b[h];
        out[(size_t)row * HH + h] = v;
        out8[(size_t)row * HH + h] = f8(v);
    }
}

// ---------------- weight transpose+convert fp32 -> fp8 [N][K] ----------------
template <bool LAYERS12>
__global__ __launch_bounds__(256) void conv_w_kernel(
    const float* __restrict__ Wq, const float* __restrict__ Wk,
    const float* __restrict__ Wv, const float* __restrict__ Wo,
    const float* __restrict__ Wf1, const float* __restrict__ Wf2,
    u8* __restrict__ wbuf) {
    __shared__ float tile[64][65];
    int bid = blockIdx.x;
    int layer = 0;
    if (LAYERS12) { layer = bid / 1728; bid -= layer * 1728; }
    size_t woff = (size_t)layer * 7077888;
    size_t hh2 = (size_t)layer * HH * HH;
    size_t hf2 = (size_t)layer * HH * FF_;
    const float* src; u8* dst; int R, C, bx, by;
    if (bid < 576) {
        int m = bid / 144, t = bid % 144;
        src = (m == 0 ? Wq + hh2 : m == 1 ? Wk + hh2 : m == 2 ? Wv + hh2 : Wo + hh2);
        dst = wbuf + woff + (size_t)m * 589824;
        R = 768; C = 768; bx = t % 12; by = t / 12;
    } else if (bid < 1152) {
        int t = bid - 576;
        src = Wf1 + hf2; dst = wbuf + woff + 2359296; R = 768; C = 3072;
        bx = t % 48; by = t / 48;
    } else {
        int t = bid - 1152;
        src = Wf2 + hf2; dst = wbuf + woff + 4718592; R = 3072; C = 768;
        bx = t % 12; by = t / 12;
    }
    int tx = threadIdx.x & 15, ty = threadIdx.x >> 4;   // 16 x 16
#pragma unroll
    for (int p = 0; p < 4; ++p) {
        int row = p * 16 + ty;
        float4 v = *(const float4*)&src[(size_t)(by * 64 + row) * C + bx * 64 + tx * 4];
        tile[row][tx * 4 + 0] = v.x; tile[row][tx * 4 + 1] = v.y;
        tile[row][tx * 4 + 2] = v.z; tile[row][tx * 4 + 3] = v.w;
    }
    __syncthreads();
    int rq = (threadIdx.x & 15) * 4, cc0 = threadIdx.x >> 4;   // 16 cols/pass
#pragma unroll
    for (int p = 0; p < 4; ++p) {
        int cc = p * 16 + cc0;
        u32 w0 = pk8<false>(tile[rq][cc], tile[rq + 1][cc], 0);
        w0 = pk8<true>(tile[rq + 2][cc], tile[rq + 3][cc], w0);
        *(u32*)&dst[(size_t)(bx * 64 + cc) * R + by * 64 + rq] = w0;
    }
}

// ---------------- prologue: pack w_hh fp8 frags + convert w_ih -> fp8 ----------------
__global__ __launch_bounds__(256) void prep_kernel(
    const float* __restrict__ whf, const float* __restrict__ whb,
    const float* __restrict__ wif, const float* __restrict__ wib,
    u8* __restrict__ wfrag8, u8* __restrict__ wihT) {
    int bid = blockIdx.x;
    int tid = threadIdx.x;
    if (bid < 256) {
        int idx = bid * 256 + tid;
        int dir = idx >> 15;
        int kt  = (idx >> 12) & 7;
        int mt  = (idx >> 6) & 63;
        int lane = idx & 63;
        const float* W = dir ? whb : whf;
        int row = mt * 16 + (lane & 15);
        int k = kt * 32 + (lane >> 4) * 8;
        const float* src = W + (size_t)row * LH_ + k;
        u32 w0 = pk8<false>(src[0], src[1], 0);
        w0 = pk8<true>(src[2], src[3], w0);
        u32 w1 = pk8<false>(src[4], src[5], 0);
        w1 = pk8<true>(src[6], src[7], w1);
        uint2 pk; pk.x = w0; pk.y = w1;
        size_t base = (size_t)(((dir * 8 + kt) * 64 + mt) * 64 + lane) * 8;
        *(uint2*)&wfrag8[base] = pk;
    } else {
        int which = (bid < 1024) ? 0 : 1;
        const float* src = which ? wib : wif;
        u8* dst = wihT + (size_t)which * 786432;
        int i = (bid - (which ? 1024 : 256)) * 256 + tid;
        float4 v = *(const float4*)&src[(size_t)i * 4];
        u32 w0 = pk8<false>(v.x, v.y, 0);
        w0 = pk8<true>(v.z, v.w, w0);
        *(u32*)&dst[(size_t)i * 4] = w0;
    }
}

// ---------------- GEMM v5: fp8, BK=128, templated BM/BN, XOR-8 swizzle, dbuf ----------------
// LDS rows 128B; logical 16B-block a (0..7) stored at phys = a ^ (row&7).
// global_load_lds: 1KB/instr = 8 rows; lane l writes row0+(l>>3), block l&7.
template <int BROWS>
__device__ __forceinline__ void stage8(
    const u8* __restrict__ S, int r0, int K, int k0, u8 (*lds)[128], int w, int lane) {
    int rsub = lane >> 3;       // 0..7
    int ap = lane & 7;
    constexpr int INSTS = BROWS / 32;   // per wave
#pragma unroll
    for (int i = 0; i < INSTS; ++i) {
        int row0 = (w * INSTS + i) * 8;
        int row = row0 + rsub;
        int al = ap ^ (row & 7);
        GLL16(S + (size_t)(r0 + row) * K + k0 + al * 16, &lds[row0][0]);
    }
}

static __device__ __forceinline__ long lds8_read(const u8 (*lds)[128], int row, int g) {
    int a = g >> 1;                      // 16B block 0..7
    int phys = a ^ (row & 7);
    return *(const long*)&lds[row][phys * 16 + (g & 1) * 8];
}

template <int BM, int BN, bool GELU, bool OUTF8>
__global__ __launch_bounds__(256) void gemm3_kernel(
    const u8* __restrict__ A, const u8* __restrict__ BT,
    const float* __restrict__ b0, const float* __restrict__ b1, const float* __restrict__ b2,
    int seg, float* __restrict__ C, u8* __restrict__ C8, int M, int N, int K) {
    __shared__ u8 Als[2][BM][128];
    __shared__ u8 Bls[2][BN][128];
    int tid = threadIdx.x, lane = tid & 63, w = tid >> 6;
    int m0 = blockIdx.y * BM, n0 = blockIdx.x * BN;
    int wr = w >> 1, wc = w & 1;
    int l15 = lane & 15, q = lane >> 4;
    constexpr int MI = BM / 32;
    constexpr int NJ = BN / 32;

    f32x4 acc[MI][NJ];
#pragma unroll
    for (int mi = 0; mi < MI; ++mi)
#pragma unroll
        for (int nj = 0; nj < NJ; ++nj) acc[mi][nj] = (f32x4){0.f, 0.f, 0.f, 0.f};

    stage8<BM>(A, m0, K, 0, Als[0], w, lane);
    stage8<BN>(BT, n0, K, 0, Bls[0], w, lane);
    __syncthreads();
    int KT = K >> 7, cur = 0;
    for (int kt = 0; kt < KT; ++kt) {
        if (kt + 1 < KT) {
            stage8<BM>(A, m0, K, (kt + 1) << 7, Als[cur ^ 1], w, lane);
            stage8<BN>(BT, n0, K, (kt + 1) << 7, Bls[cur ^ 1], w, lane);
        }
#pragma unroll
        for (int ks = 0; ks < 4; ++ks) {
            int g = ks * 4 + q;
            long bfr[NJ];
#pragma unroll
            for (int nj = 0; nj < NJ; ++nj)
                bfr[nj] = lds8_read(Bls[cur], wc * (BN / 2) + nj * 16 + l15, g);
#pragma unroll
            for (int mi = 0; mi < MI; ++mi) {
                long a = lds8_read(Als[cur], wr * (BM / 2) + mi * 16 + l15, g);
#pragma unroll
                for (int nj = 0; nj < NJ; ++nj)
                    acc[mi][nj] = mfma_fp8(a, bfr[nj], acc[mi][nj]);
            }
        }
        __syncthreads();
        cur ^= 1;
    }

    int rbase = m0 + wr * (BM / 2) + q * 4;
    int cbase = n0 + wc * (BN / 2) + l15;
#pragma unroll
    for (int mi = 0; mi < MI; ++mi) {
#pragma unroll
        for (int nj = 0; nj < NJ; ++nj) {
            int col = cbase + nj * 16;
            int cc = col;
            const float* bp;
            if (cc < seg) bp = b0;
            else if (cc < 2 * seg) { bp = b1; cc -= seg; }
            else { bp = b2; cc -= 2 * seg; }
            float bias = bp[cc];
#pragma unroll
            for (int j = 0; j < 4; ++j) {
                int row = rbase + mi * 16 + j;
                float v = acc[mi][nj][j] + bias;
                if (GELU) v = 0.5f * v * (1.0f + erff(v * 0.70710678118654752f));
                if (OUTF8) C8[(size_t)row * N + col] = f8(v);
                else       C[(size_t)row * N + col] = v;
            }
        }
    }
}

// ---------------- attention v4: 2-way kk unroll, dual accumulators ----------------
__global__ __launch_bounds__(256) void attention_kernel(
    const float* __restrict__ qkv, const int* __restrict__ mask, u8* __restrict__ ctx8) {
    int bid = blockIdx.x;
    int quarter = bid & 3;
    int bh = bid >> 2;
    int b = bh / NH_, h = bh % NH_;
    int tid = threadIdx.x;
    int q_i = quarter * 64 + (tid >> 2);
    int dq = tid & 3;
    const float* qp = qkv + (size_t)(b * TT + q_i) * 2304 + h * DH_ + dq * 16;
    float qv[16];
#pragma unroll
    for (int d = 0; d < 4; ++d) {
        float4 v = *(const float4*)(qp + 4 * d);
        qv[4*d] = v.x; qv[4*d+1] = v.y; qv[4*d+2] = v.z; qv[4*d+3] = v.w;
    }
    const float* kbase = qkv + (size_t)b * TT * 2304 + 768 + h * DH_ + dq * 16;
    const float* vbase = qkv + (size_t)b * TT * 2304 + 1536 + h * DH_ + dq * 16;
    __shared__ float bias_s[TT];
    for (int i = tid; i < TT; i += 256)
        bias_s[i] = (1.0f - (float)mask[b * TT + i]) * -10000.0f;
    __syncthreads();
    float acc0[16] = {}, acc1[16] = {};
    float l0 = 0.f, l1 = 0.f;
    for (int kk = 0; kk < TT; kk += 2) {
        const float4* kpA = (const float4*)(kbase + (size_t)kk * 2304);
        const float4* kpB = (const float4*)(kbase + (size_t)(kk + 1) * 2304);
        float4 sA = {0.f, 0.f, 0.f, 0.f}, sB = {0.f, 0.f, 0.f, 0.f};
#pragma unroll
        for (int d = 0; d < 4; ++d) {
            float4 kA = kpA[d], kB = kpB[d];
            sA.x += qv[4*d] * kA.x;   sB.x += qv[4*d] * kB.x;
            sA.y += qv[4*d+1] * kA.y; sB.y += qv[4*d+1] * kB.y;
            sA.z += qv[4*d+2] * kA.z; sB.z += qv[4*d+2] * kB.z;
            sA.w += qv[4*d+3] * kA.w; sB.w += qv[4*d+3] * kB.w;
        }
        float pA = (sA.x + sA.y) + (sA.z + sA.w);
        float pB = (sB.x + sB.y) + (sB.z + sB.w);
        pA += __shfl_xor(pA, 1); pA += __shfl_xor(pA, 2);
        pB += __shfl_xor(pB, 1); pB += __shfl_xor(pB, 2);
        float eA = __expf(pA * 0.125f + bias_s[kk]);
        float eB = __expf(pB * 0.125f + bias_s[kk + 1]);
        l0 += eA; l1 += eB;
        const float4* vpA = (const float4*)(vbase + (size_t)kk * 2304);
        const float4* vpB = (const float4*)(vbase + (size_t)(kk + 1) * 2304);
#pragma unroll
        for (int d = 0; d < 4; ++d) {
            float4 vA = vpA[d], vB = vpB[d];
            acc0[4*d]   += eA * vA.x; acc1[4*d]   += eB * vB.x;
            acc0[4*d+1] += eA * vA.y; acc1[4*d+1] += eB * vB.y;
            acc0[4*d+2] += eA * vA.z; acc1[4*d+2] += eB * vB.z;
            acc0[4*d+3] += eA * vA.w; acc1[4*d+3] += eB * vB.w;
        }
    }
    float inv = __builtin_amdgcn_rcpf(l0 + l1);
    size_t base = (size_t)(b * TT + q_i) * HH + h * DH_ + dq * 16;
#pragma unroll
    for (int d = 0; d < 4; ++d) {
        u32 w0 = pk8<false>((acc0[4*d] + acc1[4*d]) * inv,
                            (acc0[4*d+1] + acc1[4*d+1]) * inv, 0);
        w0 = pk8<true>((acc0[4*d+2] + acc1[4*d+2]) * inv,
                       (acc0[4*d+3] + acc1[4*d+3]) * inv, w0);
        *(u32*)&ctx8[base + 4*d] = w0;
    }
}

// ---------------- LSTM v13: streamed W hoisted + pinned ----------------
__global__ __launch_bounds__(1024, 4) void lstm13_kernel(
    const float* __restrict__ xg, const u8* __restrict__ wfrag8,
    const float* __restrict__ bhh_f, const float* __restrict__ bhh_b,
    float* __restrict__ hf, float* __restrict__ hb) {
    int dir = blockIdx.x;
    const u8* wf8 = wfrag8 + (size_t)dir * 262144;
    const float* bhh = dir ? bhh_b : bhh_f;
    float* hout = dir ? hb : hf;
    int tid = threadIdx.x, lane = tid & 63, wid = tid >> 6;
    __shared__ u8 wlds[4 * 64 * 512];
    __shared__ u8 h_f8[16][280];
    __shared__ u16 g_bf[1024][10];
    for (int i = tid; i < 16 * 280; i += 1024) ((u8*)h_f8)[i] = 0;
#pragma unroll
    for (int c = 0; c < 8; ++c) {
        int off = wid * 8192 + c * 1024;
        GLL16(wf8 + off + lane * 16, &wlds[off]);
    }
    long wst[4][4];
#pragma unroll
    for (int kt = 0; kt < 4; ++kt)
#pragma unroll
        for (int m = 0; m < 4; ++m) {
            wst[kt][m] = *(const long*)&wf8[(size_t)(((4 + kt) * 64) + wid * 4 + m) * 512 + lane * 8];
            asm volatile("" : "+v"(wst[kt][m]));
        }
    int l15 = lane & 15, qq = lane >> 4;
    int j = tid & 255;
    int bq = (tid >> 8) * 2;
    float bi_ = bhh[j], bf_ = bhh[256 + j], bg_ = bhh[512 + j], bo_ = bhh[768 + j];
    float c_s[2] = {0.f, 0.f};
    __syncthreads();
    for (int step = 0; step < TT; ++step) {
        int t = dir ? (TT - 1 - step) : step;
        float xgi[2], xgf[2], xgg[2], xgo[2];
#pragma unroll
        for (int bi = 0; bi < 2; ++bi) {
            size_t xa = ((size_t)((bq + bi) * TT + t)) * 2048 + (size_t)dir * 1024;
            xgi[bi] = xg[xa + j];
            xgf[bi] = xg[xa + 256 + j];
            xgg[bi] = xg[xa + 512 + j];
            xgo[bi] = xg[xa + 768 + j];
        }
        f32x4 acc[4];
#pragma unroll
        for (int m = 0; m < 4; ++m) acc[m] = (f32x4){0.f, 0.f, 0.f, 0.f};
#pragma unroll
        for (int kt = 0; kt < 4; ++kt) {
            long hfr = *(const long*)&h_f8[l15][kt * 32 + qq * 8];
#pragma unroll
            for (int m = 0; m < 4; ++m) {
                long a = *(const long*)&wlds[(size_t)(kt * 64 + wid * 4 + m) * 512 + lane * 8];
                acc[m] = mfma_fp8(a, hfr, acc[m]);
            }
        }
#pragma unroll
        for (int kt = 0; kt < 4; ++kt) {
            long hfr = *(const long*)&h_f8[l15][(4 + kt) * 32 + qq * 8];
#pragma unroll
            for (int m = 0; m < 4; ++m)
                acc[m] = mfma_fp8(wst[kt][m], hfr, acc[m]);
        }
        if (l15 < 8) {
#pragma unroll
            for (int m = 0; m < 4; ++m) {
                int R = (wid * 4 + m) * 16 + qq * 4;
#pragma unroll
                for (int jj = 0; jj < 4; ++jj)
                    g_bf[R + jj][l15] = (u16)(__float_as_uint(acc[m][jj]) >> 16);
            }
        }
        __syncthreads();
#pragma unroll
        for (int bi = 0; bi < 2; ++bi) {
            int b = bq + bi;
            float gi = xgi[bi] + bi_ + bf2f(g_bf[j][b]);
            float gf = xgf[bi] + bf_ + bf2f(g_bf[256 + j][b]);
            float gg = xgg[bi] + bg_ + bf2f(g_bf[512 + j][b]);
            float go = xgo[bi] + bo_ + bf2f(g_bf[768 + j][b]);
            float cc = sigm_fast(gf) * c_s[bi] + sigm_fast(gi) * tanh_fast(gg);
            c_s[bi] = cc;
            float hh = sigm_fast(go) * tanh_fast(cc);
            h_f8[b][j] = f8(hh);
            hout[((size_t)(b * TT + t)) * LH_ + j] = hh;
        }
        __syncthreads();
    }
}

// ---------------- classifier ----------------
__global__ __launch_bounds__(256) void clf_kernel(
    const float* __restrict__ hf, const float* __restrict__ hb,
    const float* __restrict__ W, const float* __restrict__ bias, float* __restrict__ em) {
    int idx = blockIdx.x * blockDim.x + threadIdx.x;
    if (idx >= BB * TT * KK_) return;
    int row = idx / KK_, j = idx % KK_;
    float acc = bias[j];
    const float* hfp = hf + (size_t)row * LH_;
    const float* hbp = hb + (size_t)row * LH_;
    for (int kk = 0; kk < LH_; ++kk) acc += hfp[kk] * W[kk * KK_ + j];
    for (int kk = 0; kk < LH_; ++kk) acc += hbp[kk] * W[(LH_ + kk) * KK_ + j];
    em[idx] = acc;
}

// ---------------- CRF v2 ----------------
__global__ __launch_bounds__(512) void crf2_kernel(
    const float* __restrict__ em, const int* __restrict__ labels, const int* __restrict__ mask,
    const float* __restrict__ cstart, const float* __restrict__ cend,
    const float* __restrict__ ctrans, float* __restrict__ out) {
    __shared__ float trans_s[81];
    __shared__ float res[8];
    int tid = threadIdx.x;
    int b = tid >> 6;
    int l = tid & 63;
    if (tid < 81) trans_s[tid] = ctrans[tid];
    __syncthreads();
    int lc = (l < 9) ? l : 0;
    float tcol[9];
#pragma unroll
    for (int i = 0; i < 9; ++i) tcol[i] = trans_s[i * 9 + lc];
    float alpha = (l < 9) ? cstart[lc] + em[(size_t)b * TT * KK_ + lc] : -1e30f;
    for (int t = 1; t < TT; ++t) {
        float e_t = (l < 9) ? em[((size_t)b * TT + t) * KK_ + lc] : 0.f;
        float m = -1e30f;
        float av[9];
#pragma unroll
        for (int i = 0; i < 9; ++i) {
            av[i] = __shfl(alpha, i) + tcol[i];
            m = fmaxf(m, av[i]);
        }
        float s = 0.f;
#pragma unroll
        for (int i = 0; i < 9; ++i) s += expf(av[i] - m);
        float nv = m + logf(s) + e_t;
        bool upd = (mask[b * TT + t] > 0) && (l < 9);
        alpha = upd ? nv : alpha;
    }
    float z = (l < 9) ? alpha + cend[lc] : -1e30f;
    float zm = z;
#pragma unroll
    for (int o = 32; o > 0; o >>= 1) zm = fmaxf(zm, __shfl_xor(zm, o));
    float zs = (l < 9) ? expf(z - zm) : 0.f;
#pragma unroll
    for (int o = 32; o > 0; o >>= 1) zs += __shfl_xor(zs, o);
    float logZ = zm + logf(zs);
    float sc = 0.f;
    int cnt = 0;
    for (int t = l; t < TT; t += 64) {
        cnt += mask[b * TT + t];
        if (t == 0) {
            int l0 = labels[b * TT];
            sc += cstart[l0] + em[(size_t)b * TT * KK_ + l0];
        } else {
            int lp = labels[b * TT + t - 1];
            int lt = labels[b * TT + t];
            sc += (trans_s[lp * KK_ + lt] + em[((size_t)b * TT + t) * KK_ + lt]) *
                  (float)mask[b * TT + t];
        }
    }
#pragma unroll
    for (int o = 32; o > 0; o >>= 1) { sc += __shfl_xor(sc, o); cnt += __shfl_xor(cnt, o); }
    if (l == 0) {
        int last = labels[b * TT + (cnt - 1)];
        sc += cend[last];
        res[b] = sc - logZ;
    }
    __syncthreads();
    if (tid == 0) {
        float acc = 0.f;
        for (int bb = 0; bb < BB; ++bb) acc += res[bb];
        out[0] = -acc / (float)BB;
    }
}

extern "C" void kernel_launch(void* const* d_in, const int* in_sizes, int n_in,
                              void* d_out, int out_size, void* d_ws, size_t ws_size,
                              hipStream_t stream) {
    const int* input_ids = (const int*)d_in[0];
    const int* attn_mask = (const int*)d_in[1];
    const int* labels    = (const int*)d_in[2];
    const float* word_emb = (const float*)d_in[3];
    const float* pos_emb  = (const float*)d_in[4];
    const float* type_emb = (const float*)d_in[5];
    const float* emb_ln_g = (const float*)d_in[6];
    const float* emb_ln_b = (const float*)d_in[7];
    const float* Wq = (const float*)d_in[8];
    const float* bq = (const float*)d_in[9];
    const float* Wk = (const float*)d_in[10];
    const float* bk = (const float*)d_in[11];
    const float* Wv = (const float*)d_in[12];
    const float* bv = (const float*)d_in[13];
    const float* Wo = (const float*)d_in[14];
    const float* bo = (const float*)d_in[15];
    const float* ln1_g = (const float*)d_in[16];
    const float* ln1_b = (const float*)d_in[17];
    const float* Wf1 = (const float*)d_in[18];
    const float* bf1 = (const float*)d_in[19];
    const float* Wf2 = (const float*)d_in[20];
    const float* bf2 = (const float*)d_in[21];
    const float* ln2_g = (const float*)d_in[22];
    const float* ln2_b = (const float*)d_in[23];
    const float* w_ih_f = (const float*)d_in[24];
    const float* w_hh_f = (const float*)d_in[25];
    const float* b_ih_f = (const float*)d_in[26];
    const float* b_hh_f = (const float*)d_in[27];
    const float* w_ih_b = (const float*)d_in[28];
    const float* w_hh_b = (const float*)d_in[29];
    const float* b_ih_b = (const float*)d_in[30];
    const float* b_hh_b = (const float*)d_in[31];
    const float* W_clf  = (const float*)d_in[32];
    const float* b_clf  = (const float*)d_in[33];
    const float* crf_start = (const float*)d_in[34];
    const float* crf_end   = (const float*)d_in[35];
    const float* crf_trans = (const float*)d_in[36];

    const size_t NTOK = (size_t)BB * TT;          // 2048
    const size_t SZ = NTOK * HH;                  // 1,572,864

    float* ws = (float*)d_ws;
    float* x    = ws;                              // SZ
    float* qkv  = x + SZ;                          // 2048*2304
    float* tmp  = qkv + NTOK * 2304;               // SZ
    float* ab   = tmp + SZ;                        // SZ
    float* xg   = ab + SZ;                         // 2048*2048
    u8* x_f8    = (u8*)(xg + NTOK * 2048);         // SZ bytes
    u8* ab_f8   = x_f8 + SZ;
    u8* ctx_f8  = ab_f8 + SZ;
    u8* big_f8  = ctx_f8 + SZ;                     // 2048*3072
    u8* wihT    = big_f8 + NTOK * (size_t)FF_;     // 2048*768 bytes
    u8* wfrag8  = wihT + 1572864;                  // 524,288 bytes
    u8* wbuf    = wfrag8 + 524288;                 // per-layer 7,077,888 B (or x12)
    const size_t base_off = (size_t)((u8*)wbuf - (u8*)d_ws);
    bool big = ws_size >= base_off + 12ull * 7077888ull + (1u << 20);

    float* hf = qkv;
    float* hb = qkv + 524288;
    float* em = qkv + 1048576;

    embed_ln_kernel<<<NTOK, 256, 0, stream>>>(input_ids, word_emb, pos_emb, type_emb,
                                              emb_ln_g, emb_ln_b, x, x_f8);
    prep_kernel<<<1792, 256, 0, stream>>>(w_hh_f, w_hh_b, w_ih_f, w_ih_b, wfrag8, wihT);
    if (big)
        conv_w_kernel<true><<<1728 * 12, 256, 0, stream>>>(Wq, Wk, Wv, Wo, Wf1, Wf2, wbuf);

    dim3 gQKV(2304 / 128, NTOK / 128);  // 18 x 16
    dim3 gH(HH / 64, NTOK / 64);        // 12 x 32  (64x64 tiles)
    dim3 gF1(FF_ / 128, NTOK / 128);    // 24 x 16
    dim3 gG(2048 / 128, NTOK / 128);    // 16 x 16

    for (int l = 0; l < NL; ++l) {
        u8* wb = big ? wbuf + (size_t)l * 7077888 : wbuf;
        if (!big)
            conv_w_kernel<false><<<1728, 256, 0, stream>>>(
                Wq + (size_t)l * HH * HH, Wk + (size_t)l * HH * HH,
                Wv + (size_t)l * HH * HH, Wo + (size_t)l * HH * HH,
                Wf1 + (size_t)l * HH * FF_, Wf2 + (size_t)l * FF_ * HH, wb);

        const float* bq_l = bq + (size_t)l * HH;
        const float* bk_l = bk + (size_t)l * HH;
        const float* bv_l = bv + (size_t)l * HH;
        const float* bo_l = bo + (size_t)l * HH;
        const float* g1 = ln1_g + (size_t)l * HH;
        const float* b1 = ln1_b + (size_t)l * HH;
        const float* bf1_l = bf1 + (size_t)l * FF_;
        const float* bf2_l = bf2 + (size_t)l * HH;
        const float* g2 = ln2_g + (size_t)l * HH;
        const float* b2 = ln2_b + (size_t)l * HH;

        gemm3_kernel<128, 128, false, false><<<gQKV, 256, 0, stream>>>(
            x_f8, wb, bq_l, bk_l, bv_l, 768, qkv, nullptr, NTOK, 2304, HH);
        attention_kernel<<<BB * NH_ * 4, 256, 0, stream>>>(qkv, attn_mask, ctx_f8);
        gemm3_kernel<64, 64, false, false><<<gH, 256, 0, stream>>>(
            ctx_f8, wb + 1769472, bo_l, bo_l, bo_l, 768, tmp, nullptr, NTOK, HH, HH);
        ln_residual_kernel<<<NTOK, 256, 0, stream>>>(x, tmp, g1, b1, ab, ab_f8);
        gemm3_kernel<128, 128, true, true><<<gF1, 256, 0, stream>>>(
            ab_f8, wb + 2359296, bf1_l, bf1_l, bf1_l, FF_, nullptr, big_f8, NTOK, FF_, HH);
        gemm3_kernel<64, 64, false, false><<<gH, 256, 0, stream>>>(
            big_f8, wb + 4718592, bf2_l, bf2_l, bf2_l, 768, tmp, nullptr, NTOK, HH, FF_);
        ln_residual_kernel<<<NTOK, 256, 0, stream>>>(ab, tmp, g2, b2, x, x_f8);
    }

    // fused LSTM input projections: xg[tok][dir*1024+g]
    gemm3_kernel<128, 128, false, false><<<gG, 256, 0, stream>>>(
        x_f8, wihT, b_ih_f, b_ih_b, b_ih_b, 1024, xg, nullptr, NTOK, 2048, HH);

    lstm13_kernel<<<2, 1024, 0, stream>>>(xg, wfrag8, b_hh_f, b_hh_b, hf, hb);
    clf_kernel<<<(BB * TT * KK_ + 255) / 256, 256, 0, stream>>>(hf, hb, W_clf, b_clf, em);
    crf2_kernel<<<1, 512, 0, stream>>>(em, labels, attn_mask, crf_start, crf_end, crf_trans,
                                       (float*)d_out);
}

// Round 20
// 2113.662 us; speedup vs baseline: 10.3547x; 2.2663x over previous
//
#include <hip/hip_runtime.h>
#include <math.h>

#define BB 8
#define TT 256
#define HH 768
#define NL 12
#define NH_ 12
#define DH_ 64
#define FF_ 3072
#define LH_ 256
#define KK_ 9

typedef unsigned char u8;
typedef unsigned short u16;
typedef unsigned int u32;
typedef __attribute__((ext_vector_type(4))) float f32x4;

static __device__ __forceinline__ float sigm_fast(float x) {
    return __builtin_amdgcn_rcpf(1.0f + __expf(-x));
}
static __device__ __forceinline__ float tanh_fast(float x) {
    return 1.0f - 2.0f * __builtin_amdgcn_rcpf(1.0f + __expf(2.0f * x));
}
static __device__ __forceinline__ float bf2f(u16 v) {
    return __uint_as_float(((u32)v) << 16);
}
template <bool HI>
static __device__ __forceinline__ u32 pk8(float a, float b, u32 old) {
    return (u32)__builtin_amdgcn_cvt_pk_fp8_f32(a, b, (int)old, HI);
}
static __device__ __forceinline__ u8 f8(float v) {
    return (u8)(pk8<false>(v, v, 0) & 0xff);
}

static __device__ __forceinline__ f32x4 mfma_fp8(long a, long b, f32x4 c) {
    return __builtin_amdgcn_mfma_f32_16x16x32_fp8_fp8(a, b, c, 0, 0, 0);
}

#define GLL16(gp, lp) __builtin_amdgcn_global_load_lds( \
    (const __attribute__((address_space(1))) void*)(gp), \
    (__attribute__((address_space(3))) void*)(lp), 16, 0, 0)

// ---------------- block reduce ----------------
static __device__ __forceinline__ float block_sum(float v, float* red) {
    int tid = threadIdx.x;
#pragma unroll
    for (int o = 32; o > 0; o >>= 1) v += __shfl_xor(v, o);
    if ((tid & 63) == 0) red[tid >> 6] = v;
    __syncthreads();
    return red[0] + red[1] + red[2] + red[3];
}

// ---------------- embedding + LN -> fp32 + fp8 ----------------
__global__ __launch_bounds__(256) void embed_ln_kernel(
    const int* __restrict__ ids, const float* __restrict__ we, const float* __restrict__ pe,
    const float* __restrict__ te, const float* __restrict__ g, const float* __restrict__ b,
    float* __restrict__ out, u8* __restrict__ out8) {
    int row = blockIdx.x;
    int t = row % TT;
    int id = ids[row];
    __shared__ float xr[HH];
    __shared__ float reda[8], redb[8];
    int tid = threadIdx.x;
    float s = 0.f;
    for (int h = tid; h < HH; h += 256) {
        float v = we[(size_t)id * HH + h] + pe[(size_t)t * HH + h] + te[h];
        xr[h] = v; s += v;
    }
    float mean = block_sum(s, reda) * (1.0f / HH);
    float vs = 0.f;
    for (int h = tid; h < HH; h += 256) { float d = xr[h] - mean; vs += d * d; }
    float var = block_sum(vs, redb) * (1.0f / HH);
    float rstd = rsqrtf(var + 1e-12f);
    for (int h = tid; h < HH; h += 256) {
        float v = (xr[h] - mean) * rstd * g[h] + b[h];
        out[(size_t)row * HH + h] = v;
        out8[(size_t)row * HH + h] = f8(v);
    }
}

// ---------------- LN(a + f) -> fp32 + fp8 ----------------
__global__ __launch_bounds__(256) void ln_residual_kernel(
    const float* __restrict__ a, const float* __restrict__ f,
    const float* __restrict__ g, const float* __restrict__ b,
    float* __restrict__ out, u8* __restrict__ out8) {
    int row = blockIdx.x;
    __shared__ float xr[HH];
    __shared__ float reda[8], redb[8];
    int tid = threadIdx.x;
    float s = 0.f;
    for (int h = tid; h < HH; h += 256) {
        float v = a[(size_t)row * HH + h] + f[(size_t)row * HH + h];
        xr[h] = v; s += v;
    }
    float mean = block_sum(s, reda) * (1.0f / HH);
    float vs = 0.f;
    for (int h = tid; h < HH; h += 256) { float d = xr[h] - mean; vs += d * d; }
    float var = block_sum(vs, redb) * (1.0f / HH);
    float rstd = rsqrtf(var + 1e-12f);
    for (int h = tid; h < HH; h += 256) {
        float v = (xr[h] - mean) * rstd * g[h] + b[h];
        out[(size_t)row * HH + h] = v;
        out8[(size_t)row * HH + h] = f8(v);
    }
}

// ---------------- weight transpose+convert fp32 -> fp8 [N][K] ----------------
template <bool LAYERS12>
__global__ __launch_bounds__(256) void conv_w_kernel(
    const float* __restrict__ Wq, const float* __restrict__ Wk,
    const float* __restrict__ Wv, const float* __restrict__ Wo,
    const float* __restrict__ Wf1, const float* __restrict__ Wf2,
    u8* __restrict__ wbuf) {
    __shared__ float tile[64][65];
    int bid = blockIdx.x;
    int layer = 0;
    if (LAYERS12) { layer = bid / 1728; bid -= layer * 1728; }
    size_t woff = (size_t)layer * 7077888;
    size_t hh2 = (size_t)layer * HH * HH;
    size_t hf2 = (size_t)layer * HH * FF_;
    const float* src; u8* dst; int R, C, bx, by;
    if (bid < 576) {
        int m = bid / 144, t = bid % 144;
        src = (m == 0 ? Wq + hh2 : m == 1 ? Wk + hh2 : m == 2 ? Wv + hh2 : Wo + hh2);
        dst = wbuf + woff + (size_t)m * 589824;
        R = 768; C = 768; bx = t % 12; by = t / 12;
    } else if (bid < 1152) {
        int t = bid - 576;
        src = Wf1 + hf2; dst = wbuf + woff + 2359296; R = 768; C = 3072;
        bx = t % 48; by = t / 48;
    } else {
        int t = bid - 1152;
        src = Wf2 + hf2; dst = wbuf + woff + 4718592; R = 3072; C = 768;
        bx = t % 12; by = t / 12;
    }
    int tx = threadIdx.x & 15, ty = threadIdx.x >> 4;   // 16 x 16
#pragma unroll
    for (int p = 0; p < 4; ++p) {
        int row = p * 16 + ty;
        float4 v = *(const float4*)&src[(size_t)(by * 64 + row) * C + bx * 64 + tx * 4];
        tile[row][tx * 4 + 0] = v.x; tile[row][tx * 4 + 1] = v.y;
        tile[row][tx * 4 + 2] = v.z; tile[row][tx * 4 + 3] = v.w;
    }
    __syncthreads();
    int rq = (threadIdx.x & 15) * 4, cc0 = threadIdx.x >> 4;   // 16 cols/pass
#pragma unroll
    for (int p = 0; p < 4; ++p) {
        int cc = p * 16 + cc0;
        u32 w0 = pk8<false>(tile[rq][cc], tile[rq + 1][cc], 0);
        w0 = pk8<true>(tile[rq + 2][cc], tile[rq + 3][cc], w0);
        *(u32*)&dst[(size_t)(bx * 64 + cc) * R + by * 64 + rq] = w0;
    }
}

// ---------------- prologue: pack w_hh fp8 frags + convert w_ih -> fp8 ----------------
__global__ __launch_bounds__(256) void prep_kernel(
    const float* __restrict__ whf, const float* __restrict__ whb,
    const float* __restrict__ wif, const float* __restrict__ wib,
    u8* __restrict__ wfrag8, u8* __restrict__ wihT) {
    int bid = blockIdx.x;
    int tid = threadIdx.x;
    if (bid < 256) {
        int idx = bid * 256 + tid;
        int dir = idx >> 15;
        int kt  = (idx >> 12) & 7;
        int mt  = (idx >> 6) & 63;
        int lane = idx & 63;
        const float* W = dir ? whb : whf;
        int row = mt * 16 + (lane & 15);
        int k = kt * 32 + (lane >> 4) * 8;
        const float* src = W + (size_t)row * LH_ + k;
        u32 w0 = pk8<false>(src[0], src[1], 0);
        w0 = pk8<true>(src[2], src[3], w0);
        u32 w1 = pk8<false>(src[4], src[5], 0);
        w1 = pk8<true>(src[6], src[7], w1);
        uint2 pk; pk.x = w0; pk.y = w1;
        size_t base = (size_t)(((dir * 8 + kt) * 64 + mt) * 64 + lane) * 8;
        *(uint2*)&wfrag8[base] = pk;
    } else {
        int which = (bid < 1024) ? 0 : 1;
        const float* src = which ? wib : wif;
        u8* dst = wihT + (size_t)which * 786432;
        int i = (bid - (which ? 1024 : 256)) * 256 + tid;
        float4 v = *(const float4*)&src[(size_t)i * 4];
        u32 w0 = pk8<false>(v.x, v.y, 0);
        w0 = pk8<true>(v.z, v.w, w0);
        *(u32*)&dst[(size_t)i * 4] = w0;
    }
}

// ---------------- GEMM v5: fp8, BK=128, templated BM/BN, XOR-8 swizzle, dbuf ----------------
template <int BROWS>
__device__ __forceinline__ void stage8(
    const u8* __restrict__ S, int r0, int K, int k0, u8 (*lds)[128], int w, int lane) {
    int rsub = lane >> 3;       // 0..7
    int ap = lane & 7;
    constexpr int INSTS = BROWS / 32;   // per wave
#pragma unroll
    for (int i = 0; i < INSTS; ++i) {
        int row0 = (w * INSTS + i) * 8;
        int row = row0 + rsub;
        int al = ap ^ (row & 7);
        GLL16(S + (size_t)(r0 + row) * K + k0 + al * 16, &lds[row0][0]);
    }
}

static __device__ __forceinline__ long lds8_read(const u8 (*lds)[128], int row, int g) {
    int a = g >> 1;                      // 16B block 0..7
    int phys = a ^ (row & 7);
    return *(const long*)&lds[row][phys * 16 + (g & 1) * 8];
}

// QKVW: N=2304; cols<1536 -> qkv8 fp8 bytes; cols>=1536 -> vT packed u32.
template <int BM, int BN, bool GELU, bool OUTF8, bool QKVW>
__global__ __launch_bounds__(256) void gemm3_kernel(
    const u8* __restrict__ A, const u8* __restrict__ BT,
    const float* __restrict__ b0, const float* __restrict__ b1, const float* __restrict__ b2,
    int seg, float* __restrict__ C, u8* __restrict__ C8, u8* __restrict__ vT,
    int M, int N, int K) {
    __shared__ u8 Als[2][BM][128];
    __shared__ u8 Bls[2][BN][128];
    int tid = threadIdx.x, lane = tid & 63, w = tid >> 6;
    int m0 = blockIdx.y * BM, n0 = blockIdx.x * BN;
    int wr = w >> 1, wc = w & 1;
    int l15 = lane & 15, q = lane >> 4;
    constexpr int MI = BM / 32;
    constexpr int NJ = BN / 32;

    f32x4 acc[MI][NJ];
#pragma unroll
    for (int mi = 0; mi < MI; ++mi)
#pragma unroll
        for (int nj = 0; nj < NJ; ++nj) acc[mi][nj] = (f32x4){0.f, 0.f, 0.f, 0.f};

    stage8<BM>(A, m0, K, 0, Als[0], w, lane);
    stage8<BN>(BT, n0, K, 0, Bls[0], w, lane);
    __syncthreads();
    int KT = K >> 7, cur = 0;
    for (int kt = 0; kt < KT; ++kt) {
        if (kt + 1 < KT) {
            stage8<BM>(A, m0, K, (kt + 1) << 7, Als[cur ^ 1], w, lane);
            stage8<BN>(BT, n0, K, (kt + 1) << 7, Bls[cur ^ 1], w, lane);
        }
#pragma unroll
        for (int ks = 0; ks < 4; ++ks) {
            int g = ks * 4 + q;
            long bfr[NJ];
#pragma unroll
            for (int nj = 0; nj < NJ; ++nj)
                bfr[nj] = lds8_read(Bls[cur], wc * (BN / 2) + nj * 16 + l15, g);
#pragma unroll
            for (int mi = 0; mi < MI; ++mi) {
                long a = lds8_read(Als[cur], wr * (BM / 2) + mi * 16 + l15, g);
#pragma unroll
                for (int nj = 0; nj < NJ; ++nj)
                    acc[mi][nj] = mfma_fp8(a, bfr[nj], acc[mi][nj]);
            }
        }
        __syncthreads();
        cur ^= 1;
    }

    int rbase = m0 + wr * (BM / 2) + q * 4;
    int cbase = n0 + wc * (BN / 2) + l15;
#pragma unroll
    for (int mi = 0; mi < MI; ++mi) {
#pragma unroll
        for (int nj = 0; nj < NJ; ++nj) {
            int col = cbase + nj * 16;
            int cc = col;
            const float* bp;
            if (cc < seg) bp = b0;
            else if (cc < 2 * seg) { bp = b1; cc -= seg; }
            else { bp = b2; cc -= 2 * seg; }
            float bias = bp[cc];
            if (QKVW && col >= 1536) {
                // V part: pack 4 consecutive token-rows, write transposed vT[b][h][d][t]
                int hh = (col - 1536) >> 6, dl = (col - 1536) & 63;
                int brow = rbase + mi * 16;
                int bb = brow >> 8, t0 = brow & 255;
                u32 pkv = pk8<false>(acc[mi][nj][0] + bias, acc[mi][nj][1] + bias, 0);
                pkv = pk8<true>(acc[mi][nj][2] + bias, acc[mi][nj][3] + bias, pkv);
                *(u32*)&vT[(size_t)((bb * NH_ + hh) * DH_ + dl) * TT + t0] = pkv;
            } else {
#pragma unroll
                for (int j = 0; j < 4; ++j) {
                    int row = rbase + mi * 16 + j;
                    float v = acc[mi][nj][j] + bias;
                    if (GELU) v = 0.5f * v * (1.0f + erff(v * 0.70710678118654752f));
                    if (OUTF8 || QKVW) C8[(size_t)row * N + col] = f8(v);
                    else               C[(size_t)row * N + col] = v;
                }
            }
        }
    }
}

// ---------------- attention v5: MFMA fp8, single-pass softmax in registers ----------------
// block = (b,h,qquad of 64 rows), 4 waves x 16 q-rows. S kept in 16 f32x4 accs.
__global__ __launch_bounds__(256) void attn_mfma_kernel(
    const u8* __restrict__ qkv8, const u8* __restrict__ vT,
    const int* __restrict__ mask, u8* __restrict__ ctx8) {
    int bid = blockIdx.x;
    int qb = bid & 3;
    int bh = bid >> 2;
    int b = bh / NH_, h = bh % NH_;
    int tid = threadIdx.x, lane = tid & 63, w = tid >> 6;
    int l15 = lane & 15, g4 = lane >> 4;
    __shared__ float bias_s[TT];
    __shared__ u8 P[64][260];
    for (int i = tid; i < TT; i += 256)
        bias_s[i] = (1.0f - (float)mask[b * TT + i]) * -10000.0f;
    __syncthreads();

    // Q A-frags: m = l15 -> q-row qb*64 + w*16 + l15
    size_t qoff = (size_t)(b * TT + qb * 64 + w * 16 + l15) * 2304 + h * DH_ + g4 * 8;
    long aq0 = *(const long*)&qkv8[qoff];
    long aq1 = *(const long*)&qkv8[qoff + 32];

    // S = Q @ K^T  (16 n-tiles of 16 keys)
    f32x4 sacc[16];
#pragma unroll
    for (int nt = 0; nt < 16; ++nt) sacc[nt] = (f32x4){0.f, 0.f, 0.f, 0.f};
#pragma unroll
    for (int nt = 0; nt < 16; ++nt) {
        size_t koff = (size_t)(b * TT + nt * 16 + l15) * 2304 + 768 + h * DH_ + g4 * 8;
        long b0 = *(const long*)&qkv8[koff];
        long b1 = *(const long*)&qkv8[koff + 32];
        sacc[nt] = mfma_fp8(aq0, b0, sacc[nt]);
        sacc[nt] = mfma_fp8(aq1, b1, sacc[nt]);
    }
    // softmax (rows (g4*4+j) are lane-local in reg j; reduce over 16-lane col group)
    float m[4] = {-1e30f, -1e30f, -1e30f, -1e30f};
#pragma unroll
    for (int nt = 0; nt < 16; ++nt) {
        float bv = bias_s[nt * 16 + l15];
#pragma unroll
        for (int j = 0; j < 4; ++j) {
            float s = sacc[nt][j] * 0.125f + bv;
            sacc[nt][j] = s;
            m[j] = fmaxf(m[j], s);
        }
    }
#pragma unroll
    for (int j = 0; j < 4; ++j) {
        m[j] = fmaxf(m[j], __shfl_xor(m[j], 1));
        m[j] = fmaxf(m[j], __shfl_xor(m[j], 2));
        m[j] = fmaxf(m[j], __shfl_xor(m[j], 4));
        m[j] = fmaxf(m[j], __shfl_xor(m[j], 8));
    }
    float l[4] = {0.f, 0.f, 0.f, 0.f};
#pragma unroll
    for (int nt = 0; nt < 16; ++nt) {
#pragma unroll
        for (int j = 0; j < 4; ++j) {
            float p = __expf(sacc[nt][j] - m[j]);
            sacc[nt][j] = p;
            l[j] += p;
        }
    }
#pragma unroll
    for (int j = 0; j < 4; ++j) {
        l[j] += __shfl_xor(l[j], 1);
        l[j] += __shfl_xor(l[j], 2);
        l[j] += __shfl_xor(l[j], 4);
        l[j] += __shfl_xor(l[j], 8);
    }
    // P -> LDS fp8 (wave-private rows: no barrier needed)
#pragma unroll
    for (int nt = 0; nt < 16; ++nt) {
#pragma unroll
        for (int j = 0; j < 4; ++j)
            P[w * 16 + g4 * 4 + j][nt * 16 + l15] = f8(sacc[nt][j]);
    }
    // O = P @ V  (A-frags from P rows w*16+l15; B-frags from vT)
    f32x4 oacc[4];
#pragma unroll
    for (int nt4 = 0; nt4 < 4; ++nt4) oacc[nt4] = (f32x4){0.f, 0.f, 0.f, 0.f};
    const u8* vbase = vT + (size_t)(bh * DH_) * TT;
#pragma unroll
    for (int ks = 0; ks < 8; ++ks) {
        long pa = *(const long*)&P[w * 16 + l15][ks * 32 + g4 * 8];
#pragma unroll
        for (int nt4 = 0; nt4 < 4; ++nt4) {
            long bv = *(const long*)&vbase[(size_t)(nt4 * 16 + l15) * TT + ks * 32 + g4 * 8];
            oacc[nt4] = mfma_fp8(pa, bv, oacc[nt4]);
        }
    }
    float inv[4];
#pragma unroll
    for (int j = 0; j < 4; ++j) inv[j] = __builtin_amdgcn_rcpf(l[j]);
    int rowg = b * TT + qb * 64 + w * 16 + g4 * 4;
#pragma unroll
    for (int nt4 = 0; nt4 < 4; ++nt4) {
        int col = h * DH_ + nt4 * 16 + l15;
#pragma unroll
        for (int j = 0; j < 4; ++j)
            ctx8[(size_t)(rowg + j) * HH + col] = f8(oacc[nt4][j] * inv[j]);
    }
}

// ---------------- LSTM v13: streamed W hoisted + pinned ----------------
__global__ __launch_bounds__(1024, 4) void lstm13_kernel(
    const float* __restrict__ xg, const u8* __restrict__ wfrag8,
    const float* __restrict__ bhh_f, const float* __restrict__ bhh_b,
    float* __restrict__ hf, float* __restrict__ hb) {
    int dir = blockIdx.x;
    const u8* wf8 = wfrag8 + (size_t)dir * 262144;
    const float* bhh = dir ? bhh_b : bhh_f;
    float* hout = dir ? hb : hf;
    int tid = threadIdx.x, lane = tid & 63, wid = tid >> 6;
    __shared__ u8 wlds[4 * 64 * 512];
    __shared__ u8 h_f8[16][280];
    __shared__ u16 g_bf[1024][10];
    for (int i = tid; i < 16 * 280; i += 1024) ((u8*)h_f8)[i] = 0;
#pragma unroll
    for (int c = 0; c < 8; ++c) {
        int off = wid * 8192 + c * 1024;
        GLL16(wf8 + off + lane * 16, &wlds[off]);
    }
    long wst[4][4];
#pragma unroll
    for (int kt = 0; kt < 4; ++kt)
#pragma unroll
        for (int m = 0; m < 4; ++m) {
            wst[kt][m] = *(const long*)&wf8[(size_t)(((4 + kt) * 64) + wid * 4 + m) * 512 + lane * 8];
            asm volatile("" : "+v"(wst[kt][m]));
        }
    int l15 = lane & 15, qq = lane >> 4;
    int j = tid & 255;
    int bq = (tid >> 8) * 2;
    float bi_ = bhh[j], bf_ = bhh[256 + j], bg_ = bhh[512 + j], bo_ = bhh[768 + j];
    float c_s[2] = {0.f, 0.f};
    __syncthreads();
    for (int step = 0; step < TT; ++step) {
        int t = dir ? (TT - 1 - step) : step;
        float xgi[2], xgf[2], xgg[2], xgo[2];
#pragma unroll
        for (int bi = 0; bi < 2; ++bi) {
            size_t xa = ((size_t)((bq + bi) * TT + t)) * 2048 + (size_t)dir * 1024;
            xgi[bi] = xg[xa + j];
            xgf[bi] = xg[xa + 256 + j];
            xgg[bi] = xg[xa + 512 + j];
            xgo[bi] = xg[xa + 768 + j];
        }
        f32x4 acc[4];
#pragma unroll
        for (int m = 0; m < 4; ++m) acc[m] = (f32x4){0.f, 0.f, 0.f, 0.f};
#pragma unroll
        for (int kt = 0; kt < 4; ++kt) {
            long hfr = *(const long*)&h_f8[l15][kt * 32 + qq * 8];
#pragma unroll
            for (int m = 0; m < 4; ++m) {
                long a = *(const long*)&wlds[(size_t)(kt * 64 + wid * 4 + m) * 512 + lane * 8];
                acc[m] = mfma_fp8(a, hfr, acc[m]);
            }
        }
#pragma unroll
        for (int kt = 0; kt < 4; ++kt) {
            long hfr = *(const long*)&h_f8[l15][(4 + kt) * 32 + qq * 8];
#pragma unroll
            for (int m = 0; m < 4; ++m)
                acc[m] = mfma_fp8(wst[kt][m], hfr, acc[m]);
        }
        if (l15 < 8) {
#pragma unroll
            for (int m = 0; m < 4; ++m) {
                int R = (wid * 4 + m) * 16 + qq * 4;
#pragma unroll
                for (int jj = 0; jj < 4; ++jj)
                    g_bf[R + jj][l15] = (u16)(__float_as_uint(acc[m][jj]) >> 16);
            }
        }
        __syncthreads();
#pragma unroll
        for (int bi = 0; bi < 2; ++bi) {
            int b = bq + bi;
            float gi = xgi[bi] + bi_ + bf2f(g_bf[j][b]);
            float gf = xgf[bi] + bf_ + bf2f(g_bf[256 + j][b]);
            float gg = xgg[bi] + bg_ + bf2f(g_bf[512 + j][b]);
            float go = xgo[bi] + bo_ + bf2f(g_bf[768 + j][b]);
            float cc = sigm_fast(gf) * c_s[bi] + sigm_fast(gi) * tanh_fast(gg);
            c_s[bi] = cc;
            float hh = sigm_fast(go) * tanh_fast(cc);
            h_f8[b][j] = f8(hh);
            hout[((size_t)(b * TT + t)) * LH_ + j] = hh;
        }
        __syncthreads();
    }
}

// ---------------- classifier ----------------
__global__ __launch_bounds__(256) void clf_kernel(
    const float* __restrict__ hf, const float* __restrict__ hb,
    const float* __restrict__ W, const float* __restrict__ bias, float* __restrict__ em) {
    int idx = blockIdx.x * blockDim.x + threadIdx.x;
    if (idx >= BB * TT * KK_) return;
    int row = idx / KK_, j = idx % KK_;
    float acc = bias[j];
    const float* hfp = hf + (size_t)row * LH_;
    const float* hbp = hb + (size_t)row * LH_;
    for (int kk = 0; kk < LH_; ++kk) acc += hfp[kk] * W[kk * KK_ + j];
    for (int kk = 0; kk < LH_; ++kk) acc += hbp[kk] * W[(LH_ + kk) * KK_ + j];
    em[idx] = acc;
}

// ---------------- CRF v2 ----------------
__global__ __launch_bounds__(512) void crf2_kernel(
    const float* __restrict__ em, const int* __restrict__ labels, const int* __restrict__ mask,
    const float* __restrict__ cstart, const float* __restrict__ cend,
    const float* __restrict__ ctrans, float* __restrict__ out) {
    __shared__ float trans_s[81];
    __shared__ float res[8];
    int tid = threadIdx.x;
    int b = tid >> 6;
    int l = tid & 63;
    if (tid < 81) trans_s[tid] = ctrans[tid];
    __syncthreads();
    int lc = (l < 9) ? l : 0;
    float tcol[9];
#pragma unroll
    for (int i = 0; i < 9; ++i) tcol[i] = trans_s[i * 9 + lc];
    float alpha = (l < 9) ? cstart[lc] + em[(size_t)b * TT * KK_ + lc] : -1e30f;
    for (int t = 1; t < TT; ++t) {
        float e_t = (l < 9) ? em[((size_t)b * TT + t) * KK_ + lc] : 0.f;
        float m = -1e30f;
        float av[9];
#pragma unroll
        for (int i = 0; i < 9; ++i) {
            av[i] = __shfl(alpha, i) + tcol[i];
            m = fmaxf(m, av[i]);
        }
        float s = 0.f;
#pragma unroll
        for (int i = 0; i < 9; ++i) s += expf(av[i] - m);
        float nv = m + logf(s) + e_t;
        bool upd = (mask[b * TT + t] > 0) && (l < 9);
        alpha = upd ? nv : alpha;
    }
    float z = (l < 9) ? alpha + cend[lc] : -1e30f;
    float zm = z;
#pragma unroll
    for (int o = 32; o > 0; o >>= 1) zm = fmaxf(zm, __shfl_xor(zm, o));
    float zs = (l < 9) ? expf(z - zm) : 0.f;
#pragma unroll
    for (int o = 32; o > 0; o >>= 1) zs += __shfl_xor(zs, o);
    float logZ = zm + logf(zs);
    float sc = 0.f;
    int cnt = 0;
    for (int t = l; t < TT; t += 64) {
        cnt += mask[b * TT + t];
        if (t == 0) {
            int l0 = labels[b * TT];
            sc += cstart[l0] + em[(size_t)b * TT * KK_ + l0];
        } else {
            int lp = labels[b * TT + t - 1];
            int lt = labels[b * TT + t];
            sc += (trans_s[lp * KK_ + lt] + em[((size_t)b * TT + t) * KK_ + lt]) *
                  (float)mask[b * TT + t];
        }
    }
#pragma unroll
    for (int o = 32; o > 0; o >>= 1) { sc += __shfl_xor(sc, o); cnt += __shfl_xor(cnt, o); }
    if (l == 0) {
        int last = labels[b * TT + (cnt - 1)];
        sc += cend[last];
        res[b] = sc - logZ;
    }
    __syncthreads();
    if (tid == 0) {
        float acc = 0.f;
        for (int bb = 0; bb < BB; ++bb) acc += res[bb];
        out[0] = -acc / (float)BB;
    }
}

extern "C" void kernel_launch(void* const* d_in, const int* in_sizes, int n_in,
                              void* d_out, int out_size, void* d_ws, size_t ws_size,
                              hipStream_t stream) {
    const int* input_ids = (const int*)d_in[0];
    const int* attn_mask = (const int*)d_in[1];
    const int* labels    = (const int*)d_in[2];
    const float* word_emb = (const float*)d_in[3];
    const float* pos_emb  = (const float*)d_in[4];
    const float* type_emb = (const float*)d_in[5];
    const float* emb_ln_g = (const float*)d_in[6];
    const float* emb_ln_b = (const float*)d_in[7];
    const float* Wq = (const float*)d_in[8];
    const float* bq = (const float*)d_in[9];
    const float* Wk = (const float*)d_in[10];
    const float* bk = (const float*)d_in[11];
    const float* Wv = (const float*)d_in[12];
    const float* bv = (const float*)d_in[13];
    const float* Wo = (const float*)d_in[14];
    const float* bo = (const float*)d_in[15];
    const float* ln1_g = (const float*)d_in[16];
    const float* ln1_b = (const float*)d_in[17];
    const float* Wf1 = (const float*)d_in[18];
    const float* bf1 = (const float*)d_in[19];
    const float* Wf2 = (const float*)d_in[20];
    const float* bf2 = (const float*)d_in[21];
    const float* ln2_g = (const float*)d_in[22];
    const float* ln2_b = (const float*)d_in[23];
    const float* w_ih_f = (const float*)d_in[24];
    const float* w_hh_f = (const float*)d_in[25];
    const float* b_ih_f = (const float*)d_in[26];
    const float* b_hh_f = (const float*)d_in[27];
    const float* w_ih_b = (const float*)d_in[28];
    const float* w_hh_b = (const float*)d_in[29];
    const float* b_ih_b = (const float*)d_in[30];
    const float* b_hh_b = (const float*)d_in[31];
    const float* W_clf  = (const float*)d_in[32];
    const float* b_clf  = (const float*)d_in[33];
    const float* crf_start = (const float*)d_in[34];
    const float* crf_end   = (const float*)d_in[35];
    const float* crf_trans = (const float*)d_in[36];

    const size_t NTOK = (size_t)BB * TT;          // 2048
    const size_t SZ = NTOK * HH;                  // 1,572,864

    float* ws = (float*)d_ws;
    float* x    = ws;                              // SZ
    float* scr  = x + SZ;                          // scratch (hf/hb/em) 2048*2304
    float* tmp  = scr + NTOK * 2304;               // SZ
    float* ab   = tmp + SZ;                        // SZ
    float* xg   = ab + SZ;                         // 2048*2048
    u8* x_f8    = (u8*)(xg + NTOK * 2048);         // SZ bytes
    u8* ab_f8   = x_f8 + SZ;
    u8* ctx_f8  = ab_f8 + SZ;
    u8* big_f8  = ctx_f8 + SZ;                     // 2048*3072
    u8* qkv8    = big_f8 + NTOK * (size_t)FF_;     // 2048*2304 bytes
    u8* vT      = qkv8 + NTOK * 2304;              // 2048*768 bytes
    u8* wihT    = vT + SZ;                         // 2048*768 bytes
    u8* wfrag8  = wihT + 1572864;                  // 524,288 bytes
    u8* wbuf    = wfrag8 + 524288;                 // per-layer 7,077,888 B (or x12)
    const size_t base_off = (size_t)((u8*)wbuf - (u8*)d_ws);
    bool big = ws_size >= base_off + 12ull * 7077888ull + (1u << 20);

    float* hf = scr;
    float* hb = scr + 524288;
    float* em = scr + 1048576;

    embed_ln_kernel<<<NTOK, 256, 0, stream>>>(input_ids, word_emb, pos_emb, type_emb,
                                              emb_ln_g, emb_ln_b, x, x_f8);
    prep_kernel<<<1792, 256, 0, stream>>>(w_hh_f, w_hh_b, w_ih_f, w_ih_b, wfrag8, wihT);
    if (big)
        conv_w_kernel<true><<<1728 * 12, 256, 0, stream>>>(Wq, Wk, Wv, Wo, Wf1, Wf2, wbuf);

    dim3 gQKV(2304 / 128, NTOK / 128);  // 18 x 16
    dim3 gH(HH / 64, NTOK / 64);        // 12 x 32  (64x64 tiles)
    dim3 gF1(FF_ / 128, NTOK / 128);    // 24 x 16
    dim3 gG(2048 / 128, NTOK / 128);    // 16 x 16

    for (int l = 0; l < NL; ++l) {
        u8* wb = big ? wbuf + (size_t)l * 7077888 : wbuf;
        if (!big)
            conv_w_kernel<false><<<1728, 256, 0, stream>>>(
                Wq + (size_t)l * HH * HH, Wk + (size_t)l * HH * HH,
                Wv + (size_t)l * HH * HH, Wo + (size_t)l * HH * HH,
                Wf1 + (size_t)l * HH * FF_, Wf2 + (size_t)l * FF_ * HH, wb);

        const float* bq_l = bq + (size_t)l * HH;
        const float* bk_l = bk + (size_t)l * HH;
        const float* bv_l = bv + (size_t)l * HH;
        const float* bo_l = bo + (size_t)l * HH;
        const float* g1 = ln1_g + (size_t)l * HH;
        const float* b1 = ln1_b + (size_t)l * HH;
        const float* bf1_l = bf1 + (size_t)l * FF_;
        const float* bf2_l = bf2 + (size_t)l * HH;
        const float* g2 = ln2_g + (size_t)l * HH;
        const float* b2 = ln2_b + (size_t)l * HH;

        gemm3_kernel<128, 128, false, false, true><<<gQKV, 256, 0, stream>>>(
            x_f8, wb, bq_l, bk_l, bv_l, 768, nullptr, qkv8, vT, NTOK, 2304, HH);
        attn_mfma_kernel<<<BB * NH_ * 4, 256, 0, stream>>>(qkv8, vT, attn_mask, ctx_f8);
        gemm3_kernel<64, 64, false, false, false><<<gH, 256, 0, stream>>>(
            ctx_f8, wb + 1769472, bo_l, bo_l, bo_l, 768, tmp, nullptr, nullptr, NTOK, HH, HH);
        ln_residual_kernel<<<NTOK, 256, 0, stream>>>(x, tmp, g1, b1, ab, ab_f8);
        gemm3_kernel<128, 128, true, true, false><<<gF1, 256, 0, stream>>>(
            ab_f8, wb + 2359296, bf1_l, bf1_l, bf1_l, FF_, nullptr, big_f8, nullptr, NTOK, FF_, HH);
        gemm3_kernel<64, 64, false, false, false><<<gH, 256, 0, stream>>>(
            big_f8, wb + 4718592, bf2_l, bf2_l, bf2_l, 768, tmp, nullptr, nullptr, NTOK, HH, FF_);
        ln_residual_kernel<<<NTOK, 256, 0, stream>>>(ab, tmp, g2, b2, x, x_f8);
    }

    // fused LSTM input projections: xg[tok][dir*1024+g]
    gemm3_kernel<128, 128, false, false, false><<<gG, 256, 0, stream>>>(
        x_f8, wihT, b_ih_f, b_ih_b, b_ih_b, 1024, xg, nullptr, nullptr, NTOK, 2048, HH);

    lstm13_kernel<<<2, 1024, 0, stream>>>(xg, wfrag8, b_hh_f, b_hh_b, hf, hb);
    clf_kernel<<<(BB * TT * KK_ + 255) / 256, 256, 0, stream>>>(hf, hb, W_clf, b_clf, em);
    crf2_kernel<<<1, 512, 0, stream>>>(em, labels, attn_mask, crf_start, crf_end, crf_trans,
                                       (float*)d_out);
}

// Round 21
// 1978.244 us; speedup vs baseline: 11.0635x; 1.0685x over previous
//
#include <hip/hip_runtime.h>
#include <math.h>

#define BB 8
#define TT 256
#define HH 768
#define NL 12
#define NH_ 12
#define DH_ 64
#define FF_ 3072
#define LH_ 256
#define KK_ 9

typedef unsigned char u8;
typedef unsigned short u16;
typedef unsigned int u32;
typedef __attribute__((ext_vector_type(4))) float f32x4;

static __device__ __forceinline__ float sigm_fast(float x) {
    return __builtin_amdgcn_rcpf(1.0f + __expf(-x));
}
static __device__ __forceinline__ float tanh_fast(float x) {
    return 1.0f - 2.0f * __builtin_amdgcn_rcpf(1.0f + __expf(2.0f * x));
}
static __device__ __forceinline__ float bf2f(u16 v) {
    return __uint_as_float(((u32)v) << 16);
}
static __device__ __forceinline__ u16 f2b16(float f) {
    u32 u = __float_as_uint(f);
    u += 0x7fffu + ((u >> 16) & 1u);
    return (u16)(u >> 16);
}
template <bool HI>
static __device__ __forceinline__ u32 pk8(float a, float b, u32 old) {
    return (u32)__builtin_amdgcn_cvt_pk_fp8_f32(a, b, (int)old, HI);
}
static __device__ __forceinline__ u8 f8(float v) {
    return (u8)(pk8<false>(v, v, 0) & 0xff);
}

static __device__ __forceinline__ f32x4 mfma_fp8(long a, long b, f32x4 c) {
    return __builtin_amdgcn_mfma_f32_16x16x32_fp8_fp8(a, b, c, 0, 0, 0);
}

#define GLL16(gp, lp) __builtin_amdgcn_global_load_lds( \
    (const __attribute__((address_space(1))) void*)(gp), \
    (__attribute__((address_space(3))) void*)(lp), 16, 0, 0)

// ---------------- block reduce ----------------
static __device__ __forceinline__ float block_sum(float v, float* red) {
    int tid = threadIdx.x;
#pragma unroll
    for (int o = 32; o > 0; o >>= 1) v += __shfl_xor(v, o);
    if ((tid & 63) == 0) red[tid >> 6] = v;
    __syncthreads();
    return red[0] + red[1] + red[2] + red[3];
}

// ---------------- embedding + LN -> fp32 + fp8 ----------------
__global__ __launch_bounds__(256) void embed_ln_kernel(
    const int* __restrict__ ids, const float* __restrict__ we, const float* __restrict__ pe,
    const float* __restrict__ te, const float* __restrict__ g, const float* __restrict__ b,
    float* __restrict__ out, u8* __restrict__ out8) {
    int row = blockIdx.x;
    int t = row % TT;
    int id = ids[row];
    __shared__ float xr[HH];
    __shared__ float reda[8], redb[8];
    int tid = threadIdx.x;
    float s = 0.f;
    for (int h = tid; h < HH; h += 256) {
        float v = we[(size_t)id * HH + h] + pe[(size_t)t * HH + h] + te[h];
        xr[h] = v; s += v;
    }
    float mean = block_sum(s, reda) * (1.0f / HH);
    float vs = 0.f;
    for (int h = tid; h < HH; h += 256) { float d = xr[h] - mean; vs += d * d; }
    float var = block_sum(vs, redb) * (1.0f / HH);
    float rstd = rsqrtf(var + 1e-12f);
    for (int h = tid; h < HH; h += 256) {
        float v = (xr[h] - mean) * rstd * g[h] + b[h];
        out[(size_t)row * HH + h] = v;
        out8[(size_t)row * HH + h] = f8(v);
    }
}

// ---------------- LN(a + f) -> fp32 + fp8 ----------------
__global__ __launch_bounds__(256) void ln_residual_kernel(
    const float* __restrict__ a, const float* __restrict__ f,
    const float* __restrict__ g, const float* __restrict__ b,
    float* __restrict__ out, u8* __restrict__ out8) {
    int row = blockIdx.x;
    __shared__ float xr[HH];
    __shared__ float reda[8], redb[8];
    int tid = threadIdx.x;
    float s = 0.f;
    for (int h = tid; h < HH; h += 256) {
        float v = a[(size_t)row * HH + h] + f[(size_t)row * HH + h];
        xr[h] = v; s += v;
    }
    float mean = block_sum(s, reda) * (1.0f / HH);
    float vs = 0.f;
    for (int h = tid; h < HH; h += 256) { float d = xr[h] - mean; vs += d * d; }
    float var = block_sum(vs, redb) * (1.0f / HH);
    float rstd = rsqrtf(var + 1e-12f);
    for (int h = tid; h < HH; h += 256) {
        float v = (xr[h] - mean) * rstd * g[h] + b[h];
        out[(size_t)row * HH + h] = v;
        out8[(size_t)row * HH + h] = f8(v);
    }
}

// ---------------- weight transpose+convert fp32 -> fp8 [N][K] ----------------
template <bool LAYERS12>
__global__ __launch_bounds__(256) void conv_w_kernel(
    const float* __restrict__ Wq, const float* __restrict__ Wk,
    const float* __restrict__ Wv, const float* __restrict__ Wo,
    const float* __restrict__ Wf1, const float* __restrict__ Wf2,
    u8* __restrict__ wbuf) {
    __shared__ float tile[64][65];
    int bid = blockIdx.x;
    int layer = 0;
    if (LAYERS12) { layer = bid / 1728; bid -= layer * 1728; }
    size_t woff = (size_t)layer * 7077888;
    size_t hh2 = (size_t)layer * HH * HH;
    size_t hf2 = (size_t)layer * HH * FF_;
    const float* src; u8* dst; int R, C, bx, by;
    if (bid < 576) {
        int m = bid / 144, t = bid % 144;
        src = (m == 0 ? Wq + hh2 : m == 1 ? Wk + hh2 : m == 2 ? Wv + hh2 : Wo + hh2);
        dst = wbuf + woff + (size_t)m * 589824;
        R = 768; C = 768; bx = t % 12; by = t / 12;
    } else if (bid < 1152) {
        int t = bid - 576;
        src = Wf1 + hf2; dst = wbuf + woff + 2359296; R = 768; C = 3072;
        bx = t % 48; by = t / 48;
    } else {
        int t = bid - 1152;
        src = Wf2 + hf2; dst = wbuf + woff + 4718592; R = 3072; C = 768;
        bx = t % 12; by = t / 12;
    }
    int tx = threadIdx.x & 15, ty = threadIdx.x >> 4;   // 16 x 16
#pragma unroll
    for (int p = 0; p < 4; ++p) {
        int row = p * 16 + ty;
        float4 v = *(const float4*)&src[(size_t)(by * 64 + row) * C + bx * 64 + tx * 4];
        tile[row][tx * 4 + 0] = v.x; tile[row][tx * 4 + 1] = v.y;
        tile[row][tx * 4 + 2] = v.z; tile[row][tx * 4 + 3] = v.w;
    }
    __syncthreads();
    int rq = (threadIdx.x & 15) * 4, cc0 = threadIdx.x >> 4;   // 16 cols/pass
#pragma unroll
    for (int p = 0; p < 4; ++p) {
        int cc = p * 16 + cc0;
        u32 w0 = pk8<false>(tile[rq][cc], tile[rq + 1][cc], 0);
        w0 = pk8<true>(tile[rq + 2][cc], tile[rq + 3][cc], w0);
        *(u32*)&dst[(size_t)(bx * 64 + cc) * R + by * 64 + rq] = w0;
    }
}

// ---------------- prologue: pack w_hh fp8 frags + convert w_ih -> fp8 ----------------
__global__ __launch_bounds__(256) void prep_kernel(
    const float* __restrict__ whf, const float* __restrict__ whb,
    const float* __restrict__ wif, const float* __restrict__ wib,
    u8* __restrict__ wfrag8, u8* __restrict__ wihT) {
    int bid = blockIdx.x;
    int tid = threadIdx.x;
    if (bid < 256) {
        int idx = bid * 256 + tid;
        int dir = idx >> 15;
        int kt  = (idx >> 12) & 7;
        int mt  = (idx >> 6) & 63;
        int lane = idx & 63;
        const float* W = dir ? whb : whf;
        int row = mt * 16 + (lane & 15);
        int k = kt * 32 + (lane >> 4) * 8;
        const float* src = W + (size_t)row * LH_ + k;
        u32 w0 = pk8<false>(src[0], src[1], 0);
        w0 = pk8<true>(src[2], src[3], w0);
        u32 w1 = pk8<false>(src[4], src[5], 0);
        w1 = pk8<true>(src[6], src[7], w1);
        uint2 pk; pk.x = w0; pk.y = w1;
        size_t base = (size_t)(((dir * 8 + kt) * 64 + mt) * 64 + lane) * 8;
        *(uint2*)&wfrag8[base] = pk;
    } else {
        int which = (bid < 1024) ? 0 : 1;
        const float* src = which ? wib : wif;
        u8* dst = wihT + (size_t)which * 786432;
        int i = (bid - (which ? 1024 : 256)) * 256 + tid;
        float4 v = *(const float4*)&src[(size_t)i * 4];
        u32 w0 = pk8<false>(v.x, v.y, 0);
        w0 = pk8<true>(v.z, v.w, w0);
        *(u32*)&dst[(size_t)i * 4] = w0;
    }
}

// ---------------- GEMM v6: fp8, BK=128, OM: 0=f32 1=fp8 2=bf16 ----------------
template <int BROWS>
__device__ __forceinline__ void stage8(
    const u8* __restrict__ S, int r0, int K, int k0, u8 (*lds)[128], int w, int lane) {
    int rsub = lane >> 3;       // 0..7
    int ap = lane & 7;
    constexpr int INSTS = BROWS / 32;   // per wave
#pragma unroll
    for (int i = 0; i < INSTS; ++i) {
        int row0 = (w * INSTS + i) * 8;
        int row = row0 + rsub;
        int al = ap ^ (row & 7);
        GLL16(S + (size_t)(r0 + row) * K + k0 + al * 16, &lds[row0][0]);
    }
}

static __device__ __forceinline__ long lds8_read(const u8 (*lds)[128], int row, int g) {
    int a = g >> 1;                      // 16B block 0..7
    int phys = a ^ (row & 7);
    return *(const long*)&lds[row][phys * 16 + (g & 1) * 8];
}

template <int BM, int BN, int OM, bool GELU, bool QKVW>
__global__ __launch_bounds__(256) void gemm3_kernel(
    const u8* __restrict__ A, const u8* __restrict__ BT,
    const float* __restrict__ b0, const float* __restrict__ b1, const float* __restrict__ b2,
    int seg, float* __restrict__ C, u8* __restrict__ C8, u16* __restrict__ C16,
    u8* __restrict__ vT, int M, int N, int K) {
    __shared__ u8 Als[2][BM][128];
    __shared__ u8 Bls[2][BN][128];
    int tid = threadIdx.x, lane = tid & 63, w = tid >> 6;
    int m0 = blockIdx.y * BM, n0 = blockIdx.x * BN;
    int wr = w >> 1, wc = w & 1;
    int l15 = lane & 15, q = lane >> 4;
    constexpr int MI = BM / 32;
    constexpr int NJ = BN / 32;

    f32x4 acc[MI][NJ];
#pragma unroll
    for (int mi = 0; mi < MI; ++mi)
#pragma unroll
        for (int nj = 0; nj < NJ; ++nj) acc[mi][nj] = (f32x4){0.f, 0.f, 0.f, 0.f};

    stage8<BM>(A, m0, K, 0, Als[0], w, lane);
    stage8<BN>(BT, n0, K, 0, Bls[0], w, lane);
    __syncthreads();
    int KT = K >> 7, cur = 0;
    for (int kt = 0; kt < KT; ++kt) {
        if (kt + 1 < KT) {
            stage8<BM>(A, m0, K, (kt + 1) << 7, Als[cur ^ 1], w, lane);
            stage8<BN>(BT, n0, K, (kt + 1) << 7, Bls[cur ^ 1], w, lane);
        }
#pragma unroll
        for (int ks = 0; ks < 4; ++ks) {
            int g = ks * 4 + q;
            long bfr[NJ];
#pragma unroll
            for (int nj = 0; nj < NJ; ++nj)
                bfr[nj] = lds8_read(Bls[cur], wc * (BN / 2) + nj * 16 + l15, g);
#pragma unroll
            for (int mi = 0; mi < MI; ++mi) {
                long a = lds8_read(Als[cur], wr * (BM / 2) + mi * 16 + l15, g);
#pragma unroll
                for (int nj = 0; nj < NJ; ++nj)
                    acc[mi][nj] = mfma_fp8(a, bfr[nj], acc[mi][nj]);
            }
        }
        __syncthreads();
        cur ^= 1;
    }

    int rbase = m0 + wr * (BM / 2) + q * 4;
    int cbase = n0 + wc * (BN / 2) + l15;
#pragma unroll
    for (int mi = 0; mi < MI; ++mi) {
#pragma unroll
        for (int nj = 0; nj < NJ; ++nj) {
            int col = cbase + nj * 16;
            int cc = col;
            const float* bp;
            if (cc < seg) bp = b0;
            else if (cc < 2 * seg) { bp = b1; cc -= seg; }
            else { bp = b2; cc -= 2 * seg; }
            float bias = bp[cc];
            if (QKVW && col >= 1536) {
                // V part: pack 4 consecutive token-rows, write transposed vT[b][h][d][t]
                int hh = (col - 1536) >> 6, dl = (col - 1536) & 63;
                int brow = rbase + mi * 16;
                int bb = brow >> 8, t0 = brow & 255;
                u32 pkv = pk8<false>(acc[mi][nj][0] + bias, acc[mi][nj][1] + bias, 0);
                pkv = pk8<true>(acc[mi][nj][2] + bias, acc[mi][nj][3] + bias, pkv);
                *(u32*)&vT[(size_t)((bb * NH_ + hh) * DH_ + dl) * TT + t0] = pkv;
            } else {
#pragma unroll
                for (int j = 0; j < 4; ++j) {
                    int row = rbase + mi * 16 + j;
                    float v = acc[mi][nj][j] + bias;
                    if (GELU) v = 0.5f * v * (1.0f + erff(v * 0.70710678118654752f));
                    if (OM == 1) C8[(size_t)row * N + col] = f8(v);
                    else if (OM == 2) C16[(size_t)row * N + col] = f2b16(v);
                    else C[(size_t)row * N + col] = v;
                }
            }
        }
    }
}

// ---------------- attention v5: MFMA fp8, single-pass softmax in registers ----------------
__global__ __launch_bounds__(256) void attn_mfma_kernel(
    const u8* __restrict__ qkv8, const u8* __restrict__ vT,
    const int* __restrict__ mask, u8* __restrict__ ctx8) {
    int bid = blockIdx.x;
    int qb = bid & 3;
    int bh = bid >> 2;
    int b = bh / NH_, h = bh % NH_;
    int tid = threadIdx.x, lane = tid & 63, w = tid >> 6;
    int l15 = lane & 15, g4 = lane >> 4;
    __shared__ float bias_s[TT];
    __shared__ u8 P[64][260];
    for (int i = tid; i < TT; i += 256)
        bias_s[i] = (1.0f - (float)mask[b * TT + i]) * -10000.0f;
    __syncthreads();

    size_t qoff = (size_t)(b * TT + qb * 64 + w * 16 + l15) * 2304 + h * DH_ + g4 * 8;
    long aq0 = *(const long*)&qkv8[qoff];
    long aq1 = *(const long*)&qkv8[qoff + 32];

    f32x4 sacc[16];
#pragma unroll
    for (int nt = 0; nt < 16; ++nt) sacc[nt] = (f32x4){0.f, 0.f, 0.f, 0.f};
#pragma unroll
    for (int nt = 0; nt < 16; ++nt) {
        size_t koff = (size_t)(b * TT + nt * 16 + l15) * 2304 + 768 + h * DH_ + g4 * 8;
        long b0 = *(const long*)&qkv8[koff];
        long b1 = *(const long*)&qkv8[koff + 32];
        sacc[nt] = mfma_fp8(aq0, b0, sacc[nt]);
        sacc[nt] = mfma_fp8(aq1, b1, sacc[nt]);
    }
    float m[4] = {-1e30f, -1e30f, -1e30f, -1e30f};
#pragma unroll
    for (int nt = 0; nt < 16; ++nt) {
        float bv = bias_s[nt * 16 + l15];
#pragma unroll
        for (int j = 0; j < 4; ++j) {
            float s = sacc[nt][j] * 0.125f + bv;
            sacc[nt][j] = s;
            m[j] = fmaxf(m[j], s);
        }
    }
#pragma unroll
    for (int j = 0; j < 4; ++j) {
        m[j] = fmaxf(m[j], __shfl_xor(m[j], 1));
        m[j] = fmaxf(m[j], __shfl_xor(m[j], 2));
        m[j] = fmaxf(m[j], __shfl_xor(m[j], 4));
        m[j] = fmaxf(m[j], __shfl_xor(m[j], 8));
    }
    float l[4] = {0.f, 0.f, 0.f, 0.f};
#pragma unroll
    for (int nt = 0; nt < 16; ++nt) {
#pragma unroll
        for (int j = 0; j < 4; ++j) {
            float p = __expf(sacc[nt][j] - m[j]);
            sacc[nt][j] = p;
            l[j] += p;
        }
    }
#pragma unroll
    for (int j = 0; j < 4; ++j) {
        l[j] += __shfl_xor(l[j], 1);
        l[j] += __shfl_xor(l[j], 2);
        l[j] += __shfl_xor(l[j], 4);
        l[j] += __shfl_xor(l[j], 8);
    }
#pragma unroll
    for (int nt = 0; nt < 16; ++nt) {
#pragma unroll
        for (int j = 0; j < 4; ++j)
            P[w * 16 + g4 * 4 + j][nt * 16 + l15] = f8(sacc[nt][j]);
    }
    f32x4 oacc[4];
#pragma unroll
    for (int nt4 = 0; nt4 < 4; ++nt4) oacc[nt4] = (f32x4){0.f, 0.f, 0.f, 0.f};
    const u8* vbase = vT + (size_t)(bh * DH_) * TT;
#pragma unroll
    for (int ks = 0; ks < 8; ++ks) {
        long pa = *(const long*)&P[w * 16 + l15][ks * 32 + g4 * 8];
#pragma unroll
        for (int nt4 = 0; nt4 < 4; ++nt4) {
            long bv = *(const long*)&vbase[(size_t)(nt4 * 16 + l15) * TT + ks * 32 + g4 * 8];
            oacc[nt4] = mfma_fp8(pa, bv, oacc[nt4]);
        }
    }
    float inv[4];
#pragma unroll
    for (int j = 0; j < 4; ++j) inv[j] = __builtin_amdgcn_rcpf(l[j]);
    int rowg = b * TT + qb * 64 + w * 16 + g4 * 4;
#pragma unroll
    for (int nt4 = 0; nt4 < 4; ++nt4) {
        int col = h * DH_ + nt4 * 16 + l15;
#pragma unroll
        for (int j = 0; j < 4; ++j)
            ctx8[(size_t)(rowg + j) * HH + col] = f8(oacc[nt4][j] * inv[j]);
    }
}

// ---------------- LSTM v14: 16 blocks (dir x batch); W fully resident; 1-batch update ----------------
__global__ __launch_bounds__(1024, 4) void lstm14_kernel(
    const u16* __restrict__ xgb, const u8* __restrict__ wfrag8,
    const float* __restrict__ bhh_f, const float* __restrict__ bhh_b,
    float* __restrict__ hf, float* __restrict__ hb) {
    int dir = blockIdx.x >> 3;
    int bat = blockIdx.x & 7;
    const u8* wf8 = wfrag8 + (size_t)dir * 262144;
    const float* bhh = dir ? bhh_b : bhh_f;
    float* hout = dir ? hb : hf;
    int tid = threadIdx.x, lane = tid & 63, wid = tid >> 6;
    __shared__ u8 wlds[4 * 64 * 512];     // kt 0..3: 128 KB
    __shared__ u8 h_f8[16][280];
    __shared__ u16 g_bf[1024][10];
    for (int i = tid; i < 16 * 280; i += 1024) ((u8*)h_f8)[i] = 0;
#pragma unroll
    for (int c = 0; c < 8; ++c) {
        int off = wid * 8192 + c * 1024;
        GLL16(wf8 + off + lane * 16, &wlds[off]);
    }
    // kt 4..7 fully register-pinned (32 VGPR): zero per-step global traffic
    long wst[4][4];
#pragma unroll
    for (int kt = 0; kt < 4; ++kt)
#pragma unroll
        for (int m = 0; m < 4; ++m) {
            wst[kt][m] = *(const long*)&wf8[(size_t)(((4 + kt) * 64) + wid * 4 + m) * 512 + lane * 8];
            asm volatile("" : "+v"(wst[kt][m]));
        }
    int l15 = lane & 15, qq = lane >> 4;
    int j = tid & 255;
    float bi_ = bhh[j], bf_ = bhh[256 + j], bg_ = bhh[512 + j], bo_ = bhh[768 + j];
    float c_r = 0.f;
    __syncthreads();
    for (int step = 0; step < TT; ++step) {
        int t = dir ? (TT - 1 - step) : step;
        float xgi = 0.f, xgf = 0.f, xgg = 0.f, xgo = 0.f;
        if (tid < 256) {
            size_t xa = ((size_t)(bat * TT + t)) * 2048 + (size_t)dir * 1024;
            xgi = bf2f(xgb[xa + j]);
            xgf = bf2f(xgb[xa + 256 + j]);
            xgg = bf2f(xgb[xa + 512 + j]);
            xgo = bf2f(xgb[xa + 768 + j]);
        }
        f32x4 acc[4];
#pragma unroll
        for (int m = 0; m < 4; ++m) acc[m] = (f32x4){0.f, 0.f, 0.f, 0.f};
#pragma unroll
        for (int kt = 0; kt < 4; ++kt) {
            long hfr = *(const long*)&h_f8[l15][kt * 32 + qq * 8];
#pragma unroll
            for (int m = 0; m < 4; ++m) {
                long a = *(const long*)&wlds[(size_t)(kt * 64 + wid * 4 + m) * 512 + lane * 8];
                acc[m] = mfma_fp8(a, hfr, acc[m]);
            }
        }
#pragma unroll
        for (int kt = 0; kt < 4; ++kt) {
            long hfr = *(const long*)&h_f8[l15][(4 + kt) * 32 + qq * 8];
#pragma unroll
            for (int m = 0; m < 4; ++m)
                acc[m] = mfma_fp8(wst[kt][m], hfr, acc[m]);
        }
        if (l15 == 0) {
#pragma unroll
            for (int m = 0; m < 4; ++m) {
                int R = (wid * 4 + m) * 16 + qq * 4;
#pragma unroll
                for (int jj = 0; jj < 4; ++jj)
                    g_bf[R + jj][0] = (u16)(__float_as_uint(acc[m][jj]) >> 16);
            }
        }
        __syncthreads();
        if (tid < 256) {
            float gi = xgi + bi_ + bf2f(g_bf[j][0]);
            float gf = xgf + bf_ + bf2f(g_bf[256 + j][0]);
            float gg = xgg + bg_ + bf2f(g_bf[512 + j][0]);
            float go = xgo + bo_ + bf2f(g_bf[768 + j][0]);
            float cc = sigm_fast(gf) * c_r + sigm_fast(gi) * tanh_fast(gg);
            c_r = cc;
            float hh = sigm_fast(go) * tanh_fast(cc);
            h_f8[0][j] = f8(hh);
            hout[((size_t)(bat * TT + t)) * LH_ + j] = hh;
        }
        __syncthreads();
    }
}

// ---------------- classifier ----------------
__global__ __launch_bounds__(256) void clf_kernel(
    const float* __restrict__ hf, const float* __restrict__ hb,
    const float* __restrict__ W, const float* __restrict__ bias, float* __restrict__ em) {
    int idx = blockIdx.x * blockDim.x + threadIdx.x;
    if (idx >= BB * TT * KK_) return;
    int row = idx / KK_, j = idx % KK_;
    float acc = bias[j];
    const float* hfp = hf + (size_t)row * LH_;
    const float* hbp = hb + (size_t)row * LH_;
    for (int kk = 0; kk < LH_; ++kk) acc += hfp[kk] * W[kk * KK_ + j];
    for (int kk = 0; kk < LH_; ++kk) acc += hbp[kk] * W[(LH_ + kk) * KK_ + j];
    em[idx] = acc;
}

// ---------------- CRF v2 ----------------
__global__ __launch_bounds__(512) void crf2_kernel(
    const float* __restrict__ em, const int* __restrict__ labels, const int* __restrict__ mask,
    const float* __restrict__ cstart, const float* __restrict__ cend,
    const float* __restrict__ ctrans, float* __restrict__ out) {
    __shared__ float trans_s[81];
    __shared__ float res[8];
    int tid = threadIdx.x;
    int b = tid >> 6;
    int l = tid & 63;
    if (tid < 81) trans_s[tid] = ctrans[tid];
    __syncthreads();
    int lc = (l < 9) ? l : 0;
    float tcol[9];
#pragma unroll
    for (int i = 0; i < 9; ++i) tcol[i] = trans_s[i * 9 + lc];
    float alpha = (l < 9) ? cstart[lc] + em[(size_t)b * TT * KK_ + lc] : -1e30f;
    for (int t = 1; t < TT; ++t) {
        float e_t = (l < 9) ? em[((size_t)b * TT + t) * KK_ + lc] : 0.f;
        float m = -1e30f;
        float av[9];
#pragma unroll
        for (int i = 0; i < 9; ++i) {
            av[i] = __shfl(alpha, i) + tcol[i];
            m = fmaxf(m, av[i]);
        }
        float s = 0.f;
#pragma unroll
        for (int i = 0; i < 9; ++i) s += expf(av[i] - m);
        float nv = m + logf(s) + e_t;
        bool upd = (mask[b * TT + t] > 0) && (l < 9);
        alpha = upd ? nv : alpha;
    }
    float z = (l < 9) ? alpha + cend[lc] : -1e30f;
    float zm = z;
#pragma unroll
    for (int o = 32; o > 0; o >>= 1) zm = fmaxf(zm, __shfl_xor(zm, o));
    float zs = (l < 9) ? expf(z - zm) : 0.f;
#pragma unroll
    for (int o = 32; o > 0; o >>= 1) zs += __shfl_xor(zs, o);
    float logZ = zm + logf(zs);
    float sc = 0.f;
    int cnt = 0;
    for (int t = l; t < TT; t += 64) {
        cnt += mask[b * TT + t];
        if (t == 0) {
            int l0 = labels[b * TT];
            sc += cstart[l0] + em[(size_t)b * TT * KK_ + l0];
        } else {
            int lp = labels[b * TT + t - 1];
            int lt = labels[b * TT + t];
            sc += (trans_s[lp * KK_ + lt] + em[((size_t)b * TT + t) * KK_ + lt]) *
                  (float)mask[b * TT + t];
        }
    }
#pragma unroll
    for (int o = 32; o > 0; o >>= 1) { sc += __shfl_xor(sc, o); cnt += __shfl_xor(cnt, o); }
    if (l == 0) {
        int last = labels[b * TT + (cnt - 1)];
        sc += cend[last];
        res[b] = sc - logZ;
    }
    __syncthreads();
    if (tid == 0) {
        float acc = 0.f;
        for (int bb = 0; bb < BB; ++bb) acc += res[bb];
        out[0] = -acc / (float)BB;
    }
}

extern "C" void kernel_launch(void* const* d_in, const int* in_sizes, int n_in,
                              void* d_out, int out_size, void* d_ws, size_t ws_size,
                              hipStream_t stream) {
    const int* input_ids = (const int*)d_in[0];
    const int* attn_mask = (const int*)d_in[1];
    const int* labels    = (const int*)d_in[2];
    const float* word_emb = (const float*)d_in[3];
    const float* pos_emb  = (const float*)d_in[4];
    const float* type_emb = (const float*)d_in[5];
    const float* emb_ln_g = (const float*)d_in[6];
    const float* emb_ln_b = (const float*)d_in[7];
    const float* Wq = (const float*)d_in[8];
    const float* bq = (const float*)d_in[9];
    const float* Wk = (const float*)d_in[10];
    const float* bk = (const float*)d_in[11];
    const float* Wv = (const float*)d_in[12];
    const float* bv = (const float*)d_in[13];
    const float* Wo = (const float*)d_in[14];
    const float* bo = (const float*)d_in[15];
    const float* ln1_g = (const float*)d_in[16];
    const float* ln1_b = (const float*)d_in[17];
    const float* Wf1 = (const float*)d_in[18];
    const float* bf1 = (const float*)d_in[19];
    const float* Wf2 = (const float*)d_in[20];
    const float* bf2 = (const float*)d_in[21];
    const float* ln2_g = (const float*)d_in[22];
    const float* ln2_b = (const float*)d_in[23];
    const float* w_ih_f = (const float*)d_in[24];
    const float* w_hh_f = (const float*)d_in[25];
    const float* b_ih_f = (const float*)d_in[26];
    const float* b_hh_f = (const float*)d_in[27];
    const float* w_ih_b = (const float*)d_in[28];
    const float* w_hh_b = (const float*)d_in[29];
    const float* b_ih_b = (const float*)d_in[30];
    const float* b_hh_b = (const float*)d_in[31];
    const float* W_clf  = (const float*)d_in[32];
    const float* b_clf  = (const float*)d_in[33];
    const float* crf_start = (const float*)d_in[34];
    const float* crf_end   = (const float*)d_in[35];
    const float* crf_trans = (const float*)d_in[36];

    const size_t NTOK = (size_t)BB * TT;          // 2048
    const size_t SZ = NTOK * HH;                  // 1,572,864

    float* ws = (float*)d_ws;
    float* x    = ws;                              // SZ
    float* scr  = x + SZ;                          // scratch (hf/hb/em) 2048*2304
    float* tmp  = scr + NTOK * 2304;               // SZ
    float* ab   = tmp + SZ;                        // SZ
    u16* xg16   = (u16*)(ab + SZ);                 // 2048*2048 u16 (8 MB)
    u8* x_f8    = (u8*)(xg16 + NTOK * 2048);       // SZ bytes
    u8* ab_f8   = x_f8 + SZ;
    u8* ctx_f8  = ab_f8 + SZ;
    u8* big_f8  = ctx_f8 + SZ;                     // 2048*3072
    u8* qkv8    = big_f8 + NTOK * (size_t)FF_;     // 2048*2304 bytes
    u8* vT      = qkv8 + NTOK * 2304;              // 2048*768 bytes
    u8* wihT    = vT + SZ;                         // 2048*768 bytes
    u8* wfrag8  = wihT + 1572864;                  // 524,288 bytes
    u8* wbuf    = wfrag8 + 524288;                 // per-layer 7,077,888 B (or x12)
    const size_t base_off = (size_t)((u8*)wbuf - (u8*)d_ws);
    bool big = ws_size >= base_off + 12ull * 7077888ull + (1u << 20);

    float* hf = scr;
    float* hb = scr + 524288;
    float* em = scr + 1048576;

    embed_ln_kernel<<<NTOK, 256, 0, stream>>>(input_ids, word_emb, pos_emb, type_emb,
                                              emb_ln_g, emb_ln_b, x, x_f8);
    prep_kernel<<<1792, 256, 0, stream>>>(w_hh_f, w_hh_b, w_ih_f, w_ih_b, wfrag8, wihT);
    if (big)
        conv_w_kernel<true><<<1728 * 12, 256, 0, stream>>>(Wq, Wk, Wv, Wo, Wf1, Wf2, wbuf);

    dim3 gQKV(2304 / 128, NTOK / 128);  // 18 x 16
    dim3 gH(HH / 64, NTOK / 64);        // 12 x 32  (64x64 tiles)
    dim3 gF1(FF_ / 128, NTOK / 128);    // 24 x 16
    dim3 gG(2048 / 128, NTOK / 128);    // 16 x 16

    for (int l = 0; l < NL; ++l) {
        u8* wb = big ? wbuf + (size_t)l * 7077888 : wbuf;
        if (!big)
            conv_w_kernel<false><<<1728, 256, 0, stream>>>(
                Wq + (size_t)l * HH * HH, Wk + (size_t)l * HH * HH,
                Wv + (size_t)l * HH * HH, Wo + (size_t)l * HH * HH,
                Wf1 + (size_t)l * HH * FF_, Wf2 + (size_t)l * FF_ * HH, wb);

        const float* bq_l = bq + (size_t)l * HH;
        const float* bk_l = bk + (size_t)l * HH;
        const float* bv_l = bv + (size_t)l * HH;
        const float* bo_l = bo + (size_t)l * HH;
        const float* g1 = ln1_g + (size_t)l * HH;
        const float* b1 = ln1_b + (size_t)l * HH;
        const float* bf1_l = bf1 + (size_t)l * FF_;
        const float* bf2_l = bf2 + (size_t)l * HH;
        const float* g2 = ln2_g + (size_t)l * HH;
        const float* b2 = ln2_b + (size_t)l * HH;

        gemm3_kernel<128, 128, 1, false, true><<<gQKV, 256, 0, stream>>>(
            x_f8, wb, bq_l, bk_l, bv_l, 768, nullptr, qkv8, nullptr, vT, NTOK, 2304, HH);
        attn_mfma_kernel<<<BB * NH_ * 4, 256, 0, stream>>>(qkv8, vT, attn_mask, ctx_f8);
        gemm3_kernel<64, 64, 0, false, false><<<gH, 256, 0, stream>>>(
            ctx_f8, wb + 1769472, bo_l, bo_l, bo_l, 768, tmp, nullptr, nullptr, nullptr,
            NTOK, HH, HH);
        ln_residual_kernel<<<NTOK, 256, 0, stream>>>(x, tmp, g1, b1, ab, ab_f8);
        gemm3_kernel<128, 128, 1, true, false><<<gF1, 256, 0, stream>>>(
            ab_f8, wb + 2359296, bf1_l, bf1_l, bf1_l, FF_, nullptr, big_f8, nullptr, nullptr,
            NTOK, FF_, HH);
        gemm3_kernel<64, 64, 0, false, false><<<gH, 256, 0, stream>>>(
            big_f8, wb + 4718592, bf2_l, bf2_l, bf2_l, 768, tmp, nullptr, nullptr, nullptr,
            NTOK, HH, FF_);
        ln_residual_kernel<<<NTOK, 256, 0, stream>>>(ab, tmp, g2, b2, x, x_f8);
    }

    // fused LSTM input projections: xg16[tok][dir*1024+g] (bf16)
    gemm3_kernel<128, 128, 2, false, false><<<gG, 256, 0, stream>>>(
        x_f8, wihT, b_ih_f, b_ih_b, b_ih_b, 1024, nullptr, nullptr, xg16, nullptr,
        NTOK, 2048, HH);

    lstm14_kernel<<<16, 1024, 0, stream>>>(xg16, wfrag8, b_hh_f, b_hh_b, hf, hb);
    clf_kernel<<<(BB * TT * KK_ + 255) / 256, 256, 0, stream>>>(hf, hb, W_clf, b_clf, em);
    crf2_kernel<<<1, 512, 0, stream>>>(em, labels, attn_mask, crf_start, crf_end, crf_trans,
                                       (float*)d_out);
}